// Round 2
// baseline (1480.670 us; speedup 1.0000x reference)
//
#include <hip/hip_runtime.h>
#include <hip/hip_bf16.h>
#include <math.h>

#define BB 4
#define CC 64
#define HH 64
#define WW 64
#define NN 4096        // HH*WW
#define HD 64
#define HID 256
#define EPSV 1e-5f
#define CNT (CC*HH*WW)  // 262144 per-batch elements

__device__ __forceinline__ float gelu_exact(float x) {
    return 0.5f * x * (1.0f + erff(x * 0.70710678118654752f));
}

// ---------------- RoPE sin/cos tables ----------------
__global__ void rope_kernel(float* __restrict__ sin_t, float* __restrict__ cos_t) {
    int i = blockIdx.x * 256 + threadIdx.x;    // NN*HD
    int d = i & 63;
    int n = i >> 6;
    int h = n >> 6, w = n & 63;
    int dd = d & 31;
    int j = dd >> 1;
    float freq = powf(10000.0f, -(float)j / 15.0f);
    float pos = (d < 32) ? (float)h : (float)w;
    float val = pos * freq;
    sin_t[i] = sinf(val);
    cos_t[i] = cosf(val);
}

// ---------------- per-batch mean/rstd ----------------
__global__ __launch_bounds__(256) void stats_kernel(const float* __restrict__ src,
                                                    float* __restrict__ stats, int slot) {
    int b = blockIdx.x;
    const float4* p = (const float4*)(src + (size_t)b * CNT);
    float s = 0.f, s2 = 0.f;
    for (int i = threadIdx.x; i < CNT / 4; i += 256) {
        float4 v = p[i];
        s  += v.x + v.y + v.z + v.w;
        s2 += v.x * v.x + v.y * v.y + v.z * v.z + v.w * v.w;
    }
    for (int off = 32; off > 0; off >>= 1) {
        s  += __shfl_down(s, off);
        s2 += __shfl_down(s2, off);
    }
    __shared__ float shs[4], shs2[4];
    int wid = threadIdx.x >> 6, lane = threadIdx.x & 63;
    if (lane == 0) { shs[wid] = s; shs2[wid] = s2; }
    __syncthreads();
    if (threadIdx.x == 0) {
        float S = shs[0] + shs[1] + shs[2] + shs[3];
        float S2 = shs2[0] + shs2[1] + shs2[2] + shs2[3];
        float mu = S / (float)CNT;
        float var = S2 / (float)CNT - mu * mu;
        stats[slot * 8 + b] = mu;
        stats[slot * 8 + 4 + b] = rsqrtf(var + EPSV);
    }
}

// ---------------- apply GN: dst = (src-mu)*rstd*g + b ----------------
// grid: BB*CC*NN / 256 = 4096 blocks
__global__ __launch_bounds__(256) void gn_apply(const float* __restrict__ src,
                                                float* __restrict__ dst,
                                                const float* __restrict__ g,
                                                const float* __restrict__ bta,
                                                const float* __restrict__ stats, int slot) {
    int i = blockIdx.x * 256 + threadIdx.x;   // BB*CC*NN = 1,048,576
    int b = i >> 18;
    int c = (i >> 12) & 63;
    float mu = stats[slot * 8 + b];
    float rs = stats[slot * 8 + 4 + b];
    dst[i] = (src[i] - mu) * rs * g[c] + bta[c];
}

// ---------------- depthwise 3x3 + bias + residual ----------------
// grid: 4096 blocks
__global__ __launch_bounds__(256) void dw3_res(const float* __restrict__ cn,
                                               const float* __restrict__ w,
                                               const float* __restrict__ bias,
                                               float* __restrict__ out) {
    int i = blockIdx.x * 256 + threadIdx.x;   // BB*CC*HH*WW = 1,048,576
    int x = i & 63;
    int y = (i >> 6) & 63;
    int c = (i >> 12) & 63;
    const float* plane = cn + ((size_t)(i >> 12) << 12);
    float acc = bias[c];
    #pragma unroll
    for (int dy = 0; dy < 3; ++dy) {
        int yy = y + dy - 1;
        if (yy < 0 || yy >= 64) continue;
        #pragma unroll
        for (int dx = 0; dx < 3; ++dx) {
            int xx = x + dx - 1;
            if (xx < 0 || xx >= 64) continue;
            acc += w[c * 9 + dy * 3 + dx] * plane[(yy << 6) + xx];
        }
    }
    out[i] = acc + cn[i];
}

// ---------------- Q = qw @ xn + qb, then RoPE, write (B,N,HD) ----------------
__global__ __launch_bounds__(256) void q_kernel(const float* __restrict__ xn,
                                                const float* __restrict__ qw,
                                                const float* __restrict__ qb,
                                                const float* __restrict__ sin_t,
                                                const float* __restrict__ cos_t,
                                                float* __restrict__ qr) {
    int b = blockIdx.y;
    int n = blockIdx.x * 256 + threadIdx.x;
    float xc[64];
    const float* xp = xn + (size_t)b * CC * NN + n;
    #pragma unroll
    for (int c2 = 0; c2 < 64; ++c2) xc[c2] = xp[(size_t)c2 * NN];
    float* qrow = qr + ((size_t)b * NN + n) * HD;
    const float* st = sin_t + n * 64;
    const float* ct = cos_t + n * 64;
    for (int o = 0; o < 64; o += 2) {
        float a0 = qb[o], a1 = qb[o + 1];
        #pragma unroll
        for (int c2 = 0; c2 < 64; ++c2) {
            a0 += qw[o * 64 + c2] * xc[c2];
            a1 += qw[(o + 1) * 64 + c2] * xc[c2];
        }
        qrow[o]     = a0 * ct[o]     - a1 * st[o];
        qrow[o + 1] = a1 * ct[o + 1] + a0 * st[o + 1];
    }
}

// ---------------- KV = kvw @ kvin + kvb; K gets RoPE ----------------
__global__ __launch_bounds__(256) void kv_kernel(const float* __restrict__ kvin,
                                                 const float* __restrict__ kvw,
                                                 const float* __restrict__ kvb,
                                                 const float* __restrict__ sin_t,
                                                 const float* __restrict__ cos_t,
                                                 float* __restrict__ kr,
                                                 float* __restrict__ v) {
    int b = blockIdx.y;
    int n = blockIdx.x * 256 + threadIdx.x;
    float xc[64];
    const float* xp = kvin + (size_t)b * CC * NN + n;
    #pragma unroll
    for (int c2 = 0; c2 < 64; ++c2) xc[c2] = xp[(size_t)c2 * NN];
    float* krow = kr + ((size_t)b * NN + n) * HD;
    float* vrow = v  + ((size_t)b * NN + n) * HD;
    const float* st = sin_t + n * 64;
    const float* ct = cos_t + n * 64;
    for (int o = 0; o < 128; o += 2) {
        float a0 = kvb[o], a1 = kvb[o + 1];
        #pragma unroll
        for (int c2 = 0; c2 < 64; ++c2) {
            a0 += kvw[o * 64 + c2] * xc[c2];
            a1 += kvw[(o + 1) * 64 + c2] * xc[c2];
        }
        if (o < 64) {
            krow[o]     = a0 * ct[o]     - a1 * st[o];
            krow[o + 1] = a1 * ct[o + 1] + a0 * st[o + 1];
        } else {
            vrow[o - 64] = a0;
            vrow[o - 63] = a1;
        }
    }
}

// ---------------- flash attention + residual; writes x2 (B,C,N) ----------------
#define QB 32
#define KB 32
__global__ __launch_bounds__(256) void attn_kernel(const float* __restrict__ qr,
                                                   const float* __restrict__ kr,
                                                   const float* __restrict__ v,
                                                   const float* __restrict__ x,
                                                   float* __restrict__ x2) {
    int b = blockIdx.y;
    int q0 = blockIdx.x * QB;
    int tid = threadIdx.x;
    int qi = tid >> 3;     // 0..31
    int g = tid & 7;       // 0..7
    int d0 = g * 8;

    __shared__ float Ks[KB][68];
    __shared__ float Vs[KB][68];
    __shared__ float Ps[QB][33];
    __shared__ float Sc[QB];

    float Qreg[64];
    const float* qp = qr + ((size_t)b * NN + q0 + qi) * HD;
    #pragma unroll
    for (int c2 = 0; c2 < 64; ++c2) Qreg[c2] = qp[c2];

    float m = -INFINITY, l = 0.f;
    float oacc[8];
    #pragma unroll
    for (int j = 0; j < 8; ++j) oacc[j] = 0.f;

    for (int t = 0; t < NN / KB; ++t) {
        __syncthreads();
        const float* kbase = kr + ((size_t)b * NN + t * KB) * HD;
        const float* vbase = v  + ((size_t)b * NN + t * KB) * HD;
        for (int i = tid; i < KB * HD; i += 256) {
            Ks[i >> 6][i & 63] = kbase[i];
            Vs[i >> 6][i & 63] = vbase[i];
        }
        __syncthreads();

        float s4[4];
        #pragma unroll
        for (int jj = 0; jj < 4; ++jj) {
            int ki = g + 8 * jj;
            const float4* krow = (const float4*)(&Ks[ki][0]);
            float a = 0.f;
            #pragma unroll
            for (int t4 = 0; t4 < 16; ++t4) {
                float4 kk = krow[t4];
                a += Qreg[4 * t4] * kk.x + Qreg[4 * t4 + 1] * kk.y +
                     Qreg[4 * t4 + 2] * kk.z + Qreg[4 * t4 + 3] * kk.w;
            }
            s4[jj] = a * 0.125f;
        }
        float tmax = fmaxf(fmaxf(s4[0], s4[1]), fmaxf(s4[2], s4[3]));
        #pragma unroll
        for (int off = 1; off < 8; off <<= 1) tmax = fmaxf(tmax, __shfl_xor(tmax, off, 8));
        float mnew = fmaxf(m, tmax);
        float corr = expf(m - mnew);
        float psum = 0.f;
        #pragma unroll
        for (int jj = 0; jj < 4; ++jj) {
            float p = expf(s4[jj] - mnew);
            Ps[qi][g + 8 * jj] = p;
            psum += p;
        }
        #pragma unroll
        for (int off = 1; off < 8; off <<= 1) psum += __shfl_xor(psum, off, 8);
        l = l * corr + psum;
        m = mnew;
        if (g == 0) Sc[qi] = corr;
        __syncthreads();

        float cf = Sc[qi];
        #pragma unroll
        for (int j = 0; j < 8; ++j) oacc[j] *= cf;
        #pragma unroll 4
        for (int ki = 0; ki < KB; ++ki) {
            float p = Ps[qi][ki];
            float4 v0 = *(const float4*)&Vs[ki][d0];
            float4 v1 = *(const float4*)&Vs[ki][d0 + 4];
            oacc[0] += p * v0.x; oacc[1] += p * v0.y;
            oacc[2] += p * v0.z; oacc[3] += p * v0.w;
            oacc[4] += p * v1.x; oacc[5] += p * v1.y;
            oacc[6] += p * v1.z; oacc[7] += p * v1.w;
        }
    }

    float inv = 1.f / l;
    int n = q0 + qi;
    const float* xp = x + (size_t)b * CC * NN + n;
    float* x2p = x2 + (size_t)b * CC * NN + n;
    #pragma unroll
    for (int j = 0; j < 8; ++j) {
        size_t off = (size_t)(d0 + j) * NN;
        x2p[off] = oacc[j] * inv + xp[off];
    }
}

// ---------------- fc1: h1 = gelu(bn1(fc1w @ gn2(x2))) ----------------
__global__ __launch_bounds__(256) void fc1_kernel(const float* __restrict__ x2,
                                                  const float* __restrict__ fc1w,
                                                  const float* __restrict__ n2g,
                                                  const float* __restrict__ n2b,
                                                  const float* __restrict__ bn1g,
                                                  const float* __restrict__ bn1b,
                                                  const float* __restrict__ stats,
                                                  float* __restrict__ h1) {
    int b = blockIdx.y;
    int n = blockIdx.x * 256 + threadIdx.x;
    float mu = stats[2 * 8 + b];
    float rs = stats[2 * 8 + 4 + b];
    float xc[64];
    const float* xp = x2 + (size_t)b * CC * NN + n;
    #pragma unroll
    for (int c2 = 0; c2 < 64; ++c2)
        xc[c2] = (xp[(size_t)c2 * NN] - mu) * rs * n2g[c2] + n2b[c2];
    float* hp = h1 + (size_t)b * HID * NN + n;
    const float sb = rsqrtf(1.f + EPSV);
    for (int o = 0; o < HID; ++o) {
        float a = 0.f;
        #pragma unroll
        for (int c2 = 0; c2 < 64; ++c2) a += fc1w[o * 64 + c2] * xc[c2];
        float t = a * bn1g[o] * sb + bn1b[o];
        hp[(size_t)o * NN] = gelu_exact(t);
    }
}

// ---------------- mixer: dw(1/3/5/7) + fft-scale + residual + gelu + bnm ----------------
// grid: BB*HID*HH*WW/256 = 16384
__global__ __launch_bounds__(256) void mixer_kernel(const float* __restrict__ h1,
                                                    const float* __restrict__ dw1w, const float* __restrict__ dw1b,
                                                    const float* __restrict__ dw3w, const float* __restrict__ dw3b,
                                                    const float* __restrict__ dw5w, const float* __restrict__ dw5b,
                                                    const float* __restrict__ dw7w, const float* __restrict__ dw7b,
                                                    const float* __restrict__ fftw,
                                                    const float* __restrict__ bnmg, const float* __restrict__ bnmb,
                                                    float* __restrict__ h2) {
    int i = blockIdx.x * 256 + threadIdx.x;   // BB*HID*HH*WW = 4,194,304
    int x = i & 63;
    int y = (i >> 6) & 63;
    int c = (i >> 12) & 255;
    const float* plane = h1 + ((size_t)(i >> 12) << 12);
    float acc;
    if (c < 64) {
        acc = dw1w[c] * plane[(y << 6) + x] + dw1b[c];
    } else if (c < 128) {
        int lc = c - 64;
        acc = dw3b[lc];
        const float* wp = dw3w + lc * 9;
        #pragma unroll
        for (int dy = 0; dy < 3; ++dy) {
            int yy = y + dy - 1;
            if (yy < 0 || yy >= 64) continue;
            #pragma unroll
            for (int dx = 0; dx < 3; ++dx) {
                int xx = x + dx - 1;
                if (xx < 0 || xx >= 64) continue;
                acc += wp[dy * 3 + dx] * plane[(yy << 6) + xx];
            }
        }
    } else if (c < 192) {
        int lc = c - 128;
        acc = dw5b[lc];
        const float* wp = dw5w + lc * 25;
        #pragma unroll
        for (int dy = 0; dy < 5; ++dy) {
            int yy = y + dy - 2;
            if (yy < 0 || yy >= 64) continue;
            #pragma unroll
            for (int dx = 0; dx < 5; ++dx) {
                int xx = x + dx - 2;
                if (xx < 0 || xx >= 64) continue;
                acc += wp[dy * 5 + dx] * plane[(yy << 6) + xx];
            }
        }
    } else {
        int lc = c - 192;
        acc = dw7b[lc];
        const float* wp = dw7w + lc * 49;
        #pragma unroll
        for (int dy = 0; dy < 7; ++dy) {
            int yy = y + dy - 3;
            if (yy < 0 || yy >= 64) continue;
            #pragma unroll
            for (int dx = 0; dx < 7; ++dx) {
                int xx = x + dx - 3;
                if (xx < 0 || xx >= 64) continue;
                acc += wp[dy * 7 + dx] * plane[(yy << 6) + xx];
            }
        }
    }
    // FFT with real per-channel scalar filter == per-channel scale (linearity)
    float val = fftw[c] * acc + h1[i];
    float gg = gelu_exact(val);
    h2[i] = gg * bnmg[c] * rsqrtf(1.f + EPSV) + bnmb[c];
}

// ---------------- fc2 + bn2 + final residual ----------------
__global__ __launch_bounds__(256) void fc2_kernel(const float* __restrict__ h2,
                                                  const float* __restrict__ fc2w,
                                                  const float* __restrict__ bn2g,
                                                  const float* __restrict__ bn2b,
                                                  const float* __restrict__ x2,
                                                  float* __restrict__ out) {
    int b = blockIdx.y;
    int n = blockIdx.x * 256 + threadIdx.x;
    float acc[64];
    #pragma unroll
    for (int o = 0; o < 64; ++o) acc[o] = 0.f;
    const float* hp = h2 + (size_t)b * HID * NN + n;
    for (int c2 = 0; c2 < HID; ++c2) {
        float hv = hp[(size_t)c2 * NN];
        #pragma unroll
        for (int o = 0; o < 64; ++o) acc[o] += fc2w[o * 256 + c2] * hv;
    }
    const float* xp = x2 + (size_t)b * CC * NN + n;
    float* op = out + (size_t)b * CC * NN + n;
    const float sb = rsqrtf(1.f + EPSV);
    for (int o = 0; o < 64; ++o) {
        float val = acc[o] * bn2g[o] * sb + bn2b[o] + xp[(size_t)o * NN];
        op[(size_t)o * NN] = val;
    }
}

extern "C" void kernel_launch(void* const* d_in, const int* in_sizes, int n_in,
                              void* d_out, int out_size, void* d_ws, size_t ws_size,
                              hipStream_t stream) {
    const float* x    = (const float*)d_in[0];
    const float* cnn  = (const float*)d_in[1];
    const float* n1g  = (const float*)d_in[2];
    const float* n1b  = (const float*)d_in[3];
    const float* n2g  = (const float*)d_in[4];
    const float* n2b  = (const float*)d_in[5];
    const float* n3g  = (const float*)d_in[6];
    const float* n3b  = (const float*)d_in[7];
    const float* qw   = (const float*)d_in[8];
    const float* qb   = (const float*)d_in[9];
    const float* kvw  = (const float*)d_in[10];
    const float* kvb  = (const float*)d_in[11];
    const float* lcw  = (const float*)d_in[12];
    const float* lcb  = (const float*)d_in[13];
    const float* fc1w = (const float*)d_in[14];
    const float* bn1g = (const float*)d_in[15];
    const float* bn1b = (const float*)d_in[16];
    const float* dw1w = (const float*)d_in[17];
    const float* dw1b = (const float*)d_in[18];
    const float* dw3w = (const float*)d_in[19];
    const float* dw3b = (const float*)d_in[20];
    const float* dw5w = (const float*)d_in[21];
    const float* dw5b = (const float*)d_in[22];
    const float* dw7w = (const float*)d_in[23];
    const float* dw7b = (const float*)d_in[24];
    const float* bnmg = (const float*)d_in[25];
    const float* bnmb = (const float*)d_in[26];
    const float* fftw = (const float*)d_in[27];
    const float* fc2w = (const float*)d_in[28];
    const float* bn2g = (const float*)d_in[29];
    const float* bn2b = (const float*)d_in[30];

    float* ws = (float*)d_ws;
    // layout (floats): sin 262144 | cos 262144 | stats 64 | buffers
    float* sin_t = ws;
    float* cos_t = ws + 262144;
    float* stats = ws + 524288;
    float* base  = ws + 524352;
    const size_t SM = 1048576;        // x-shaped buffer (floats)
    float* bufA = base;               // xn        (later part of h1)
    float* bufC = base + 1 * SM;      // kv_in     (later part of h1)
    float* bufD = base + 2 * SM;      // qr        (later part of h1)
    float* bufE = base + 3 * SM;      // v         (later part of h1)
    float* bufB = base + 4 * SM;      // cn, later kr
    float* bufF = base + 5 * SM;      // x2
    float* h1   = base;               // 4M floats over A,C,D,E (all dead by then)
    float* h2   = base + 6 * SM;      // 4M floats
    float* outp = (float*)d_out;
    // total ws use: 524352 + 10*SM floats ~= 44 MB

    rope_kernel<<<1024, 256, 0, stream>>>(sin_t, cos_t);
    stats_kernel<<<4, 256, 0, stream>>>(x, stats, 0);
    stats_kernel<<<4, 256, 0, stream>>>(cnn, stats, 1);
    gn_apply<<<4096, 256, 0, stream>>>(x, bufA, n1g, n1b, stats, 0);
    gn_apply<<<4096, 256, 0, stream>>>(cnn, bufB, n3g, n3b, stats, 1);
    dw3_res<<<4096, 256, 0, stream>>>(bufB, lcw, lcb, bufC);
    q_kernel<<<dim3(16, 4), 256, 0, stream>>>(bufA, qw, qb, sin_t, cos_t, bufD);
    kv_kernel<<<dim3(16, 4), 256, 0, stream>>>(bufC, kvw, kvb, sin_t, cos_t, bufB, bufE);
    attn_kernel<<<dim3(128, 4), 256, 0, stream>>>(bufD, bufB, bufE, x, bufF);
    stats_kernel<<<4, 256, 0, stream>>>(bufF, stats, 2);
    fc1_kernel<<<dim3(16, 4), 256, 0, stream>>>(bufF, fc1w, n2g, n2b, bn1g, bn1b, stats, h1);
    mixer_kernel<<<16384, 256, 0, stream>>>(h1, dw1w, dw1b, dw3w, dw3b, dw5w, dw5b,
                                            dw7w, dw7b, fftw, bnmg, bnmb, h2);
    fc2_kernel<<<dim3(16, 4), 256, 0, stream>>>(h2, fc2w, bn2g, bn2b, bufF, outp);
}

// Round 3
// 385.425 us; speedup vs baseline: 3.8417x; 3.8417x over previous
//
#include <hip/hip_runtime.h>
#include <hip/hip_bf16.h>
#include <math.h>

#define BB 4
#define CC 64
#define HH 64
#define WW 64
#define NN 4096
#define HD 64
#define HID 256
#define EPSV 1e-5f
#define CNT (CC*HH*WW)

typedef float f32x4 __attribute__((ext_vector_type(4)));
typedef short bf16x8 __attribute__((ext_vector_type(8)));
#define MFMA16(a, b, c) __builtin_amdgcn_mfma_f32_16x16x32_bf16(a, b, c, 0, 0, 0)

__device__ __forceinline__ float gelu_exact(float x) {
    return 0.5f * x * (1.0f + erff(x * 0.70710678118654752f));
}
__device__ __forceinline__ ushort f2bf(float f) {
    unsigned u = __float_as_uint(f);
    unsigned r = (u + 0x7FFFu + ((u >> 16) & 1u)) >> 16;
    return (ushort)r;
}

// ---------------- RoPE sin/cos tables ----------------
__global__ __launch_bounds__(256) void rope_kernel(float* __restrict__ sin_t, float* __restrict__ cos_t) {
    int i = blockIdx.x * 256 + threadIdx.x;    // NN*HD
    int d = i & 63;
    int n = i >> 6;
    int h = n >> 6, w = n & 63;
    int j = (d & 31) >> 1;
    float freq = exp2f(-0.88584749f * (float)j);   // 10000^{-j/15}
    float pos = (d < 32) ? (float)h : (float)w;
    float val = pos * freq;
    sin_t[i] = __sinf(val);
    cos_t[i] = __cosf(val);
}

// ---------------- stats stage 1: per-block partial sums ----------------
__global__ __launch_bounds__(256) void stats1_kernel(const float* __restrict__ src,
                                                     float* __restrict__ part) {
    int b = blockIdx.y;
    int blk = blockIdx.x;       // 64 per batch
    const float4* p = (const float4*)(src + (size_t)b * CNT);
    float s = 0.f, s2 = 0.f;
    #pragma unroll
    for (int k = 0; k < 4; ++k) {
        float4 v = p[blk * 1024 + k * 256 + threadIdx.x];
        s  += v.x + v.y + v.z + v.w;
        s2 += v.x * v.x + v.y * v.y + v.z * v.z + v.w * v.w;
    }
    #pragma unroll
    for (int off = 32; off > 0; off >>= 1) {
        s  += __shfl_xor(s, off);
        s2 += __shfl_xor(s2, off);
    }
    __shared__ float shs[4], shs2[4];
    int wid = threadIdx.x >> 6, lane = threadIdx.x & 63;
    if (lane == 0) { shs[wid] = s; shs2[wid] = s2; }
    __syncthreads();
    if (threadIdx.x == 0) {
        part[(b * 64 + blk) * 2]     = shs[0] + shs[1] + shs[2] + shs[3];
        part[(b * 64 + blk) * 2 + 1] = shs2[0] + shs2[1] + shs2[2] + shs2[3];
    }
}

// ---------------- stats stage 2 ----------------
__global__ __launch_bounds__(64) void stats2_kernel(const float* __restrict__ part,
                                                    float* __restrict__ stats, int slot) {
    int b = blockIdx.x;
    int lane = threadIdx.x;
    float s = part[(b * 64 + lane) * 2];
    float s2 = part[(b * 64 + lane) * 2 + 1];
    #pragma unroll
    for (int off = 32; off > 0; off >>= 1) {
        s  += __shfl_xor(s, off);
        s2 += __shfl_xor(s2, off);
    }
    if (lane == 0) {
        float mu = s / (float)CNT;
        float var = s2 / (float)CNT - mu * mu;
        stats[slot * 8 + b] = mu;
        stats[slot * 8 + 4 + b] = rsqrtf(var + EPSV);
    }
}

// ---------------- apply GN ----------------
__global__ __launch_bounds__(256) void gn_apply(const float* __restrict__ src,
                                                float* __restrict__ dst,
                                                const float* __restrict__ g,
                                                const float* __restrict__ bta,
                                                const float* __restrict__ stats, int slot) {
    int i = blockIdx.x * 256 + threadIdx.x;   // 1,048,576
    int b = i >> 18;
    int c = (i >> 12) & 63;
    float mu = stats[slot * 8 + b];
    float rs = stats[slot * 8 + 4 + b];
    dst[i] = (src[i] - mu) * rs * g[c] + bta[c];
}

// ---------------- depthwise 3x3 + bias + residual ----------------
__global__ __launch_bounds__(256) void dw3_res(const float* __restrict__ cn,
                                               const float* __restrict__ w,
                                               const float* __restrict__ bias,
                                               float* __restrict__ out) {
    int i = blockIdx.x * 256 + threadIdx.x;   // 1,048,576
    int x = i & 63;
    int y = (i >> 6) & 63;
    int c = (i >> 12) & 63;
    const float* plane = cn + ((size_t)(i >> 12) << 12);
    float acc = bias[c];
    #pragma unroll
    for (int dy = 0; dy < 3; ++dy) {
        int yy = y + dy - 1;
        if (yy < 0 || yy >= 64) continue;
        #pragma unroll
        for (int dx = 0; dx < 3; ++dx) {
            int xx = x + dx - 1;
            if (xx < 0 || xx >= 64) continue;
            acc += w[c * 9 + dy * 3 + dx] * plane[(yy << 6) + xx];
        }
    }
    out[i] = acc + cn[i];
}

// ---------------- Q projection + RoPE -> bf16 (B,N,HD) ----------------
// grid dim3(64, B), 256 thr: 64 tokens x 4 output-groups of 16
__global__ __launch_bounds__(256) void q_kernel(const float* __restrict__ xn,
                                                const float* __restrict__ qw,
                                                const float* __restrict__ qb,
                                                const float* __restrict__ sin_t,
                                                const float* __restrict__ cos_t,
                                                ushort* __restrict__ qr) {
    int b = blockIdx.y;
    int tok0 = blockIdx.x * 64;
    int tl = threadIdx.x & 63;
    int og = threadIdx.x >> 6;
    int tok = tok0 + tl;
    __shared__ float xs[64][64];
    for (int k = 0; k < 16; ++k) {
        int e = threadIdx.x + k * 256;
        xs[e >> 6][e & 63] = xn[((size_t)b * 64 + (e >> 6)) * NN + tok0 + (e & 63)];
    }
    __syncthreads();
    float xc[64];
    #pragma unroll
    for (int c = 0; c < 64; ++c) xc[c] = xs[c][tl];
    const float* st = sin_t + tok * 64;
    const float* ct = cos_t + tok * 64;
    ushort* qrow = qr + ((size_t)b * NN + tok) * 64;
    for (int oo = 0; oo < 16; oo += 2) {
        int o = og * 16 + oo;
        float a0 = qb[o], a1 = qb[o + 1];
        #pragma unroll
        for (int c = 0; c < 64; ++c) {
            a0 += qw[o * 64 + c] * xc[c];
            a1 += qw[(o + 1) * 64 + c] * xc[c];
        }
        qrow[o]     = f2bf(a0 * ct[o]     - a1 * st[o]);
        qrow[o + 1] = f2bf(a1 * ct[o + 1] + a0 * st[o + 1]);
    }
}

// ---------------- KV projection; K+RoPE -> bf16 (B,N,HD); V -> bf16 (B,HD,N) ----------------
__global__ __launch_bounds__(256) void kv_kernel(const float* __restrict__ kvin,
                                                 const float* __restrict__ kvw,
                                                 const float* __restrict__ kvb,
                                                 const float* __restrict__ sin_t,
                                                 const float* __restrict__ cos_t,
                                                 ushort* __restrict__ kr,
                                                 ushort* __restrict__ vt) {
    int b = blockIdx.y;
    int tok0 = blockIdx.x * 64;
    int tl = threadIdx.x & 63;
    int og = threadIdx.x >> 6;
    int tok = tok0 + tl;
    __shared__ float xs[64][64];
    for (int k = 0; k < 16; ++k) {
        int e = threadIdx.x + k * 256;
        xs[e >> 6][e & 63] = kvin[((size_t)b * 64 + (e >> 6)) * NN + tok0 + (e & 63)];
    }
    __syncthreads();
    float xc[64];
    #pragma unroll
    for (int c = 0; c < 64; ++c) xc[c] = xs[c][tl];
    if (og < 2) {
        const float* st = sin_t + tok * 64;
        const float* ct = cos_t + tok * 64;
        ushort* krow = kr + ((size_t)b * NN + tok) * 64;
        for (int oo = 0; oo < 32; oo += 2) {
            int o = og * 32 + oo;
            float a0 = kvb[o], a1 = kvb[o + 1];
            #pragma unroll
            for (int c = 0; c < 64; ++c) {
                a0 += kvw[o * 64 + c] * xc[c];
                a1 += kvw[(o + 1) * 64 + c] * xc[c];
            }
            krow[o]     = f2bf(a0 * ct[o]     - a1 * st[o]);
            krow[o + 1] = f2bf(a1 * ct[o + 1] + a0 * st[o + 1]);
        }
    } else {
        int hd0 = (og - 2) * 32;
        for (int oo = 0; oo < 32; ++oo) {
            int o = 64 + hd0 + oo;
            float a0 = kvb[o];
            #pragma unroll
            for (int c = 0; c < 64; ++c) a0 += kvw[o * 64 + c] * xc[c];
            vt[((size_t)b * 64 + hd0 + oo) * NN + tok] = f2bf(a0);
        }
    }
}

// ---------------- MFMA flash attention + residual -> x2 (B,C,N) fp32 ----------------
// grid dim3(64, B), 256 thr = 4 waves x 16 q-rows; KV tile = 64
__global__ __launch_bounds__(256) void attn_kernel(const ushort* __restrict__ qr,
                                                   const ushort* __restrict__ kr,
                                                   const ushort* __restrict__ vt,
                                                   const float* __restrict__ x,
                                                   float* __restrict__ x2) {
    int b = blockIdx.y;
    int q0 = blockIdx.x * 64;
    int tid = threadIdx.x;
    int w = tid >> 6;
    int lane = tid & 63;
    int lr = lane & 15;
    int lg = lane >> 4;

    __shared__ ushort Kl[64 * 64];
    __shared__ ushort Vl[64 * 64];
    __shared__ ushort Pl[4 * 16 * 64];
    ushort* Pw = Pl + w * 1024;

    // Q fragments (A-operand): lane holds Q[w*16+lr][ks*32 + lg*8 .. +8]
    bf16x8 qf[2];
    {
        const ushort* qp = qr + ((size_t)b * NN + q0 + w * 16 + lr) * 64;
        qf[0] = *(const bf16x8*)(qp + lg * 8);
        qf[1] = *(const bf16x8*)(qp + 32 + lg * 8);
    }

    f32x4 oacc[4];
    #pragma unroll
    for (int t = 0; t < 4; ++t) oacc[t] = (f32x4){0.f, 0.f, 0.f, 0.f};
    float m_[4], l_[4];
    #pragma unroll
    for (int r = 0; r < 4; ++r) { m_[r] = -INFINITY; l_[r] = 0.f; }

    const size_t kbase = ((size_t)b * NN) * 64;

    for (int t = 0; t < NN / 64; ++t) {
        int k0 = t * 64;
        __syncthreads();
        // stage K (row=key, col=hd) and Vt (row=hd, col=key), XOR-swizzled 16B chunks
        #pragma unroll
        for (int it = 0; it < 2; ++it) {
            int e = tid + it * 256;           // 0..511 chunk id
            int row = e >> 3, cib = e & 7;
            int sw = cib ^ (row & 7);
            *(bf16x8*)(Kl + row * 64 + sw * 8) =
                *(const bf16x8*)(kr + kbase + (size_t)(k0 + row) * 64 + cib * 8);
            *(bf16x8*)(Vl + row * 64 + sw * 8) =
                *(const bf16x8*)(vt + ((size_t)b * 64 + row) * NN + k0 + cib * 8);
        }
        __syncthreads();

        // S = Q K^T  (4 tiles of 16 keys)
        f32x4 sacc[4];
        #pragma unroll
        for (int kt = 0; kt < 4; ++kt) {
            int row = kt * 16 + lr;
            bf16x8 k0f = *(const bf16x8*)(Kl + row * 64 + ((0 * 4 + lg) ^ (lr & 7)) * 8);
            bf16x8 k1f = *(const bf16x8*)(Kl + row * 64 + ((1 * 4 + lg) ^ (lr & 7)) * 8);
            f32x4 z = {0.f, 0.f, 0.f, 0.f};
            z = MFMA16(qf[0], k0f, z);
            sacc[kt] = MFMA16(qf[1], k1f, z);
        }

        // online softmax (rows live in one 16-lane group)
        float mx[4];
        #pragma unroll
        for (int r = 0; r < 4; ++r) {
            float v0 = fmaxf(fmaxf(sacc[0][r], sacc[1][r]), fmaxf(sacc[2][r], sacc[3][r]));
            v0 = fmaxf(v0, __shfl_xor(v0, 1));
            v0 = fmaxf(v0, __shfl_xor(v0, 2));
            v0 = fmaxf(v0, __shfl_xor(v0, 4));
            v0 = fmaxf(v0, __shfl_xor(v0, 8));
            mx[r] = v0 * 0.125f;
        }
        float corr[4], mnew[4], rowsum[4];
        #pragma unroll
        for (int r = 0; r < 4; ++r) {
            mnew[r] = fmaxf(m_[r], mx[r]);
            corr[r] = __expf(m_[r] - mnew[r]);
            rowsum[r] = 0.f;
        }
        #pragma unroll
        for (int kt = 0; kt < 4; ++kt) {
            #pragma unroll
            for (int r = 0; r < 4; ++r) {
                int R = lg * 4 + r;
                float pv = __expf(sacc[kt][r] * 0.125f - mnew[r]);
                rowsum[r] += pv;
                Pw[R * 64 + ((kt * 2 + (lr >> 3)) ^ (R & 7)) * 8 + (lr & 7)] = f2bf(pv);
            }
        }
        #pragma unroll
        for (int r = 0; r < 4; ++r) {
            float s = rowsum[r];
            s += __shfl_xor(s, 1);
            s += __shfl_xor(s, 2);
            s += __shfl_xor(s, 4);
            s += __shfl_xor(s, 8);
            l_[r] = l_[r] * corr[r] + s;
            m_[r] = mnew[r];
        }
        #pragma unroll
        for (int ht = 0; ht < 4; ++ht)
            #pragma unroll
            for (int r = 0; r < 4; ++r) oacc[ht][r] *= corr[r];

        // O += P V   (A = P from per-wave LDS, B = Vt rows)
        bf16x8 pa0 = *(const bf16x8*)(Pw + lr * 64 + ((0 * 4 + lg) ^ (lr & 7)) * 8);
        bf16x8 pa1 = *(const bf16x8*)(Pw + lr * 64 + ((1 * 4 + lg) ^ (lr & 7)) * 8);
        #pragma unroll
        for (int ht = 0; ht < 4; ++ht) {
            int row = ht * 16 + lr;
            bf16x8 v0f = *(const bf16x8*)(Vl + row * 64 + ((0 * 4 + lg) ^ (lr & 7)) * 8);
            bf16x8 v1f = *(const bf16x8*)(Vl + row * 64 + ((1 * 4 + lg) ^ (lr & 7)) * 8);
            oacc[ht] = MFMA16(pa0, v0f, oacc[ht]);
            oacc[ht] = MFMA16(pa1, v1f, oacc[ht]);
        }
    }

    // epilogue: x2 = O/l + x
    float inv[4];
    #pragma unroll
    for (int r = 0; r < 4; ++r) inv[r] = 1.f / l_[r];
    #pragma unroll
    for (int ht = 0; ht < 4; ++ht) {
        int hd = ht * 16 + lr;
        #pragma unroll
        for (int r = 0; r < 4; ++r) {
            int n = q0 + w * 16 + lg * 4 + r;
            size_t off = ((size_t)b * 64 + hd) * NN + n;
            x2[off] = oacc[ht][r] * inv[r] + x[off];
        }
    }
}

// ---------------- fc1: h1 = gelu(bn1(fc1w @ gn2(x2))) ----------------
// grid dim3(64,B), 256 thr: 64 tokens x 4 groups of 64 outputs
__global__ __launch_bounds__(256) void fc1_kernel(const float* __restrict__ x2,
                                                  const float* __restrict__ fc1w,
                                                  const float* __restrict__ n2g,
                                                  const float* __restrict__ n2b,
                                                  const float* __restrict__ bn1g,
                                                  const float* __restrict__ bn1b,
                                                  const float* __restrict__ stats,
                                                  float* __restrict__ h1) {
    int b = blockIdx.y;
    int tok0 = blockIdx.x * 64;
    int tl = threadIdx.x & 63;
    int og = threadIdx.x >> 6;
    int tok = tok0 + tl;
    float mu = stats[2 * 8 + b];
    float rs = stats[2 * 8 + 4 + b];
    __shared__ float xs[64][64];
    for (int k = 0; k < 16; ++k) {
        int e = threadIdx.x + k * 256;
        xs[e >> 6][e & 63] = x2[((size_t)b * 64 + (e >> 6)) * NN + tok0 + (e & 63)];
    }
    __syncthreads();
    float xc[64];
    #pragma unroll
    for (int c = 0; c < 64; ++c) xc[c] = (xs[c][tl] - mu) * rs * n2g[c] + n2b[c];
    const float sb = rsqrtf(1.f + EPSV);
    float* hp = h1 + (size_t)b * HID * NN + tok;
    for (int oo = 0; oo < 64; oo += 4) {
        int o = og * 64 + oo;
        float a0 = 0.f, a1 = 0.f, a2 = 0.f, a3 = 0.f;
        #pragma unroll
        for (int c = 0; c < 64; ++c) {
            float xv = xc[c];
            a0 += fc1w[o * 64 + c] * xv;
            a1 += fc1w[(o + 1) * 64 + c] * xv;
            a2 += fc1w[(o + 2) * 64 + c] * xv;
            a3 += fc1w[(o + 3) * 64 + c] * xv;
        }
        hp[(size_t)o * NN]       = gelu_exact(a0 * bn1g[o] * sb + bn1b[o]);
        hp[(size_t)(o + 1) * NN] = gelu_exact(a1 * bn1g[o + 1] * sb + bn1b[o + 1]);
        hp[(size_t)(o + 2) * NN] = gelu_exact(a2 * bn1g[o + 2] * sb + bn1b[o + 2]);
        hp[(size_t)(o + 3) * NN] = gelu_exact(a3 * bn1g[o + 3] * sb + bn1b[o + 3]);
    }
}

// ---------------- mixer ----------------
__global__ __launch_bounds__(256) void mixer_kernel(const float* __restrict__ h1,
                                                    const float* __restrict__ dw1w, const float* __restrict__ dw1b,
                                                    const float* __restrict__ dw3w, const float* __restrict__ dw3b,
                                                    const float* __restrict__ dw5w, const float* __restrict__ dw5b,
                                                    const float* __restrict__ dw7w, const float* __restrict__ dw7b,
                                                    const float* __restrict__ fftw,
                                                    const float* __restrict__ bnmg, const float* __restrict__ bnmb,
                                                    float* __restrict__ h2) {
    int i = blockIdx.x * 256 + threadIdx.x;   // 4,194,304
    int x = i & 63;
    int y = (i >> 6) & 63;
    int c = (i >> 12) & 255;
    const float* plane = h1 + ((size_t)(i >> 12) << 12);
    float acc;
    if (c < 64) {
        acc = dw1w[c] * plane[(y << 6) + x] + dw1b[c];
    } else if (c < 128) {
        int lc = c - 64;
        acc = dw3b[lc];
        const float* wp = dw3w + lc * 9;
        #pragma unroll
        for (int dy = 0; dy < 3; ++dy) {
            int yy = y + dy - 1;
            if (yy < 0 || yy >= 64) continue;
            #pragma unroll
            for (int dx = 0; dx < 3; ++dx) {
                int xx = x + dx - 1;
                if (xx < 0 || xx >= 64) continue;
                acc += wp[dy * 3 + dx] * plane[(yy << 6) + xx];
            }
        }
    } else if (c < 192) {
        int lc = c - 128;
        acc = dw5b[lc];
        const float* wp = dw5w + lc * 25;
        #pragma unroll
        for (int dy = 0; dy < 5; ++dy) {
            int yy = y + dy - 2;
            if (yy < 0 || yy >= 64) continue;
            #pragma unroll
            for (int dx = 0; dx < 5; ++dx) {
                int xx = x + dx - 2;
                if (xx < 0 || xx >= 64) continue;
                acc += wp[dy * 5 + dx] * plane[(yy << 6) + xx];
            }
        }
    } else {
        int lc = c - 192;
        acc = dw7b[lc];
        const float* wp = dw7w + lc * 49;
        #pragma unroll
        for (int dy = 0; dy < 7; ++dy) {
            int yy = y + dy - 3;
            if (yy < 0 || yy >= 64) continue;
            #pragma unroll
            for (int dx = 0; dx < 7; ++dx) {
                int xx = x + dx - 3;
                if (xx < 0 || xx >= 64) continue;
                acc += wp[dy * 7 + dx] * plane[(yy << 6) + xx];
            }
        }
    }
    float val = fftw[c] * acc + h1[i];   // FFT w/ real per-channel scalar == scale
    float gg = gelu_exact(val);
    h2[i] = gg * bnmg[c] * rsqrtf(1.f + EPSV) + bnmb[c];
}

// ---------------- fc2 + bn2 + residual ----------------
// grid dim3(64,B), 256 thr: 64 tokens x 4 groups of 16 outputs; h2 tile in LDS
__global__ __launch_bounds__(256) void fc2_kernel(const float* __restrict__ h2,
                                                  const float* __restrict__ fc2w,
                                                  const float* __restrict__ bn2g,
                                                  const float* __restrict__ bn2b,
                                                  const float* __restrict__ x2,
                                                  float* __restrict__ out) {
    int b = blockIdx.y;
    int tok0 = blockIdx.x * 64;
    int tl = threadIdx.x & 63;
    int og = threadIdx.x >> 6;
    int tok = tok0 + tl;
    __shared__ float xs[256][64];
    for (int k = 0; k < 64; ++k) {
        int e = threadIdx.x + k * 256;
        xs[e >> 6][e & 63] = h2[((size_t)b * 256 + (e >> 6)) * NN + tok0 + (e & 63)];
    }
    __syncthreads();
    float acc[16];
    #pragma unroll
    for (int j = 0; j < 16; ++j) acc[j] = 0.f;
    int o0 = og * 16;
    for (int c = 0; c < 256; ++c) {
        float hv = xs[c][tl];
        #pragma unroll
        for (int j = 0; j < 16; ++j) acc[j] += fc2w[(o0 + j) * 256 + c] * hv;
    }
    const float sb = rsqrtf(1.f + EPSV);
    #pragma unroll
    for (int j = 0; j < 16; ++j) {
        int o = o0 + j;
        size_t off = ((size_t)b * 64 + o) * NN + tok;
        out[off] = acc[j] * bn2g[o] * sb + bn2b[o] + x2[off];
    }
}

extern "C" void kernel_launch(void* const* d_in, const int* in_sizes, int n_in,
                              void* d_out, int out_size, void* d_ws, size_t ws_size,
                              hipStream_t stream) {
    const float* x    = (const float*)d_in[0];
    const float* cnn  = (const float*)d_in[1];
    const float* n1g  = (const float*)d_in[2];
    const float* n1b  = (const float*)d_in[3];
    const float* n2g  = (const float*)d_in[4];
    const float* n2b  = (const float*)d_in[5];
    const float* n3g  = (const float*)d_in[6];
    const float* n3b  = (const float*)d_in[7];
    const float* qw   = (const float*)d_in[8];
    const float* qb   = (const float*)d_in[9];
    const float* kvw  = (const float*)d_in[10];
    const float* kvb  = (const float*)d_in[11];
    const float* lcw  = (const float*)d_in[12];
    const float* lcb  = (const float*)d_in[13];
    const float* fc1w = (const float*)d_in[14];
    const float* bn1g = (const float*)d_in[15];
    const float* bn1b = (const float*)d_in[16];
    const float* dw1w = (const float*)d_in[17];
    const float* dw1b = (const float*)d_in[18];
    const float* dw3w = (const float*)d_in[19];
    const float* dw3b = (const float*)d_in[20];
    const float* dw5w = (const float*)d_in[21];
    const float* dw5b = (const float*)d_in[22];
    const float* dw7w = (const float*)d_in[23];
    const float* dw7b = (const float*)d_in[24];
    const float* bnmg = (const float*)d_in[25];
    const float* bnmb = (const float*)d_in[26];
    const float* fftw = (const float*)d_in[27];
    const float* fc2w = (const float*)d_in[28];
    const float* bn2g = (const float*)d_in[29];
    const float* bn2b = (const float*)d_in[30];

    float* ws = (float*)d_ws;
    float* sin_t = ws;                    // 262144
    float* cos_t = ws + 262144;           // 262144
    float* stats = ws + 524288;           // 64
    float* part  = ws + 524352;           // 512
    float* base  = ws + 524864;
    const size_t M = 1048576;
    float* xn    = base;                  // 1M fl
    float* kv_in = base + M;              // 1M
    float* cn    = base + 2 * M;          // 1M
    ushort* qr_bf = (ushort*)(base + 3 * M);            // 1M bf16 = 0.5M fl
    ushort* kr_bf = (ushort*)(base + 3 * M + M / 2);    // 0.5M fl
    ushort* vt_bf = (ushort*)(base + 4 * M);            // 0.5M fl
    float* h1 = base;                     // 4M fl (overlays xn..kr, all dead post-attn)
    float* x2 = base + 9 * M / 2;         // 1M
    float* h2 = base + 11 * M / 2;        // 4M
    float* outp = (float*)d_out;

    rope_kernel<<<1024, 256, 0, stream>>>(sin_t, cos_t);
    stats1_kernel<<<dim3(64, 4), 256, 0, stream>>>(x, part);
    stats2_kernel<<<4, 64, 0, stream>>>(part, stats, 0);
    stats1_kernel<<<dim3(64, 4), 256, 0, stream>>>(cnn, part);
    stats2_kernel<<<4, 64, 0, stream>>>(part, stats, 1);
    gn_apply<<<4096, 256, 0, stream>>>(x, xn, n1g, n1b, stats, 0);
    gn_apply<<<4096, 256, 0, stream>>>(cnn, cn, n3g, n3b, stats, 1);
    dw3_res<<<4096, 256, 0, stream>>>(cn, lcw, lcb, kv_in);
    q_kernel<<<dim3(64, 4), 256, 0, stream>>>(xn, qw, qb, sin_t, cos_t, qr_bf);
    kv_kernel<<<dim3(64, 4), 256, 0, stream>>>(kv_in, kvw, kvb, sin_t, cos_t, kr_bf, vt_bf);
    attn_kernel<<<dim3(64, 4), 256, 0, stream>>>(qr_bf, kr_bf, vt_bf, x, x2);
    stats1_kernel<<<dim3(64, 4), 256, 0, stream>>>(x2, part);
    stats2_kernel<<<4, 64, 0, stream>>>(part, stats, 2);
    fc1_kernel<<<dim3(64, 4), 256, 0, stream>>>(x2, fc1w, n2g, n2b, bn1g, bn1b, stats, h1);
    mixer_kernel<<<16384, 256, 0, stream>>>(h1, dw1w, dw1b, dw3w, dw3b, dw5w, dw5b,
                                            dw7w, dw7b, fftw, bnmg, bnmb, h2);
    fc2_kernel<<<dim3(64, 4), 256, 0, stream>>>(h2, fc2w, bn2g, bn2b, x2, outp);
}

// Round 5
// 316.002 us; speedup vs baseline: 4.6856x; 1.2197x over previous
//
#include <hip/hip_runtime.h>
#include <hip/hip_bf16.h>
#include <math.h>

#define BB 4
#define CC 64
#define HH 64
#define WW 64
#define NN 4096
#define HD 64
#define HID 256
#define EPSV 1e-5f
#define CNT (CC*HH*WW)
#define NCH 4            // KV split chunks

typedef float f32x4 __attribute__((ext_vector_type(4)));
typedef short bf16x8 __attribute__((ext_vector_type(8)));
#define MFMA16(a, b, c) __builtin_amdgcn_mfma_f32_16x16x32_bf16(a, b, c, 0, 0, 0)

__device__ __forceinline__ float gelu_exact(float x) {
    return 0.5f * x * (1.0f + erff(x * 0.70710678118654752f));
}
__device__ __forceinline__ ushort f2bf(float f) {
    unsigned u = __float_as_uint(f);
    unsigned r = (u + 0x7FFFu + ((u >> 16) & 1u)) >> 16;
    return (ushort)r;
}
__device__ __forceinline__ float bf2f(ushort u) {
    return __uint_as_float(((unsigned)u) << 16);
}

// ---------------- RoPE sin/cos tables ----------------
__global__ __launch_bounds__(256) void rope_kernel(float* __restrict__ sin_t, float* __restrict__ cos_t) {
    int i = blockIdx.x * 256 + threadIdx.x;    // NN*HD
    int d = i & 63;
    int n = i >> 6;
    int h = n >> 6, w = n & 63;
    int j = (d & 31) >> 1;
    float freq = exp2f(-0.88584749f * (float)j);   // 10000^{-j/15}
    float pos = (d < 32) ? (float)h : (float)w;
    float val = pos * freq;
    sin_t[i] = __sinf(val);
    cos_t[i] = __cosf(val);
}

// ---------------- stats stage 1 ----------------
__global__ __launch_bounds__(256) void stats1_kernel(const float* __restrict__ src,
                                                     float* __restrict__ part) {
    int b = blockIdx.y;
    int blk = blockIdx.x;
    const float4* p = (const float4*)(src + (size_t)b * CNT);
    float s = 0.f, s2 = 0.f;
    #pragma unroll
    for (int k = 0; k < 4; ++k) {
        float4 v = p[blk * 1024 + k * 256 + threadIdx.x];
        s  += v.x + v.y + v.z + v.w;
        s2 += v.x * v.x + v.y * v.y + v.z * v.z + v.w * v.w;
    }
    #pragma unroll
    for (int off = 32; off > 0; off >>= 1) {
        s  += __shfl_xor(s, off);
        s2 += __shfl_xor(s2, off);
    }
    __shared__ float shs[4], shs2[4];
    int wid = threadIdx.x >> 6, lane = threadIdx.x & 63;
    if (lane == 0) { shs[wid] = s; shs2[wid] = s2; }
    __syncthreads();
    if (threadIdx.x == 0) {
        part[(b * 64 + blk) * 2]     = shs[0] + shs[1] + shs[2] + shs[3];
        part[(b * 64 + blk) * 2 + 1] = shs2[0] + shs2[1] + shs2[2] + shs2[3];
    }
}

// ---------------- stats stage 2 ----------------
__global__ __launch_bounds__(64) void stats2_kernel(const float* __restrict__ part,
                                                    float* __restrict__ stats, int slot) {
    int b = blockIdx.x;
    int lane = threadIdx.x;
    float s = part[(b * 64 + lane) * 2];
    float s2 = part[(b * 64 + lane) * 2 + 1];
    #pragma unroll
    for (int off = 32; off > 0; off >>= 1) {
        s  += __shfl_xor(s, off);
        s2 += __shfl_xor(s2, off);
    }
    if (lane == 0) {
        float mu = s / (float)CNT;
        float var = s2 / (float)CNT - mu * mu;
        stats[slot * 8 + b] = mu;
        stats[slot * 8 + 4 + b] = rsqrtf(var + EPSV);
    }
}

// ---------------- Q: gn(x) fused + proj + RoPE -> bf16 (B,N,HD) ----------------
__global__ __launch_bounds__(256) void q_kernel(const float* __restrict__ x,
                                                const float* __restrict__ n1g,
                                                const float* __restrict__ n1b,
                                                const float* __restrict__ qw,
                                                const float* __restrict__ qb,
                                                const float* __restrict__ sin_t,
                                                const float* __restrict__ cos_t,
                                                const float* __restrict__ stats,
                                                ushort* __restrict__ qr) {
    int b = blockIdx.y;
    int tok0 = blockIdx.x * 64;
    int tl = threadIdx.x & 63;
    int og = threadIdx.x >> 6;
    int tok = tok0 + tl;
    float mu = stats[0 * 8 + b];
    float rs = stats[0 * 8 + 4 + b];
    __shared__ float xs[64][64];
    for (int k = 0; k < 16; ++k) {
        int e = threadIdx.x + k * 256;
        int c = e >> 6;
        xs[c][e & 63] = (x[((size_t)(b * 64 + c)) * NN + tok0 + (e & 63)] - mu) * rs * n1g[c] + n1b[c];
    }
    __syncthreads();
    float xc[64];
    #pragma unroll
    for (int c = 0; c < 64; ++c) xc[c] = xs[c][tl];
    const float* st = sin_t + tok * 64;
    const float* ct = cos_t + tok * 64;
    ushort* qrow = qr + ((size_t)b * NN + tok) * 64;
    for (int oo = 0; oo < 16; oo += 2) {
        int o = og * 16 + oo;
        float a0 = qb[o], a1 = qb[o + 1];
        #pragma unroll
        for (int c = 0; c < 64; ++c) {
            a0 += qw[o * 64 + c] * xc[c];
            a1 += qw[(o + 1) * 64 + c] * xc[c];
        }
        qrow[o]     = f2bf(a0 * ct[o]     - a1 * st[o]);
        qrow[o + 1] = f2bf(a1 * ct[o + 1] + a0 * st[o + 1]);
    }
}

// ---------------- KV: gn(cnn)+dw3+res fused + proj; K+RoPE (B,N,HD); V^T (B,HD,N) ----------------
__global__ __launch_bounds__(256) void kv_kernel(const float* __restrict__ cnn,
                                                 const float* __restrict__ n3g,
                                                 const float* __restrict__ n3b,
                                                 const float* __restrict__ lcw,
                                                 const float* __restrict__ lcb,
                                                 const float* __restrict__ kvw,
                                                 const float* __restrict__ kvb,
                                                 const float* __restrict__ sin_t,
                                                 const float* __restrict__ cos_t,
                                                 const float* __restrict__ stats,
                                                 ushort* __restrict__ kr,
                                                 ushort* __restrict__ vt) {
    int b = blockIdx.y;
    int y = blockIdx.x;                 // row index; tokens y*64 .. y*64+63
    int tl = threadIdx.x & 63;
    int og = threadIdx.x >> 6;
    int tok = y * 64 + tl;
    float mu = stats[1 * 8 + b];
    float rs = stats[1 * 8 + 4 + b];
    __shared__ float cs[3][64][64];     // gn'd cnn rows y-1,y,y+1  (48 KB)
    __shared__ float kvs[64][64];       // kv_in (16 KB)
    for (int k = 0; k < 48; ++k) {
        int e = threadIdx.x + k * 256;  // < 12288
        int ry = e >> 12;
        int c = (e >> 6) & 63;
        int xx = e & 63;
        int yy = y + ry - 1;
        cs[ry][c][xx] = (yy < 0 || yy > 63) ? 0.f
            : (cnn[((size_t)(b * 64 + c)) * NN + yy * 64 + xx] - mu) * rs * n3g[c] + n3b[c];
    }
    __syncthreads();
    // kv_in = dw3(cs) + cs(center)
    for (int cc = 0; cc < 16; ++cc) {
        int c = og * 16 + cc;
        float acc = lcb[c];
        #pragma unroll
        for (int dy = 0; dy < 3; ++dy) {
            const float* row = cs[dy][c];
            #pragma unroll
            for (int dx = 0; dx < 3; ++dx) {
                int xx = tl + dx - 1;
                if (xx < 0 || xx > 63) continue;
                acc += lcw[c * 9 + dy * 3 + dx] * row[xx];
            }
        }
        kvs[c][tl] = acc + cs[1][c][tl];
    }
    __syncthreads();
    float xc[64];
    #pragma unroll
    for (int c = 0; c < 64; ++c) xc[c] = kvs[c][tl];
    if (og < 2) {
        const float* st = sin_t + tok * 64;
        const float* ct = cos_t + tok * 64;
        ushort* krow = kr + ((size_t)b * NN + tok) * 64;
        for (int oo = 0; oo < 32; oo += 2) {
            int o = og * 32 + oo;
            float a0 = kvb[o], a1 = kvb[o + 1];
            #pragma unroll
            for (int c = 0; c < 64; ++c) {
                a0 += kvw[o * 64 + c] * xc[c];
                a1 += kvw[(o + 1) * 64 + c] * xc[c];
            }
            krow[o]     = f2bf(a0 * ct[o]     - a1 * st[o]);
            krow[o + 1] = f2bf(a1 * ct[o + 1] + a0 * st[o + 1]);
        }
    } else {
        int hd0 = (og - 2) * 32;
        for (int oo = 0; oo < 32; ++oo) {
            int o = 64 + hd0 + oo;
            float a0 = kvb[o];
            #pragma unroll
            for (int c = 0; c < 64; ++c) a0 += kvw[o * 64 + c] * xc[c];
            vt[((size_t)b * 64 + hd0 + oo) * NN + tok] = f2bf(a0);
        }
    }
}

// ---------------- MFMA flash attention, split-KV; partial O/m/l ----------------
// grid dim3(64, B, NCH), 256 thr = 4 waves x 16 q-rows; KV tile 64, chunk = 1024 keys
__global__ __launch_bounds__(256) void attn_kernel(const ushort* __restrict__ qr,
                                                   const ushort* __restrict__ kr,
                                                   const ushort* __restrict__ vt,
                                                   float* __restrict__ Opart,
                                                   float* __restrict__ ml) {
    int b = blockIdx.y;
    int q0 = blockIdx.x * 64;
    int chunk = blockIdx.z;
    int tid = threadIdx.x;
    int w = tid >> 6;
    int lane = tid & 63;
    int lr = lane & 15;
    int lg = lane >> 4;

    __shared__ ushort Kl[64 * 64];
    __shared__ ushort Vl[64 * 64];
    __shared__ ushort Pl[4 * 16 * 64];
    ushort* Pw = Pl + w * 1024;

    bf16x8 qf[2];
    {
        const ushort* qp = qr + ((size_t)b * NN + q0 + w * 16 + lr) * 64;
        qf[0] = *(const bf16x8*)(qp + lg * 8);
        qf[1] = *(const bf16x8*)(qp + 32 + lg * 8);
    }

    f32x4 oacc[4];
    #pragma unroll
    for (int t = 0; t < 4; ++t) oacc[t] = (f32x4){0.f, 0.f, 0.f, 0.f};
    float m_[4], l_[4];
    #pragma unroll
    for (int r = 0; r < 4; ++r) { m_[r] = -INFINITY; l_[r] = 0.f; }

    const size_t kbase = ((size_t)b * NN) * 64;

    for (int t = chunk * 16; t < chunk * 16 + 16; ++t) {
        int k0 = t * 64;
        __syncthreads();
        #pragma unroll
        for (int it = 0; it < 2; ++it) {
            int e = tid + it * 256;
            int row = e >> 3, cib = e & 7;
            int sw = cib ^ (row & 7);
            *(bf16x8*)(Kl + row * 64 + sw * 8) =
                *(const bf16x8*)(kr + kbase + (size_t)(k0 + row) * 64 + cib * 8);
            *(bf16x8*)(Vl + row * 64 + sw * 8) =
                *(const bf16x8*)(vt + ((size_t)b * 64 + row) * NN + k0 + cib * 8);
        }
        __syncthreads();

        f32x4 sacc[4];
        #pragma unroll
        for (int kt = 0; kt < 4; ++kt) {
            int row = kt * 16 + lr;
            bf16x8 k0f = *(const bf16x8*)(Kl + row * 64 + ((0 * 4 + lg) ^ (lr & 7)) * 8);
            bf16x8 k1f = *(const bf16x8*)(Kl + row * 64 + ((1 * 4 + lg) ^ (lr & 7)) * 8);
            f32x4 z = {0.f, 0.f, 0.f, 0.f};
            z = MFMA16(qf[0], k0f, z);
            sacc[kt] = MFMA16(qf[1], k1f, z);
        }

        float mx[4];
        #pragma unroll
        for (int r = 0; r < 4; ++r) {
            float v0 = fmaxf(fmaxf(sacc[0][r], sacc[1][r]), fmaxf(sacc[2][r], sacc[3][r]));
            v0 = fmaxf(v0, __shfl_xor(v0, 1));
            v0 = fmaxf(v0, __shfl_xor(v0, 2));
            v0 = fmaxf(v0, __shfl_xor(v0, 4));
            v0 = fmaxf(v0, __shfl_xor(v0, 8));
            mx[r] = v0 * 0.125f;
        }
        float corr[4], mnew[4], rowsum[4];
        #pragma unroll
        for (int r = 0; r < 4; ++r) {
            mnew[r] = fmaxf(m_[r], mx[r]);
            corr[r] = __expf(m_[r] - mnew[r]);
            rowsum[r] = 0.f;
        }
        #pragma unroll
        for (int kt = 0; kt < 4; ++kt) {
            #pragma unroll
            for (int r = 0; r < 4; ++r) {
                int R = lg * 4 + r;
                float pv = __expf(sacc[kt][r] * 0.125f - mnew[r]);
                rowsum[r] += pv;
                Pw[R * 64 + ((kt * 2 + (lr >> 3)) ^ (R & 7)) * 8 + (lr & 7)] = f2bf(pv);
            }
        }
        #pragma unroll
        for (int r = 0; r < 4; ++r) {
            float s = rowsum[r];
            s += __shfl_xor(s, 1);
            s += __shfl_xor(s, 2);
            s += __shfl_xor(s, 4);
            s += __shfl_xor(s, 8);
            l_[r] = l_[r] * corr[r] + s;
            m_[r] = mnew[r];
        }
        #pragma unroll
        for (int ht = 0; ht < 4; ++ht)
            #pragma unroll
            for (int r = 0; r < 4; ++r) oacc[ht][r] *= corr[r];

        bf16x8 pa0 = *(const bf16x8*)(Pw + lr * 64 + ((0 * 4 + lg) ^ (lr & 7)) * 8);
        bf16x8 pa1 = *(const bf16x8*)(Pw + lr * 64 + ((1 * 4 + lg) ^ (lr & 7)) * 8);
        #pragma unroll
        for (int ht = 0; ht < 4; ++ht) {
            int row = ht * 16 + lr;
            bf16x8 v0f = *(const bf16x8*)(Vl + row * 64 + ((0 * 4 + lg) ^ (lr & 7)) * 8);
            bf16x8 v1f = *(const bf16x8*)(Vl + row * 64 + ((1 * 4 + lg) ^ (lr & 7)) * 8);
            oacc[ht] = MFMA16(pa0, v0f, oacc[ht]);
            oacc[ht] = MFMA16(pa1, v1f, oacc[ht]);
        }
    }

    // write unnormalized partial O (layout [chunk][b][hd][n]) and m,l ([b][n][chunk][2])
    #pragma unroll
    for (int ht = 0; ht < 4; ++ht) {
        int hd = ht * 16 + lr;
        *(f32x4*)&Opart[(((size_t)chunk * BB + b) * 64 + hd) * NN + q0 + w * 16 + lg * 4] = oacc[ht];
    }
    if (lr == 0) {
        #pragma unroll
        for (int r = 0; r < 4; ++r) {
            int n = q0 + w * 16 + lg * 4 + r;
            ml[((size_t)b * NN + n) * 8 + chunk * 2]     = m_[r];
            ml[((size_t)b * NN + n) * 8 + chunk * 2 + 1] = l_[r];
        }
    }
}

// ---------------- combine: x2 = sum_c O_c * e^{m_c-M} / L + x ----------------
__global__ __launch_bounds__(256) void combine_kernel(const float* __restrict__ Opart,
                                                      const float* __restrict__ ml,
                                                      const float* __restrict__ x,
                                                      float* __restrict__ x2) {
    int i = blockIdx.x * 256 + threadIdx.x;   // B*64*(NN/4) = 262144
    int n4 = i & 1023;
    int hd = (i >> 10) & 63;
    int b = i >> 16;
    int n0 = n4 << 2;
    float wgt[4][4];   // [tok][chunk]
    const float* mlp = ml + ((size_t)b * NN + n0) * 8;
    #pragma unroll
    for (int tk = 0; tk < 4; ++tk) {
        float m0 = mlp[tk * 8 + 0], l0 = mlp[tk * 8 + 1];
        float m1 = mlp[tk * 8 + 2], l1 = mlp[tk * 8 + 3];
        float m2 = mlp[tk * 8 + 4], l2 = mlp[tk * 8 + 5];
        float m3 = mlp[tk * 8 + 6], l3 = mlp[tk * 8 + 7];
        float M = fmaxf(fmaxf(m0, m1), fmaxf(m2, m3));
        float w0 = __expf(m0 - M), w1 = __expf(m1 - M);
        float w2 = __expf(m2 - M), w3 = __expf(m3 - M);
        float inv = 1.f / (l0 * w0 + l1 * w1 + l2 * w2 + l3 * w3);
        wgt[tk][0] = w0 * inv; wgt[tk][1] = w1 * inv;
        wgt[tk][2] = w2 * inv; wgt[tk][3] = w3 * inv;
    }
    float4 acc = {0.f, 0.f, 0.f, 0.f};
    #pragma unroll
    for (int c = 0; c < 4; ++c) {
        float4 o = *(const float4*)&Opart[(((size_t)c * BB + b) * 64 + hd) * NN + n0];
        acc.x += o.x * wgt[0][c];
        acc.y += o.y * wgt[1][c];
        acc.z += o.z * wgt[2][c];
        acc.w += o.w * wgt[3][c];
    }
    size_t off = ((size_t)b * 64 + hd) * NN + n0;
    float4 xv = *(const float4*)&x[off];
    acc.x += xv.x; acc.y += xv.y; acc.z += xv.z; acc.w += xv.w;
    *(float4*)&x2[off] = acc;
}

// ---------------- fc1: h1 = gelu(bn1(fc1w @ gn2(x2))) -> bf16 ----------------
__global__ __launch_bounds__(256) void fc1_kernel(const float* __restrict__ x2,
                                                  const float* __restrict__ fc1w,
                                                  const float* __restrict__ n2g,
                                                  const float* __restrict__ n2b,
                                                  const float* __restrict__ bn1g,
                                                  const float* __restrict__ bn1b,
                                                  const float* __restrict__ stats,
                                                  ushort* __restrict__ h1) {
    int b = blockIdx.y;
    int tok0 = blockIdx.x * 64;
    int tl = threadIdx.x & 63;
    int og = threadIdx.x >> 6;
    int tok = tok0 + tl;
    float mu = stats[2 * 8 + b];
    float rs = stats[2 * 8 + 4 + b];
    __shared__ float xs[64][64];
    for (int k = 0; k < 16; ++k) {
        int e = threadIdx.x + k * 256;
        xs[e >> 6][e & 63] = x2[((size_t)(b * 64 + (e >> 6))) * NN + tok0 + (e & 63)];
    }
    __syncthreads();
    float xc[64];
    #pragma unroll
    for (int c = 0; c < 64; ++c) xc[c] = (xs[c][tl] - mu) * rs * n2g[c] + n2b[c];
    const float sb = rsqrtf(1.f + EPSV);
    ushort* hp = h1 + (size_t)b * HID * NN + tok;
    for (int oo = 0; oo < 64; oo += 4) {
        int o = og * 64 + oo;
        float a0 = 0.f, a1 = 0.f, a2 = 0.f, a3 = 0.f;
        #pragma unroll
        for (int c = 0; c < 64; ++c) {
            float xv = xc[c];
            a0 += fc1w[o * 64 + c] * xv;
            a1 += fc1w[(o + 1) * 64 + c] * xv;
            a2 += fc1w[(o + 2) * 64 + c] * xv;
            a3 += fc1w[(o + 3) * 64 + c] * xv;
        }
        hp[(size_t)o * NN]       = f2bf(gelu_exact(a0 * bn1g[o] * sb + bn1b[o]));
        hp[(size_t)(o + 1) * NN] = f2bf(gelu_exact(a1 * bn1g[o + 1] * sb + bn1b[o + 1]));
        hp[(size_t)(o + 2) * NN] = f2bf(gelu_exact(a2 * bn1g[o + 2] * sb + bn1b[o + 2]));
        hp[(size_t)(o + 3) * NN] = f2bf(gelu_exact(a3 * bn1g[o + 3] * sb + bn1b[o + 3]));
    }
}

// ---------------- mixer: dw(1/3/5/7) + fft-scale + residual + gelu + bnm (bf16 io) ----------------
__global__ __launch_bounds__(256) void mixer_kernel(const ushort* __restrict__ h1,
                                                    const float* __restrict__ dw1w, const float* __restrict__ dw1b,
                                                    const float* __restrict__ dw3w, const float* __restrict__ dw3b,
                                                    const float* __restrict__ dw5w, const float* __restrict__ dw5b,
                                                    const float* __restrict__ dw7w, const float* __restrict__ dw7b,
                                                    const float* __restrict__ fftw,
                                                    const float* __restrict__ bnmg, const float* __restrict__ bnmb,
                                                    ushort* __restrict__ h2) {
    int i = blockIdx.x * 256 + threadIdx.x;   // 4,194,304
    int x = i & 63;
    int y = (i >> 6) & 63;
    int c = (i >> 12) & 255;
    const ushort* plane = h1 + ((size_t)(i >> 12) << 12);
    float acc;
    if (c < 64) {
        acc = dw1w[c] * bf2f(plane[(y << 6) + x]) + dw1b[c];
    } else if (c < 128) {
        int lc = c - 64;
        acc = dw3b[lc];
        const float* wp = dw3w + lc * 9;
        #pragma unroll
        for (int dy = 0; dy < 3; ++dy) {
            int yy = y + dy - 1;
            if (yy < 0 || yy >= 64) continue;
            #pragma unroll
            for (int dx = 0; dx < 3; ++dx) {
                int xx = x + dx - 1;
                if (xx < 0 || xx >= 64) continue;
                acc += wp[dy * 3 + dx] * bf2f(plane[(yy << 6) + xx]);
            }
        }
    } else if (c < 192) {
        int lc = c - 128;
        acc = dw5b[lc];
        const float* wp = dw5w + lc * 25;
        #pragma unroll
        for (int dy = 0; dy < 5; ++dy) {
            int yy = y + dy - 2;
            if (yy < 0 || yy >= 64) continue;
            #pragma unroll
            for (int dx = 0; dx < 5; ++dx) {
                int xx = x + dx - 2;
                if (xx < 0 || xx >= 64) continue;
                acc += wp[dy * 5 + dx] * bf2f(plane[(yy << 6) + xx]);
            }
        }
    } else {
        int lc = c - 192;
        acc = dw7b[lc];
        const float* wp = dw7w + lc * 49;
        #pragma unroll
        for (int dy = 0; dy < 7; ++dy) {
            int yy = y + dy - 3;
            if (yy < 0 || yy >= 64) continue;
            #pragma unroll
            for (int dx = 0; dx < 7; ++dx) {
                int xx = x + dx - 3;
                if (xx < 0 || xx >= 64) continue;
                acc += wp[dy * 7 + dx] * bf2f(plane[(yy << 6) + xx]);
            }
        }
    }
    float val = fftw[c] * acc + bf2f(h1[i]);   // FFT w/ real per-channel scalar == scale
    float gg = gelu_exact(val);
    h2[i] = f2bf(gg * bnmg[c] * rsqrtf(1.f + EPSV) + bnmb[c]);
}

// ---------------- fc2 + bn2 + residual ----------------
__global__ __launch_bounds__(256) void fc2_kernel(const ushort* __restrict__ h2,
                                                  const float* __restrict__ fc2w,
                                                  const float* __restrict__ bn2g,
                                                  const float* __restrict__ bn2b,
                                                  const float* __restrict__ x2,
                                                  float* __restrict__ out) {
    int b = blockIdx.y;
    int tok0 = blockIdx.x * 64;
    int tl = threadIdx.x & 63;
    int og = threadIdx.x >> 6;
    int tok = tok0 + tl;
    __shared__ ushort xs[256][64];
    for (int k = 0; k < 32; ++k) {
        int e = threadIdx.x + k * 256;   // 8192 ushort2 loads
        int c = e >> 5;
        int p2 = e & 31;
        *(ushort2*)&xs[c][p2 * 2] =
            *(const ushort2*)&h2[((size_t)(b * 256 + c)) * NN + tok0 + p2 * 2];
    }
    __syncthreads();
    float acc[16];
    #pragma unroll
    for (int j = 0; j < 16; ++j) acc[j] = 0.f;
    int o0 = og * 16;
    for (int c = 0; c < 256; ++c) {
        float hv = bf2f(xs[c][tl]);
        #pragma unroll
        for (int j = 0; j < 16; ++j) acc[j] += fc2w[(o0 + j) * 256 + c] * hv;
    }
    const float sb = rsqrtf(1.f + EPSV);
    #pragma unroll
    for (int j = 0; j < 16; ++j) {
        int o = o0 + j;
        size_t off = ((size_t)b * 64 + o) * NN + tok;
        out[off] = acc[j] * bn2g[o] * sb + bn2b[o] + x2[off];
    }
}

extern "C" void kernel_launch(void* const* d_in, const int* in_sizes, int n_in,
                              void* d_out, int out_size, void* d_ws, size_t ws_size,
                              hipStream_t stream) {
    const float* x    = (const float*)d_in[0];
    const float* cnn  = (const float*)d_in[1];
    const float* n1g  = (const float*)d_in[2];
    const float* n1b  = (const float*)d_in[3];
    const float* n2g  = (const float*)d_in[4];
    const float* n2b  = (const float*)d_in[5];
    const float* n3g  = (const float*)d_in[6];
    const float* n3b  = (const float*)d_in[7];
    const float* qw   = (const float*)d_in[8];
    const float* qb   = (const float*)d_in[9];
    const float* kvw  = (const float*)d_in[10];
    const float* kvb  = (const float*)d_in[11];
    const float* lcw  = (const float*)d_in[12];
    const float* lcb  = (const float*)d_in[13];
    const float* fc1w = (const float*)d_in[14];
    const float* bn1g = (const float*)d_in[15];
    const float* bn1b = (const float*)d_in[16];
    const float* dw1w = (const float*)d_in[17];
    const float* dw1b = (const float*)d_in[18];
    const float* dw3w = (const float*)d_in[19];
    const float* dw3b = (const float*)d_in[20];
    const float* dw5w = (const float*)d_in[21];
    const float* dw5b = (const float*)d_in[22];
    const float* dw7w = (const float*)d_in[23];
    const float* dw7b = (const float*)d_in[24];
    const float* bnmg = (const float*)d_in[25];
    const float* bnmb = (const float*)d_in[26];
    const float* fftw = (const float*)d_in[27];
    const float* fc2w = (const float*)d_in[28];
    const float* bn2g = (const float*)d_in[29];
    const float* bn2b = (const float*)d_in[30];

    float* ws = (float*)d_ws;
    float* sin_t = ws;                     // 262144
    float* cos_t = ws + 262144;            // 262144
    float* stats = ws + 524288;            // 64
    float* part  = ws + 524352;            // 512
    float* base  = ws + 524864;
    const size_t M = 1048576;
    float* x2     = base;                  // [0, 1M)
    ushort* qr_bf = (ushort*)(base + M);               // [1M, 1.5M)
    ushort* kr_bf = (ushort*)(base + M + M / 2);       // [1.5M, 2M)
    ushort* vt_bf = (ushort*)(base + 2 * M);           // [2M, 2.5M)
    float* Opart  = base + 5 * M / 2;      // [2.5M, 6.5M)  4*4*64*4096 floats
    float* ml     = base + 5 * M / 2 + 4 * M;          // [6.5M, 6.625M)
    ushort* h1 = (ushort*)(base + M);      // overlays qr/kr/vt/Opart-head (dead post-combine)
    ushort* h2 = (ushort*)(base + 3 * M);  // [3M, 5M) overlays Opart mid (dead)
    float* outp = (float*)d_out;

    rope_kernel<<<1024, 256, 0, stream>>>(sin_t, cos_t);
    stats1_kernel<<<dim3(64, 4), 256, 0, stream>>>(x, part);
    stats2_kernel<<<4, 64, 0, stream>>>(part, stats, 0);
    stats1_kernel<<<dim3(64, 4), 256, 0, stream>>>(cnn, part);
    stats2_kernel<<<4, 64, 0, stream>>>(part, stats, 1);
    q_kernel<<<dim3(64, 4), 256, 0, stream>>>(x, n1g, n1b, qw, qb, sin_t, cos_t, stats, qr_bf);
    kv_kernel<<<dim3(64, 4), 256, 0, stream>>>(cnn, n3g, n3b, lcw, lcb, kvw, kvb,
                                               sin_t, cos_t, stats, kr_bf, vt_bf);
    attn_kernel<<<dim3(64, 4, NCH), 256, 0, stream>>>(qr_bf, kr_bf, vt_bf, Opart, ml);
    combine_kernel<<<1024, 256, 0, stream>>>(Opart, ml, x, x2);
    stats1_kernel<<<dim3(64, 4), 256, 0, stream>>>(x2, part);
    stats2_kernel<<<4, 64, 0, stream>>>(part, stats, 2);
    fc1_kernel<<<dim3(64, 4), 256, 0, stream>>>(x2, fc1w, n2g, n2b, bn1g, bn1b, stats, h1);
    mixer_kernel<<<16384, 256, 0, stream>>>(h1, dw1w, dw1b, dw3w, dw3b, dw5w, dw5b,
                                            dw7w, dw7b, fftw, bnmg, bnmb, h2);
    fc2_kernel<<<dim3(64, 4), 256, 0, stream>>>(h2, fc2w, bn2g, bn2b, x2, outp);
}

// Round 6
// 278.600 us; speedup vs baseline: 5.3147x; 1.1342x over previous
//
#include <hip/hip_runtime.h>
#include <hip/hip_bf16.h>
#include <math.h>

#define BB 4
#define CC 64
#define NN 4096
#define HD 64
#define HID 256
#define EPSV 1e-5f
#define CNT (CC*NN)
#define NCH 8            // KV split chunks

typedef float f32x4 __attribute__((ext_vector_type(4)));
typedef short bf16x8 __attribute__((ext_vector_type(8)));
#define MFMA16(a, b, c) __builtin_amdgcn_mfma_f32_16x16x32_bf16(a, b, c, 0, 0, 0)

__device__ __forceinline__ float gelu_exact(float x) {
    return 0.5f * x * (1.0f + erff(x * 0.70710678118654752f));
}
__device__ __forceinline__ ushort f2bf(float f) {
    unsigned u = __float_as_uint(f);
    unsigned r = (u + 0x7FFFu + ((u >> 16) & 1u)) >> 16;
    return (ushort)r;
}
__device__ __forceinline__ float bf2f(ushort u) {
    return __uint_as_float(((unsigned)u) << 16);
}

// ---------------- RoPE sin/cos tables ----------------
__global__ __launch_bounds__(256) void rope_kernel(float* __restrict__ sin_t, float* __restrict__ cos_t) {
    int i = blockIdx.x * 256 + threadIdx.x;    // NN*HD
    int d = i & 63;
    int n = i >> 6;
    int h = n >> 6, w = n & 63;
    int j = (d & 31) >> 1;
    float freq = exp2f(-0.88584749f * (float)j);   // 10000^{-j/15}
    float pos = (d < 32) ? (float)h : (float)w;
    float val = pos * freq;
    sin_t[i] = __sinf(val);
    cos_t[i] = __cosf(val);
}

// ---------------- stats stage 1 ----------------
__global__ __launch_bounds__(256) void stats1_kernel(const float* __restrict__ src,
                                                     float* __restrict__ part) {
    int b = blockIdx.y;
    int blk = blockIdx.x;
    const float4* p = (const float4*)(src + (size_t)b * CNT);
    float s = 0.f, s2 = 0.f;
    #pragma unroll
    for (int k = 0; k < 4; ++k) {
        float4 v = p[blk * 1024 + k * 256 + threadIdx.x];
        s  += v.x + v.y + v.z + v.w;
        s2 += v.x * v.x + v.y * v.y + v.z * v.z + v.w * v.w;
    }
    #pragma unroll
    for (int off = 32; off > 0; off >>= 1) {
        s  += __shfl_xor(s, off);
        s2 += __shfl_xor(s2, off);
    }
    __shared__ float shs[4], shs2[4];
    int wid = threadIdx.x >> 6, lane = threadIdx.x & 63;
    if (lane == 0) { shs[wid] = s; shs2[wid] = s2; }
    __syncthreads();
    if (threadIdx.x == 0) {
        part[(b * 64 + blk) * 2]     = shs[0] + shs[1] + shs[2] + shs[3];
        part[(b * 64 + blk) * 2 + 1] = shs2[0] + shs2[1] + shs2[2] + shs2[3];
    }
}

// ---------------- stats stage 2 (64 partials) ----------------
__global__ __launch_bounds__(64) void stats2_kernel(const float* __restrict__ part,
                                                    float* __restrict__ stats, int slot) {
    int b = blockIdx.x;
    int lane = threadIdx.x;
    float s = part[(b * 64 + lane) * 2];
    float s2 = part[(b * 64 + lane) * 2 + 1];
    #pragma unroll
    for (int off = 32; off > 0; off >>= 1) {
        s  += __shfl_xor(s, off);
        s2 += __shfl_xor(s2, off);
    }
    if (lane == 0) {
        float mu = s / (float)CNT;
        float var = s2 / (float)CNT - mu * mu;
        stats[slot * 8 + b] = mu;
        stats[slot * 8 + 4 + b] = rsqrtf(var + EPSV);
    }
}

// ---------------- stats stage 2b (256 partials) ----------------
__global__ __launch_bounds__(256) void stats2b_kernel(const float* __restrict__ part2,
                                                      float* __restrict__ stats, int slot) {
    int b = blockIdx.x;
    int t = threadIdx.x;
    float s = part2[(b * 256 + t) * 2];
    float s2 = part2[(b * 256 + t) * 2 + 1];
    #pragma unroll
    for (int off = 32; off > 0; off >>= 1) {
        s  += __shfl_xor(s, off);
        s2 += __shfl_xor(s2, off);
    }
    __shared__ float shs[4], shs2[4];
    int wid = t >> 6, lane = t & 63;
    if (lane == 0) { shs[wid] = s; shs2[wid] = s2; }
    __syncthreads();
    if (t == 0) {
        float S = shs[0] + shs[1] + shs[2] + shs[3];
        float S2 = shs2[0] + shs2[1] + shs2[2] + shs2[3];
        float mu = S / (float)CNT;
        float var = S2 / (float)CNT - mu * mu;
        stats[slot * 8 + b] = mu;
        stats[slot * 8 + 4 + b] = rsqrtf(var + EPSV);
    }
}

// ---------------- dw3k: kvin = dw3(gn(cnn)) + bias + gn(cnn) ----------------
__global__ __launch_bounds__(256) void dw3k_kernel(const float* __restrict__ cnn,
                                                   const float* __restrict__ n3g,
                                                   const float* __restrict__ n3b,
                                                   const float* __restrict__ lcw,
                                                   const float* __restrict__ lcb,
                                                   const float* __restrict__ stats,
                                                   float* __restrict__ kvin) {
    int i = blockIdx.x * 256 + threadIdx.x;   // 1,048,576
    int x = i & 63;
    int y = (i >> 6) & 63;
    int c = (i >> 12) & 63;
    int b = i >> 18;
    float mu = stats[1 * 8 + b];
    float rs = stats[1 * 8 + 4 + b];
    float sc = rs * n3g[c];
    float of = n3b[c] - mu * sc;
    const float* plane = cnn + ((size_t)(i >> 12) << 12);
    float acc = lcb[c];
    #pragma unroll
    for (int dy = 0; dy < 3; ++dy) {
        int yy = y + dy - 1;
        if (yy < 0 || yy >= 64) continue;
        #pragma unroll
        for (int dx = 0; dx < 3; ++dx) {
            int xx = x + dx - 1;
            if (xx < 0 || xx >= 64) continue;
            acc += lcw[c * 9 + dy * 3 + dx] * (plane[(yy << 6) + xx] * sc + of);
        }
    }
    kvin[i] = acc + plane[(y << 6) + x] * sc + of;
}

// ---------------- Q: gn(x) + proj + RoPE -> bf16 (B,N,HD) ----------------
// grid dim3(128, B): tokblk = bx>>1 (64 tok), half = bx&1 -> outputs half*32 + og*8
__global__ __launch_bounds__(256) void q_kernel(const float* __restrict__ x,
                                                const float* __restrict__ n1g,
                                                const float* __restrict__ n1b,
                                                const float* __restrict__ qw,
                                                const float* __restrict__ qb,
                                                const float* __restrict__ sin_t,
                                                const float* __restrict__ cos_t,
                                                const float* __restrict__ stats,
                                                ushort* __restrict__ qr) {
    int b = blockIdx.y;
    int tok0 = (blockIdx.x >> 1) * 64;
    int obase = (blockIdx.x & 1) * 32 + (threadIdx.x >> 6) * 8;
    int tl = threadIdx.x & 63;
    int tok = tok0 + tl;
    float mu = stats[0 * 8 + b];
    float rs = stats[0 * 8 + 4 + b];
    __shared__ float xs[64][64];
    for (int k = 0; k < 16; ++k) {
        int e = threadIdx.x + k * 256;
        int c = e >> 6;
        xs[c][e & 63] = (x[((size_t)(b * 64 + c)) * NN + tok0 + (e & 63)] - mu) * rs * n1g[c] + n1b[c];
    }
    __syncthreads();
    float xc[64];
    #pragma unroll
    for (int c = 0; c < 64; ++c) xc[c] = xs[c][tl];
    const float* st = sin_t + tok * 64;
    const float* ct = cos_t + tok * 64;
    ushort* qrow = qr + ((size_t)b * NN + tok) * 64;
    #pragma unroll
    for (int oo = 0; oo < 8; oo += 2) {
        int o = obase + oo;
        float a0 = qb[o], a1 = qb[o + 1];
        #pragma unroll
        for (int c = 0; c < 64; ++c) {
            a0 += qw[o * 64 + c] * xc[c];
            a1 += qw[(o + 1) * 64 + c] * xc[c];
        }
        qrow[o]     = f2bf(a0 * ct[o]     - a1 * st[o]);
        qrow[o + 1] = f2bf(a1 * ct[o + 1] + a0 * st[o + 1]);
    }
}

// ---------------- KV proj from kvin; K+RoPE (B,N,HD); V^T (B,HD,N) ----------------
// grid dim3(256, B): tokblk = bx>>2, slice = bx&3 -> outputs slice*32 + og*8
__global__ __launch_bounds__(256) void kv_kernel(const float* __restrict__ kvin,
                                                 const float* __restrict__ kvw,
                                                 const float* __restrict__ kvb,
                                                 const float* __restrict__ sin_t,
                                                 const float* __restrict__ cos_t,
                                                 ushort* __restrict__ kr,
                                                 ushort* __restrict__ vt) {
    int b = blockIdx.y;
    int tok0 = (blockIdx.x >> 2) * 64;
    int obase = (blockIdx.x & 3) * 32 + (threadIdx.x >> 6) * 8;
    int tl = threadIdx.x & 63;
    int tok = tok0 + tl;
    __shared__ float xs[64][64];
    for (int k = 0; k < 16; ++k) {
        int e = threadIdx.x + k * 256;
        xs[e >> 6][e & 63] = kvin[((size_t)(b * 64 + (e >> 6))) * NN + tok0 + (e & 63)];
    }
    __syncthreads();
    float xc[64];
    #pragma unroll
    for (int c = 0; c < 64; ++c) xc[c] = xs[c][tl];
    if (obase < 64) {
        const float* st = sin_t + tok * 64;
        const float* ct = cos_t + tok * 64;
        ushort* krow = kr + ((size_t)b * NN + tok) * 64;
        #pragma unroll
        for (int oo = 0; oo < 8; oo += 2) {
            int o = obase + oo;
            float a0 = kvb[o], a1 = kvb[o + 1];
            #pragma unroll
            for (int c = 0; c < 64; ++c) {
                a0 += kvw[o * 64 + c] * xc[c];
                a1 += kvw[(o + 1) * 64 + c] * xc[c];
            }
            krow[o]     = f2bf(a0 * ct[o]     - a1 * st[o]);
            krow[o + 1] = f2bf(a1 * ct[o + 1] + a0 * st[o + 1]);
        }
    } else {
        #pragma unroll
        for (int oo = 0; oo < 8; ++oo) {
            int o = obase + 64 + oo - 64;   // o in [64,128)
            int oa = obase + oo;            // absolute kv output
            float a0 = kvb[oa];
            #pragma unroll
            for (int c = 0; c < 64; ++c) a0 += kvw[oa * 64 + c] * xc[c];
            vt[((size_t)b * 64 + (oa - 64)) * NN + tok] = f2bf(a0);
        }
    }
}

// ---------------- MFMA flash attention, split-KV (NCH=8), base-2 softmax, defer-max ----------------
// grid dim3(64, B, NCH), 256 thr = 4 waves x 16 q-rows; KV tile 64; chunk = 512 keys
__global__ __launch_bounds__(256) void attn_kernel(const ushort* __restrict__ qr,
                                                   const ushort* __restrict__ kr,
                                                   const ushort* __restrict__ vt,
                                                   ushort* __restrict__ Opart,
                                                   float* __restrict__ ml) {
    int b = blockIdx.y;
    int q0 = blockIdx.x * 64;
    int chunk = blockIdx.z;
    int tid = threadIdx.x;
    int w = tid >> 6;
    int lane = tid & 63;
    int lr = lane & 15;
    int lg = lane >> 4;
    const float SCL2 = 0.125f * 1.44269504f;   // HD^-0.5 * log2(e)

    __shared__ ushort Kl[64 * 64];
    __shared__ ushort Vl[64 * 64];
    __shared__ ushort Pl[4 * 16 * 64];
    ushort* Pw = Pl + w * 1024;

    bf16x8 qf[2];
    {
        const ushort* qp = qr + ((size_t)b * NN + q0 + w * 16 + lr) * 64;
        qf[0] = *(const bf16x8*)(qp + lg * 8);
        qf[1] = *(const bf16x8*)(qp + 32 + lg * 8);
    }

    f32x4 oacc[4];
    #pragma unroll
    for (int t = 0; t < 4; ++t) oacc[t] = (f32x4){0.f, 0.f, 0.f, 0.f};
    float m_[4], l_[4];
    #pragma unroll
    for (int r = 0; r < 4; ++r) { m_[r] = -INFINITY; l_[r] = 0.f; }

    const size_t kbase = ((size_t)b * NN) * 64;

    for (int t = chunk * 8; t < chunk * 8 + 8; ++t) {
        int k0 = t * 64;
        __syncthreads();
        #pragma unroll
        for (int it = 0; it < 2; ++it) {
            int e = tid + it * 256;
            int row = e >> 3, cib = e & 7;
            int sw = cib ^ (row & 7);
            *(bf16x8*)(Kl + row * 64 + sw * 8) =
                *(const bf16x8*)(kr + kbase + (size_t)(k0 + row) * 64 + cib * 8);
            *(bf16x8*)(Vl + row * 64 + sw * 8) =
                *(const bf16x8*)(vt + ((size_t)b * 64 + row) * NN + k0 + cib * 8);
        }
        __syncthreads();

        f32x4 sacc[4];
        #pragma unroll
        for (int kt = 0; kt < 4; ++kt) {
            int row = kt * 16 + lr;
            bf16x8 k0f = *(const bf16x8*)(Kl + row * 64 + ((0 * 4 + lg) ^ (lr & 7)) * 8);
            bf16x8 k1f = *(const bf16x8*)(Kl + row * 64 + ((1 * 4 + lg) ^ (lr & 7)) * 8);
            f32x4 z = {0.f, 0.f, 0.f, 0.f};
            z = MFMA16(qf[0], k0f, z);
            sacc[kt] = MFMA16(qf[1], k1f, z);
        }

        // tile max (base-2 units)
        float mx[4];
        float need = 0.f;
        #pragma unroll
        for (int r = 0; r < 4; ++r) {
            float v0 = fmaxf(fmaxf(sacc[0][r], sacc[1][r]), fmaxf(sacc[2][r], sacc[3][r]));
            v0 = fmaxf(v0, __shfl_xor(v0, 1));
            v0 = fmaxf(v0, __shfl_xor(v0, 2));
            v0 = fmaxf(v0, __shfl_xor(v0, 4));
            v0 = fmaxf(v0, __shfl_xor(v0, 8));
            mx[r] = v0 * SCL2;
            need = fmaxf(need, mx[r] - m_[r]);
        }
        if (__any(need > 8.f)) {       // defer-max: rescale only on real growth
            float cr[4];
            #pragma unroll
            for (int r = 0; r < 4; ++r) {
                float mn = fmaxf(m_[r], mx[r]);
                cr[r] = exp2f(m_[r] - mn);
                l_[r] *= cr[r];
                m_[r] = mn;
            }
            #pragma unroll
            for (int ht = 0; ht < 4; ++ht)
                #pragma unroll
                for (int r = 0; r < 4; ++r) oacc[ht][r] *= cr[r];
        }
        float rowsum[4];
        #pragma unroll
        for (int r = 0; r < 4; ++r) rowsum[r] = 0.f;
        #pragma unroll
        for (int kt = 0; kt < 4; ++kt) {
            #pragma unroll
            for (int r = 0; r < 4; ++r) {
                int R = lg * 4 + r;
                float pv = exp2f(sacc[kt][r] * SCL2 - m_[r]);
                rowsum[r] += pv;
                Pw[R * 64 + ((kt * 2 + (lr >> 3)) ^ (R & 7)) * 8 + (lr & 7)] = f2bf(pv);
            }
        }
        #pragma unroll
        for (int r = 0; r < 4; ++r) {
            float s = rowsum[r];
            s += __shfl_xor(s, 1);
            s += __shfl_xor(s, 2);
            s += __shfl_xor(s, 4);
            s += __shfl_xor(s, 8);
            l_[r] += s;
        }

        bf16x8 pa0 = *(const bf16x8*)(Pw + lr * 64 + ((0 * 4 + lg) ^ (lr & 7)) * 8);
        bf16x8 pa1 = *(const bf16x8*)(Pw + lr * 64 + ((1 * 4 + lg) ^ (lr & 7)) * 8);
        #pragma unroll
        for (int ht = 0; ht < 4; ++ht) {
            int row = ht * 16 + lr;
            bf16x8 v0f = *(const bf16x8*)(Vl + row * 64 + ((0 * 4 + lg) ^ (lr & 7)) * 8);
            bf16x8 v1f = *(const bf16x8*)(Vl + row * 64 + ((1 * 4 + lg) ^ (lr & 7)) * 8);
            oacc[ht] = MFMA16(pa0, v0f, oacc[ht]);
            oacc[ht] = MFMA16(pa1, v1f, oacc[ht]);
        }
    }

    int n0 = q0 + w * 16 + lg * 4;
    #pragma unroll
    for (int ht = 0; ht < 4; ++ht) {
        int hd = ht * 16 + lr;
        ushort4 o4;
        o4.x = f2bf(oacc[ht][0]); o4.y = f2bf(oacc[ht][1]);
        o4.z = f2bf(oacc[ht][2]); o4.w = f2bf(oacc[ht][3]);
        *(ushort4*)&Opart[(((size_t)chunk * BB + b) * 64 + hd) * NN + n0] = o4;
    }
    if (lr == 0) {
        #pragma unroll
        for (int r = 0; r < 4; ++r) {
            int n = n0 + r;
            ml[((size_t)b * NN + n) * 16 + chunk * 2]     = m_[r];
            ml[((size_t)b * NN + n) * 16 + chunk * 2 + 1] = l_[r];
        }
    }
}

// ---------------- combine: x2 = sum_c O_c*w_c + x; fused stats partials ----------------
__global__ __launch_bounds__(256) void combine_kernel(const ushort* __restrict__ Opart,
                                                      const float* __restrict__ ml,
                                                      const float* __restrict__ x,
                                                      float* __restrict__ x2,
                                                      float* __restrict__ part2) {
    int i = blockIdx.x * 256 + threadIdx.x;   // 262144
    int n4 = i & 1023;
    int hd = (i >> 10) & 63;
    int b = i >> 16;
    int n0 = n4 << 2;
    float wgt[4][NCH];
    const float* mlp = ml + ((size_t)b * NN + n0) * 16;
    #pragma unroll
    for (int tk = 0; tk < 4; ++tk) {
        float m[NCH], l[NCH];
        const float4* p4 = (const float4*)(mlp + tk * 16);
        #pragma unroll
        for (int q = 0; q < 4; ++q) {
            float4 v = p4[q];
            m[q * 2] = v.x; l[q * 2] = v.y; m[q * 2 + 1] = v.z; l[q * 2 + 1] = v.w;
        }
        float M = m[0];
        #pragma unroll
        for (int c = 1; c < NCH; ++c) M = fmaxf(M, m[c]);
        float e[NCH], L = 0.f;
        #pragma unroll
        for (int c = 0; c < NCH; ++c) { e[c] = exp2f(m[c] - M); L += l[c] * e[c]; }
        float inv = 1.f / L;
        #pragma unroll
        for (int c = 0; c < NCH; ++c) wgt[tk][c] = e[c] * inv;
    }
    float4 acc = {0.f, 0.f, 0.f, 0.f};
    #pragma unroll
    for (int c = 0; c < NCH; ++c) {
        ushort4 o4 = *(const ushort4*)&Opart[(((size_t)c * BB + b) * 64 + hd) * NN + n0];
        acc.x += bf2f(o4.x) * wgt[0][c];
        acc.y += bf2f(o4.y) * wgt[1][c];
        acc.z += bf2f(o4.z) * wgt[2][c];
        acc.w += bf2f(o4.w) * wgt[3][c];
    }
    size_t off = ((size_t)b * 64 + hd) * NN + n0;
    float4 xv = *(const float4*)&x[off];
    acc.x += xv.x; acc.y += xv.y; acc.z += xv.z; acc.w += xv.w;
    *(float4*)&x2[off] = acc;

    // fused stats partials for gn2
    float s = acc.x + acc.y + acc.z + acc.w;
    float s2 = acc.x * acc.x + acc.y * acc.y + acc.z * acc.z + acc.w * acc.w;
    #pragma unroll
    for (int off2 = 32; off2 > 0; off2 >>= 1) {
        s  += __shfl_xor(s, off2);
        s2 += __shfl_xor(s2, off2);
    }
    __shared__ float shs[4], shs2[4];
    int wid = threadIdx.x >> 6, lane = threadIdx.x & 63;
    if (lane == 0) { shs[wid] = s; shs2[wid] = s2; }
    __syncthreads();
    if (threadIdx.x == 0) {
        part2[blockIdx.x * 2]     = shs[0] + shs[1] + shs[2] + shs[3];
        part2[blockIdx.x * 2 + 1] = shs2[0] + shs2[1] + shs2[2] + shs2[3];
    }
}

// ---------------- fc1: h1 = gelu(bn1(fc1w @ gn2(x2))) -> bf16 ----------------
// grid dim3(256, B): tokblk = bx>>2, slice = bx&3 -> outputs slice*64 + og*16
__global__ __launch_bounds__(256) void fc1_kernel(const float* __restrict__ x2,
                                                  const float* __restrict__ fc1w,
                                                  const float* __restrict__ n2g,
                                                  const float* __restrict__ n2b,
                                                  const float* __restrict__ bn1g,
                                                  const float* __restrict__ bn1b,
                                                  const float* __restrict__ stats,
                                                  ushort* __restrict__ h1) {
    int b = blockIdx.y;
    int tok0 = (blockIdx.x >> 2) * 64;
    int o0 = (blockIdx.x & 3) * 64 + (threadIdx.x >> 6) * 16;
    int tl = threadIdx.x & 63;
    int tok = tok0 + tl;
    float mu = stats[2 * 8 + b];
    float rs = stats[2 * 8 + 4 + b];
    __shared__ float xs[64][64];
    for (int k = 0; k < 16; ++k) {
        int e = threadIdx.x + k * 256;
        int c = e >> 6;
        xs[c][e & 63] = (x2[((size_t)(b * 64 + c)) * NN + tok0 + (e & 63)] - mu) * rs * n2g[c] + n2b[c];
    }
    __syncthreads();
    float xc[64];
    #pragma unroll
    for (int c = 0; c < 64; ++c) xc[c] = xs[c][tl];
    const float sb = rsqrtf(1.f + EPSV);
    ushort* hp = h1 + (size_t)b * HID * NN + tok;
    #pragma unroll
    for (int oo = 0; oo < 16; oo += 4) {
        int o = o0 + oo;
        float a0 = 0.f, a1 = 0.f, a2 = 0.f, a3 = 0.f;
        #pragma unroll
        for (int c = 0; c < 64; ++c) {
            float xv = xc[c];
            a0 += fc1w[o * 64 + c] * xv;
            a1 += fc1w[(o + 1) * 64 + c] * xv;
            a2 += fc1w[(o + 2) * 64 + c] * xv;
            a3 += fc1w[(o + 3) * 64 + c] * xv;
        }
        hp[(size_t)o * NN]       = f2bf(gelu_exact(a0 * bn1g[o] * sb + bn1b[o]));
        hp[(size_t)(o + 1) * NN] = f2bf(gelu_exact(a1 * bn1g[o + 1] * sb + bn1b[o + 1]));
        hp[(size_t)(o + 2) * NN] = f2bf(gelu_exact(a2 * bn1g[o + 2] * sb + bn1b[o + 2]));
        hp[(size_t)(o + 3) * NN] = f2bf(gelu_exact(a3 * bn1g[o + 3] * sb + bn1b[o + 3]));
    }
}

// ---------------- mixer: dw(1/3/5/7) + fft-scale + residual + gelu + bnm (bf16 io) ----------------
__global__ __launch_bounds__(256) void mixer_kernel(const ushort* __restrict__ h1,
                                                    const float* __restrict__ dw1w, const float* __restrict__ dw1b,
                                                    const float* __restrict__ dw3w, const float* __restrict__ dw3b,
                                                    const float* __restrict__ dw5w, const float* __restrict__ dw5b,
                                                    const float* __restrict__ dw7w, const float* __restrict__ dw7b,
                                                    const float* __restrict__ fftw,
                                                    const float* __restrict__ bnmg, const float* __restrict__ bnmb,
                                                    ushort* __restrict__ h2) {
    int i = blockIdx.x * 256 + threadIdx.x;   // 4,194,304
    int x = i & 63;
    int y = (i >> 6) & 63;
    int c = (i >> 12) & 255;
    const ushort* plane = h1 + ((size_t)(i >> 12) << 12);
    float acc;
    if (c < 64) {
        acc = dw1w[c] * bf2f(plane[(y << 6) + x]) + dw1b[c];
    } else if (c < 128) {
        int lc = c - 64;
        acc = dw3b[lc];
        const float* wp = dw3w + lc * 9;
        #pragma unroll
        for (int dy = 0; dy < 3; ++dy) {
            int yy = y + dy - 1;
            if (yy < 0 || yy >= 64) continue;
            #pragma unroll
            for (int dx = 0; dx < 3; ++dx) {
                int xx = x + dx - 1;
                if (xx < 0 || xx >= 64) continue;
                acc += wp[dy * 3 + dx] * bf2f(plane[(yy << 6) + xx]);
            }
        }
    } else if (c < 192) {
        int lc = c - 128;
        acc = dw5b[lc];
        const float* wp = dw5w + lc * 25;
        #pragma unroll
        for (int dy = 0; dy < 5; ++dy) {
            int yy = y + dy - 2;
            if (yy < 0 || yy >= 64) continue;
            #pragma unroll
            for (int dx = 0; dx < 5; ++dx) {
                int xx = x + dx - 2;
                if (xx < 0 || xx >= 64) continue;
                acc += wp[dy * 5 + dx] * bf2f(plane[(yy << 6) + xx]);
            }
        }
    } else {
        int lc = c - 192;
        acc = dw7b[lc];
        const float* wp = dw7w + lc * 49;
        #pragma unroll
        for (int dy = 0; dy < 7; ++dy) {
            int yy = y + dy - 3;
            if (yy < 0 || yy >= 64) continue;
            #pragma unroll
            for (int dx = 0; dx < 7; ++dx) {
                int xx = x + dx - 3;
                if (xx < 0 || xx >= 64) continue;
                acc += wp[dy * 7 + dx] * bf2f(plane[(yy << 6) + xx]);
            }
        }
    }
    float val = fftw[c] * acc + bf2f(h1[i]);   // FFT w/ real per-channel scalar == scale
    float gg = gelu_exact(val);
    h2[i] = f2bf(gg * bnmg[c] * rsqrtf(1.f + EPSV) + bnmb[c]);
}

// ---------------- fc2 + bn2 + residual ----------------
// grid dim3(512, B): tokblk = bx>>3 (64 tok), oblk = bx&7; thread: tok=tid&63, o0=oblk*4+og (and o0+32)
__global__ __launch_bounds__(256) void fc2_kernel(const ushort* __restrict__ h2,
                                                  const float* __restrict__ fc2w,
                                                  const float* __restrict__ bn2g,
                                                  const float* __restrict__ bn2b,
                                                  const float* __restrict__ x2,
                                                  float* __restrict__ out) {
    int b = blockIdx.y;
    int tok = (blockIdx.x >> 3) * 64 + (threadIdx.x & 63);
    int o0 = (blockIdx.x & 7) * 4 + (threadIdx.x >> 6);
    int o1 = o0 + 32;
    const ushort* hp = h2 + (size_t)b * HID * NN + tok;
    const float* w0 = fc2w + o0 * 256;
    const float* w1 = fc2w + o1 * 256;
    float acc0 = 0.f, acc1 = 0.f;
    #pragma unroll 8
    for (int c = 0; c < 256; ++c) {
        float hv = bf2f(hp[(size_t)c * NN]);
        acc0 += w0[c] * hv;
        acc1 += w1[c] * hv;
    }
    const float sb = rsqrtf(1.f + EPSV);
    size_t off0 = ((size_t)b * 64 + o0) * NN + tok;
    size_t off1 = ((size_t)b * 64 + o1) * NN + tok;
    out[off0] = acc0 * bn2g[o0] * sb + bn2b[o0] + x2[off0];
    out[off1] = acc1 * bn2g[o1] * sb + bn2b[o1] + x2[off1];
}

extern "C" void kernel_launch(void* const* d_in, const int* in_sizes, int n_in,
                              void* d_out, int out_size, void* d_ws, size_t ws_size,
                              hipStream_t stream) {
    const float* x    = (const float*)d_in[0];
    const float* cnn  = (const float*)d_in[1];
    const float* n1g  = (const float*)d_in[2];
    const float* n1b  = (const float*)d_in[3];
    const float* n2g  = (const float*)d_in[4];
    const float* n2b  = (const float*)d_in[5];
    const float* n3g  = (const float*)d_in[6];
    const float* n3b  = (const float*)d_in[7];
    const float* qw   = (const float*)d_in[8];
    const float* qb   = (const float*)d_in[9];
    const float* kvw  = (const float*)d_in[10];
    const float* kvb  = (const float*)d_in[11];
    const float* lcw  = (const float*)d_in[12];
    const float* lcb  = (const float*)d_in[13];
    const float* fc1w = (const float*)d_in[14];
    const float* bn1g = (const float*)d_in[15];
    const float* bn1b = (const float*)d_in[16];
    const float* dw1w = (const float*)d_in[17];
    const float* dw1b = (const float*)d_in[18];
    const float* dw3w = (const float*)d_in[19];
    const float* dw3b = (const float*)d_in[20];
    const float* dw5w = (const float*)d_in[21];
    const float* dw5b = (const float*)d_in[22];
    const float* dw7w = (const float*)d_in[23];
    const float* dw7b = (const float*)d_in[24];
    const float* bnmg = (const float*)d_in[25];
    const float* bnmb = (const float*)d_in[26];
    const float* fftw = (const float*)d_in[27];
    const float* fc2w = (const float*)d_in[28];
    const float* bn2g = (const float*)d_in[29];
    const float* bn2b = (const float*)d_in[30];

    float* ws = (float*)d_ws;
    float* sin_t = ws;                     // 262144
    float* cos_t = ws + 262144;            // 262144
    float* stats = ws + 524288;            // 64
    float* part  = ws + 524352;            // 512
    float* part2 = ws + 524864;            // 2048
    float* base  = ws + 526912;
    const size_t M = 1048576;
    float* x2     = base;                              // [0, 1M)
    ushort* qr_bf = (ushort*)(base + M);               // [1M, 1.5M)
    ushort* kr_bf = (ushort*)(base + M + M / 2);       // [1.5M, 2M)
    ushort* vt_bf = (ushort*)(base + 2 * M);           // [2M, 2.5M)
    float* kvin   = base + 5 * M / 2;                  // [2.5M, 3.5M)
    ushort* Opart = (ushort*)(base + 7 * M / 2);       // [3.5M, 7.5M)  NCH*B*64*NN bf16
    float* ml     = base + 15 * M / 2;                 // [7.5M, 7.75M)
    ushort* h1 = (ushort*)(base + M);       // overlay qr/kr/vt/kvin (dead post-attn)
    ushort* h2 = (ushort*)(base + 7 * M / 2);          // overlay Opart head (dead post-combine)
    float* outp = (float*)d_out;

    rope_kernel<<<1024, 256, 0, stream>>>(sin_t, cos_t);
    stats1_kernel<<<dim3(64, 4), 256, 0, stream>>>(x, part);
    stats2_kernel<<<4, 64, 0, stream>>>(part, stats, 0);
    stats1_kernel<<<dim3(64, 4), 256, 0, stream>>>(cnn, part);
    stats2_kernel<<<4, 64, 0, stream>>>(part, stats, 1);
    dw3k_kernel<<<4096, 256, 0, stream>>>(cnn, n3g, n3b, lcw, lcb, stats, kvin);
    q_kernel<<<dim3(128, 4), 256, 0, stream>>>(x, n1g, n1b, qw, qb, sin_t, cos_t, stats, qr_bf);
    kv_kernel<<<dim3(256, 4), 256, 0, stream>>>(kvin, kvw, kvb, sin_t, cos_t, kr_bf, vt_bf);
    attn_kernel<<<dim3(64, 4, NCH), 256, 0, stream>>>(qr_bf, kr_bf, vt_bf, Opart, ml);
    combine_kernel<<<1024, 256, 0, stream>>>(Opart, ml, x, x2, part2);
    stats2b_kernel<<<4, 256, 0, stream>>>(part2, stats, 2);
    fc1_kernel<<<dim3(256, 4), 256, 0, stream>>>(x2, fc1w, n2g, n2b, bn1g, bn1b, stats, h1);
    mixer_kernel<<<16384, 256, 0, stream>>>(h1, dw1w, dw1b, dw3w, dw3b, dw5w, dw5b,
                                            dw7w, dw7b, fftw, bnmg, bnmb, h2);
    fc2_kernel<<<dim3(512, 4), 256, 0, stream>>>(h2, fc2w, bn2g, bn2b, x2, outp);
}

// Round 7
// 272.659 us; speedup vs baseline: 5.4305x; 1.0218x over previous
//
#include <hip/hip_runtime.h>
#include <hip/hip_bf16.h>
#include <math.h>

#define BB 4
#define CC 64
#define NN 4096
#define HD 64
#define HID 256
#define EPSV 1e-5f
#define CNT (CC*NN)
#define NCH 8            // KV split chunks

typedef float f32x4 __attribute__((ext_vector_type(4)));
typedef short bf16x8 __attribute__((ext_vector_type(8)));
#define MFMA16(a, b, c) __builtin_amdgcn_mfma_f32_16x16x32_bf16(a, b, c, 0, 0, 0)

__device__ __forceinline__ float gelu_exact(float x) {
    return 0.5f * x * (1.0f + erff(x * 0.70710678118654752f));
}
__device__ __forceinline__ ushort f2bf(float f) {
    unsigned u = __float_as_uint(f);
    unsigned r = (u + 0x7FFFu + ((u >> 16) & 1u)) >> 16;
    return (ushort)r;
}
__device__ __forceinline__ float bf2f(ushort u) {
    return __uint_as_float(((unsigned)u) << 16);
}

// ---------------- fused stats stage 1 for x and cnn ----------------
__global__ __launch_bounds__(256) void stats_pair_kernel(const float* __restrict__ x,
                                                         const float* __restrict__ cnn,
                                                         float* __restrict__ part) {
    int b = blockIdx.y;
    int blk = blockIdx.x;
    const float4* p0 = (const float4*)(x + (size_t)b * CNT);
    const float4* p1 = (const float4*)(cnn + (size_t)b * CNT);
    float s0 = 0.f, s20 = 0.f, s1 = 0.f, s21 = 0.f;
    #pragma unroll
    for (int k = 0; k < 4; ++k) {
        float4 v = p0[blk * 1024 + k * 256 + threadIdx.x];
        s0  += v.x + v.y + v.z + v.w;
        s20 += v.x * v.x + v.y * v.y + v.z * v.z + v.w * v.w;
        float4 u = p1[blk * 1024 + k * 256 + threadIdx.x];
        s1  += u.x + u.y + u.z + u.w;
        s21 += u.x * u.x + u.y * u.y + u.z * u.z + u.w * u.w;
    }
    #pragma unroll
    for (int off = 32; off > 0; off >>= 1) {
        s0  += __shfl_xor(s0, off);
        s20 += __shfl_xor(s20, off);
        s1  += __shfl_xor(s1, off);
        s21 += __shfl_xor(s21, off);
    }
    __shared__ float sh[4][4];
    int wid = threadIdx.x >> 6, lane = threadIdx.x & 63;
    if (lane == 0) { sh[wid][0] = s0; sh[wid][1] = s20; sh[wid][2] = s1; sh[wid][3] = s21; }
    __syncthreads();
    if (threadIdx.x == 0) {
        float a0 = sh[0][0] + sh[1][0] + sh[2][0] + sh[3][0];
        float a1 = sh[0][1] + sh[1][1] + sh[2][1] + sh[3][1];
        float a2 = sh[0][2] + sh[1][2] + sh[2][2] + sh[3][2];
        float a3 = sh[0][3] + sh[1][3] + sh[2][3] + sh[3][3];
        part[((0 * 4 + b) * 64 + blk) * 2]     = a0;
        part[((0 * 4 + b) * 64 + blk) * 2 + 1] = a1;
        part[((1 * 4 + b) * 64 + blk) * 2]     = a2;
        part[((1 * 4 + b) * 64 + blk) * 2 + 1] = a3;
    }
}

// ---------------- stats finalize (both slots) ----------------
__global__ __launch_bounds__(64) void stats_fin_kernel(const float* __restrict__ part,
                                                       float* __restrict__ stats) {
    int sb_ = blockIdx.x;    // slot*4 + b, 8 blocks
    int lane = threadIdx.x;
    float s = part[(sb_ * 64 + lane) * 2];
    float s2 = part[(sb_ * 64 + lane) * 2 + 1];
    #pragma unroll
    for (int off = 32; off > 0; off >>= 1) {
        s  += __shfl_xor(s, off);
        s2 += __shfl_xor(s2, off);
    }
    if (lane == 0) {
        int slot = sb_ >> 2, b = sb_ & 3;
        float mu = s / (float)CNT;
        float var = s2 / (float)CNT - mu * mu;
        stats[slot * 8 + b] = mu;
        stats[slot * 8 + 4 + b] = rsqrtf(var + EPSV);
    }
}

// ---------------- stats stage 2b (256 partials, slot 2) ----------------
__global__ __launch_bounds__(256) void stats2b_kernel(const float* __restrict__ part2,
                                                      float* __restrict__ stats, int slot) {
    int b = blockIdx.x;
    int t = threadIdx.x;
    float s = part2[(b * 256 + t) * 2];
    float s2 = part2[(b * 256 + t) * 2 + 1];
    #pragma unroll
    for (int off = 32; off > 0; off >>= 1) {
        s  += __shfl_xor(s, off);
        s2 += __shfl_xor(s2, off);
    }
    __shared__ float shs[4], shs2[4];
    int wid = t >> 6, lane = t & 63;
    if (lane == 0) { shs[wid] = s; shs2[wid] = s2; }
    __syncthreads();
    if (t == 0) {
        float S = shs[0] + shs[1] + shs[2] + shs[3];
        float S2 = shs2[0] + shs2[1] + shs2[2] + shs2[3];
        float mu = S / (float)CNT;
        float var = S2 / (float)CNT - mu * mu;
        stats[slot * 8 + b] = mu;
        stats[slot * 8 + 4 + b] = rsqrtf(var + EPSV);
    }
}

// ---------------- dw3k: kvin = dw3(gn(cnn)) + bias + gn(cnn) ----------------
__global__ __launch_bounds__(256) void dw3k_kernel(const float* __restrict__ cnn,
                                                   const float* __restrict__ n3g,
                                                   const float* __restrict__ n3b,
                                                   const float* __restrict__ lcw,
                                                   const float* __restrict__ lcb,
                                                   const float* __restrict__ stats,
                                                   float* __restrict__ kvin) {
    int i = blockIdx.x * 256 + threadIdx.x;   // 1,048,576
    int x = i & 63;
    int y = (i >> 6) & 63;
    int c = (i >> 12) & 63;
    int b = i >> 18;
    float mu = stats[1 * 8 + b];
    float rs = stats[1 * 8 + 4 + b];
    float sc = rs * n3g[c];
    float of = n3b[c] - mu * sc;
    const float* plane = cnn + ((size_t)(i >> 12) << 12);
    float acc = lcb[c];
    #pragma unroll
    for (int dy = 0; dy < 3; ++dy) {
        int yy = y + dy - 1;
        if (yy < 0 || yy >= 64) continue;
        #pragma unroll
        for (int dx = 0; dx < 3; ++dx) {
            int xx = x + dx - 1;
            if (xx < 0 || xx >= 64) continue;
            acc += lcw[c * 9 + dy * 3 + dx] * (plane[(yy << 6) + xx] * sc + of);
        }
    }
    kvin[i] = acc + plane[(y << 6) + x] * sc + of;
}

// ---------------- Q: gn(x) + proj + inline RoPE -> bf16 (B,N,HD) ----------------
// grid dim3(128, B): tokblk = bx>>1 (64 tok), half = bx&1 -> outputs half*32 + og*8
__global__ __launch_bounds__(256) void q_kernel(const float* __restrict__ x,
                                                const float* __restrict__ n1g,
                                                const float* __restrict__ n1b,
                                                const float* __restrict__ qw,
                                                const float* __restrict__ qb,
                                                const float* __restrict__ stats,
                                                ushort* __restrict__ qr) {
    int b = blockIdx.y;
    int tok0 = (blockIdx.x >> 1) * 64;
    int obase = (blockIdx.x & 1) * 32 + (threadIdx.x >> 6) * 8;
    int tl = threadIdx.x & 63;
    int tok = tok0 + tl;
    float mu = stats[0 * 8 + b];
    float rs = stats[0 * 8 + 4 + b];
    __shared__ float xs[64][64];
    for (int k = 0; k < 16; ++k) {
        int e = threadIdx.x + k * 256;
        int c = e >> 6;
        xs[c][e & 63] = (x[((size_t)(b * 64 + c)) * NN + tok0 + (e & 63)] - mu) * rs * n1g[c] + n1b[c];
    }
    __syncthreads();
    float xc[64];
    #pragma unroll
    for (int c = 0; c < 64; ++c) xc[c] = xs[c][tl];
    // inline rope: per output pair, same angle
    int hh = tok >> 6, ww = tok & 63;
    float st[4], ct[4];
    #pragma unroll
    for (int p = 0; p < 4; ++p) {
        int o = obase + 2 * p;
        int j = (o & 31) >> 1;
        float freq = exp2f(-0.88584749f * (float)j);
        float pos = (o < 32) ? (float)hh : (float)ww;
        __sincosf(pos * freq, &st[p], &ct[p]);
    }
    ushort* qrow = qr + ((size_t)b * NN + tok) * 64;
    #pragma unroll
    for (int p = 0; p < 4; ++p) {
        int o = obase + 2 * p;
        float a0 = qb[o], a1 = qb[o + 1];
        #pragma unroll
        for (int c = 0; c < 64; ++c) {
            a0 += qw[o * 64 + c] * xc[c];
            a1 += qw[(o + 1) * 64 + c] * xc[c];
        }
        qrow[o]     = f2bf(a0 * ct[p] - a1 * st[p]);
        qrow[o + 1] = f2bf(a1 * ct[p] + a0 * st[p]);
    }
}

// ---------------- KV proj from kvin; K+inline RoPE (B,N,HD); V^T (B,HD,N) ----------------
// grid dim3(256, B): tokblk = bx>>2, slice = bx&3 -> outputs slice*32 + og*8
__global__ __launch_bounds__(256) void kv_kernel(const float* __restrict__ kvin,
                                                 const float* __restrict__ kvw,
                                                 const float* __restrict__ kvb,
                                                 ushort* __restrict__ kr,
                                                 ushort* __restrict__ vt) {
    int b = blockIdx.y;
    int tok0 = (blockIdx.x >> 2) * 64;
    int obase = (blockIdx.x & 3) * 32 + (threadIdx.x >> 6) * 8;
    int tl = threadIdx.x & 63;
    int tok = tok0 + tl;
    __shared__ float xs[64][64];
    for (int k = 0; k < 16; ++k) {
        int e = threadIdx.x + k * 256;
        xs[e >> 6][e & 63] = kvin[((size_t)(b * 64 + (e >> 6))) * NN + tok0 + (e & 63)];
    }
    __syncthreads();
    float xc[64];
    #pragma unroll
    for (int c = 0; c < 64; ++c) xc[c] = xs[c][tl];
    if (obase < 64) {
        int hh = tok >> 6, ww = tok & 63;
        float st[4], ct[4];
        #pragma unroll
        for (int p = 0; p < 4; ++p) {
            int o = obase + 2 * p;
            int j = (o & 31) >> 1;
            float freq = exp2f(-0.88584749f * (float)j);
            float pos = (o < 32) ? (float)hh : (float)ww;
            __sincosf(pos * freq, &st[p], &ct[p]);
        }
        ushort* krow = kr + ((size_t)b * NN + tok) * 64;
        #pragma unroll
        for (int p = 0; p < 4; ++p) {
            int o = obase + 2 * p;
            float a0 = kvb[o], a1 = kvb[o + 1];
            #pragma unroll
            for (int c = 0; c < 64; ++c) {
                a0 += kvw[o * 64 + c] * xc[c];
                a1 += kvw[(o + 1) * 64 + c] * xc[c];
            }
            krow[o]     = f2bf(a0 * ct[p] - a1 * st[p]);
            krow[o + 1] = f2bf(a1 * ct[p] + a0 * st[p]);
        }
    } else {
        #pragma unroll
        for (int oo = 0; oo < 8; ++oo) {
            int oa = obase + oo;            // [64,128)
            float a0 = kvb[oa];
            #pragma unroll
            for (int c = 0; c < 64; ++c) a0 += kvw[oa * 64 + c] * xc[c];
            vt[((size_t)b * 64 + (oa - 64)) * NN + tok] = f2bf(a0);
        }
    }
}

// ---------------- MFMA flash attention, split-KV, async-stage, setprio ----------------
// grid dim3(64, B, NCH), 256 thr = 4 waves x 16 q-rows; KV tile 64; chunk = 512 keys
__global__ __launch_bounds__(256) void attn_kernel(const ushort* __restrict__ qr,
                                                   const ushort* __restrict__ kr,
                                                   const ushort* __restrict__ vt,
                                                   ushort* __restrict__ Opart,
                                                   float* __restrict__ ml) {
    int b = blockIdx.y;
    int q0 = blockIdx.x * 64;
    int chunk = blockIdx.z;
    int tid = threadIdx.x;
    int w = tid >> 6;
    int lane = tid & 63;
    int lr = lane & 15;
    int lg = lane >> 4;
    const float SCL2 = 0.125f * 1.44269504f;   // HD^-0.5 * log2(e)

    __shared__ ushort Kl[64 * 64];
    __shared__ ushort Vl[64 * 64];
    __shared__ ushort Pl[4 * 16 * 64];
    ushort* Pw = Pl + w * 1024;

    bf16x8 qf[2];
    {
        const ushort* qp = qr + ((size_t)b * NN + q0 + w * 16 + lr) * 64;
        qf[0] = *(const bf16x8*)(qp + lg * 8);
        qf[1] = *(const bf16x8*)(qp + 32 + lg * 8);
    }

    f32x4 oacc[4];
    #pragma unroll
    for (int t = 0; t < 4; ++t) oacc[t] = (f32x4){0.f, 0.f, 0.f, 0.f};
    float m_[4], l_[4];
    #pragma unroll
    for (int r = 0; r < 4; ++r) { m_[r] = -INFINITY; l_[r] = 0.f; }

    const size_t kbase = ((size_t)b * NN) * 64;
    const int t0 = chunk * 8, tend = t0 + 8;

    // staging decomposition (fixed per thread)
    const int srow0 = tid >> 3, scib = tid & 7;          // it=0
    const int srow1 = (tid + 256) >> 3;                  // it=1 (same cib)
    const int ssw0 = scib ^ (srow0 & 7);
    const int ssw1 = scib ^ (srow1 & 7);

    // prefetch first tile into registers
    bf16x8 kpre0, kpre1, vpre0, vpre1;
    {
        int k0 = t0 * 64;
        kpre0 = *(const bf16x8*)(kr + kbase + (size_t)(k0 + srow0) * 64 + scib * 8);
        vpre0 = *(const bf16x8*)(vt + ((size_t)b * 64 + srow0) * NN + k0 + scib * 8);
        kpre1 = *(const bf16x8*)(kr + kbase + (size_t)(k0 + srow1) * 64 + scib * 8);
        vpre1 = *(const bf16x8*)(vt + ((size_t)b * 64 + srow1) * NN + k0 + scib * 8);
    }

    for (int t = t0; t < tend; ++t) {
        __syncthreads();
        *(bf16x8*)(Kl + srow0 * 64 + ssw0 * 8) = kpre0;
        *(bf16x8*)(Vl + srow0 * 64 + ssw0 * 8) = vpre0;
        *(bf16x8*)(Kl + srow1 * 64 + ssw1 * 8) = kpre1;
        *(bf16x8*)(Vl + srow1 * 64 + ssw1 * 8) = vpre1;
        __syncthreads();
        if (t + 1 < tend) {
            int k0n = (t + 1) * 64;
            kpre0 = *(const bf16x8*)(kr + kbase + (size_t)(k0n + srow0) * 64 + scib * 8);
            vpre0 = *(const bf16x8*)(vt + ((size_t)b * 64 + srow0) * NN + k0n + scib * 8);
            kpre1 = *(const bf16x8*)(kr + kbase + (size_t)(k0n + srow1) * 64 + scib * 8);
            vpre1 = *(const bf16x8*)(vt + ((size_t)b * 64 + srow1) * NN + k0n + scib * 8);
        }

        f32x4 sacc[4];
        __builtin_amdgcn_s_setprio(1);
        #pragma unroll
        for (int kt = 0; kt < 4; ++kt) {
            int row = kt * 16 + lr;
            bf16x8 k0f = *(const bf16x8*)(Kl + row * 64 + ((0 * 4 + lg) ^ (lr & 7)) * 8);
            bf16x8 k1f = *(const bf16x8*)(Kl + row * 64 + ((1 * 4 + lg) ^ (lr & 7)) * 8);
            f32x4 z = {0.f, 0.f, 0.f, 0.f};
            z = MFMA16(qf[0], k0f, z);
            sacc[kt] = MFMA16(qf[1], k1f, z);
        }
        __builtin_amdgcn_s_setprio(0);

        // tile max (base-2 units)
        float mx[4];
        float need = 0.f;
        #pragma unroll
        for (int r = 0; r < 4; ++r) {
            float v0 = fmaxf(fmaxf(sacc[0][r], sacc[1][r]), fmaxf(sacc[2][r], sacc[3][r]));
            v0 = fmaxf(v0, __shfl_xor(v0, 1));
            v0 = fmaxf(v0, __shfl_xor(v0, 2));
            v0 = fmaxf(v0, __shfl_xor(v0, 4));
            v0 = fmaxf(v0, __shfl_xor(v0, 8));
            mx[r] = v0 * SCL2;
            need = fmaxf(need, mx[r] - m_[r]);
        }
        if (__any(need > 8.f)) {       // defer-max: rescale only on real growth
            float cr[4];
            #pragma unroll
            for (int r = 0; r < 4; ++r) {
                float mn = fmaxf(m_[r], mx[r]);
                cr[r] = exp2f(m_[r] - mn);
                l_[r] *= cr[r];
                m_[r] = mn;
            }
            #pragma unroll
            for (int ht = 0; ht < 4; ++ht)
                #pragma unroll
                for (int r = 0; r < 4; ++r) oacc[ht][r] *= cr[r];
        }
        float rowsum[4];
        #pragma unroll
        for (int r = 0; r < 4; ++r) rowsum[r] = 0.f;
        #pragma unroll
        for (int kt = 0; kt < 4; ++kt) {
            #pragma unroll
            for (int r = 0; r < 4; ++r) {
                int R = lg * 4 + r;
                float pv = exp2f(sacc[kt][r] * SCL2 - m_[r]);
                rowsum[r] += pv;
                Pw[R * 64 + ((kt * 2 + (lr >> 3)) ^ (R & 7)) * 8 + (lr & 7)] = f2bf(pv);
            }
        }
        #pragma unroll
        for (int r = 0; r < 4; ++r) {
            float s = rowsum[r];
            s += __shfl_xor(s, 1);
            s += __shfl_xor(s, 2);
            s += __shfl_xor(s, 4);
            s += __shfl_xor(s, 8);
            l_[r] += s;
        }

        bf16x8 pa0 = *(const bf16x8*)(Pw + lr * 64 + ((0 * 4 + lg) ^ (lr & 7)) * 8);
        bf16x8 pa1 = *(const bf16x8*)(Pw + lr * 64 + ((1 * 4 + lg) ^ (lr & 7)) * 8);
        __builtin_amdgcn_s_setprio(1);
        #pragma unroll
        for (int ht = 0; ht < 4; ++ht) {
            int row = ht * 16 + lr;
            bf16x8 v0f = *(const bf16x8*)(Vl + row * 64 + ((0 * 4 + lg) ^ (lr & 7)) * 8);
            bf16x8 v1f = *(const bf16x8*)(Vl + row * 64 + ((1 * 4 + lg) ^ (lr & 7)) * 8);
            oacc[ht] = MFMA16(pa0, v0f, oacc[ht]);
            oacc[ht] = MFMA16(pa1, v1f, oacc[ht]);
        }
        __builtin_amdgcn_s_setprio(0);
    }

    int n0 = q0 + w * 16 + lg * 4;
    #pragma unroll
    for (int ht = 0; ht < 4; ++ht) {
        int hd = ht * 16 + lr;
        ushort4 o4;
        o4.x = f2bf(oacc[ht][0]); o4.y = f2bf(oacc[ht][1]);
        o4.z = f2bf(oacc[ht][2]); o4.w = f2bf(oacc[ht][3]);
        *(ushort4*)&Opart[(((size_t)chunk * BB + b) * 64 + hd) * NN + n0] = o4;
    }
    if (lr == 0) {
        #pragma unroll
        for (int r = 0; r < 4; ++r) {
            int n = n0 + r;
            ml[((size_t)b * NN + n) * 16 + chunk * 2]     = m_[r];
            ml[((size_t)b * NN + n) * 16 + chunk * 2 + 1] = l_[r];
        }
    }
}

// ---------------- combine: x2 = sum_c O_c*w_c + x; fused stats partials ----------------
__global__ __launch_bounds__(256) void combine_kernel(const ushort* __restrict__ Opart,
                                                      const float* __restrict__ ml,
                                                      const float* __restrict__ x,
                                                      float* __restrict__ x2,
                                                      float* __restrict__ part2) {
    int i = blockIdx.x * 256 + threadIdx.x;   // 262144
    int n4 = i & 1023;
    int hd = (i >> 10) & 63;
    int b = i >> 16;
    int n0 = n4 << 2;
    float wgt[4][NCH];
    const float* mlp = ml + ((size_t)b * NN + n0) * 16;
    #pragma unroll
    for (int tk = 0; tk < 4; ++tk) {
        float m[NCH], l[NCH];
        const float4* p4 = (const float4*)(mlp + tk * 16);
        #pragma unroll
        for (int q = 0; q < 4; ++q) {
            float4 v = p4[q];
            m[q * 2] = v.x; l[q * 2] = v.y; m[q * 2 + 1] = v.z; l[q * 2 + 1] = v.w;
        }
        float M = m[0];
        #pragma unroll
        for (int c = 1; c < NCH; ++c) M = fmaxf(M, m[c]);
        float e[NCH], L = 0.f;
        #pragma unroll
        for (int c = 0; c < NCH; ++c) { e[c] = exp2f(m[c] - M); L += l[c] * e[c]; }
        float inv = 1.f / L;
        #pragma unroll
        for (int c = 0; c < NCH; ++c) wgt[tk][c] = e[c] * inv;
    }
    float4 acc = {0.f, 0.f, 0.f, 0.f};
    #pragma unroll
    for (int c = 0; c < NCH; ++c) {
        ushort4 o4 = *(const ushort4*)&Opart[(((size_t)c * BB + b) * 64 + hd) * NN + n0];
        acc.x += bf2f(o4.x) * wgt[0][c];
        acc.y += bf2f(o4.y) * wgt[1][c];
        acc.z += bf2f(o4.z) * wgt[2][c];
        acc.w += bf2f(o4.w) * wgt[3][c];
    }
    size_t off = ((size_t)b * 64 + hd) * NN + n0;
    float4 xv = *(const float4*)&x[off];
    acc.x += xv.x; acc.y += xv.y; acc.z += xv.z; acc.w += xv.w;
    *(float4*)&x2[off] = acc;

    float s = acc.x + acc.y + acc.z + acc.w;
    float s2 = acc.x * acc.x + acc.y * acc.y + acc.z * acc.z + acc.w * acc.w;
    #pragma unroll
    for (int off2 = 32; off2 > 0; off2 >>= 1) {
        s  += __shfl_xor(s, off2);
        s2 += __shfl_xor(s2, off2);
    }
    __shared__ float shs[4], shs2[4];
    int wid = threadIdx.x >> 6, lane = threadIdx.x & 63;
    if (lane == 0) { shs[wid] = s; shs2[wid] = s2; }
    __syncthreads();
    if (threadIdx.x == 0) {
        part2[blockIdx.x * 2]     = shs[0] + shs[1] + shs[2] + shs[3];
        part2[blockIdx.x * 2 + 1] = shs2[0] + shs2[1] + shs2[2] + shs2[3];
    }
}

// ---------------- fc1: h1 = gelu(bn1(fc1w @ gn2(x2))) -> bf16 ----------------
// grid dim3(256, B)
__global__ __launch_bounds__(256) void fc1_kernel(const float* __restrict__ x2,
                                                  const float* __restrict__ fc1w,
                                                  const float* __restrict__ n2g,
                                                  const float* __restrict__ n2b,
                                                  const float* __restrict__ bn1g,
                                                  const float* __restrict__ bn1b,
                                                  const float* __restrict__ stats,
                                                  ushort* __restrict__ h1) {
    int b = blockIdx.y;
    int tok0 = (blockIdx.x >> 2) * 64;
    int o0 = (blockIdx.x & 3) * 64 + (threadIdx.x >> 6) * 16;
    int tl = threadIdx.x & 63;
    int tok = tok0 + tl;
    float mu = stats[2 * 8 + b];
    float rs = stats[2 * 8 + 4 + b];
    __shared__ float xs[64][64];
    for (int k = 0; k < 16; ++k) {
        int e = threadIdx.x + k * 256;
        int c = e >> 6;
        xs[c][e & 63] = (x2[((size_t)(b * 64 + c)) * NN + tok0 + (e & 63)] - mu) * rs * n2g[c] + n2b[c];
    }
    __syncthreads();
    float xc[64];
    #pragma unroll
    for (int c = 0; c < 64; ++c) xc[c] = xs[c][tl];
    const float sb = rsqrtf(1.f + EPSV);
    ushort* hp = h1 + (size_t)b * HID * NN + tok;
    #pragma unroll
    for (int oo = 0; oo < 16; oo += 4) {
        int o = o0 + oo;
        float a0 = 0.f, a1 = 0.f, a2 = 0.f, a3 = 0.f;
        #pragma unroll
        for (int c = 0; c < 64; ++c) {
            float xv = xc[c];
            a0 += fc1w[o * 64 + c] * xv;
            a1 += fc1w[(o + 1) * 64 + c] * xv;
            a2 += fc1w[(o + 2) * 64 + c] * xv;
            a3 += fc1w[(o + 3) * 64 + c] * xv;
        }
        hp[(size_t)o * NN]       = f2bf(gelu_exact(a0 * bn1g[o] * sb + bn1b[o]));
        hp[(size_t)(o + 1) * NN] = f2bf(gelu_exact(a1 * bn1g[o + 1] * sb + bn1b[o + 1]));
        hp[(size_t)(o + 2) * NN] = f2bf(gelu_exact(a2 * bn1g[o + 2] * sb + bn1b[o + 2]));
        hp[(size_t)(o + 3) * NN] = f2bf(gelu_exact(a3 * bn1g[o + 3] * sb + bn1b[o + 3]));
    }
}

// ---------------- mixer: LDS-tiled per (b,c) plane; dw + fft-scale + res + gelu + bnm ----------------
// grid dim3(HID, B), 256 thr; LDS 70x72 bf16 zero-padded halo
__global__ __launch_bounds__(256) void mixer_kernel(const ushort* __restrict__ h1,
                                                    const float* __restrict__ dw1w, const float* __restrict__ dw1b,
                                                    const float* __restrict__ dw3w, const float* __restrict__ dw3b,
                                                    const float* __restrict__ dw5w, const float* __restrict__ dw5b,
                                                    const float* __restrict__ dw7w, const float* __restrict__ dw7b,
                                                    const float* __restrict__ fftw,
                                                    const float* __restrict__ bnmg, const float* __restrict__ bnmb,
                                                    ushort* __restrict__ h2) {
    int c = blockIdx.x;
    int b = blockIdx.y;
    __shared__ ushort ls[70][72];
    uint* lz = (uint*)&ls[0][0];
    for (int i = threadIdx.x; i < 2520; i += 256) lz[i] = 0;
    __syncthreads();
    const ushort* plane = h1 + (((size_t)b * HID + c) << 12);
    for (int e = threadIdx.x; e < 4096; e += 256)
        ls[(e >> 6) + 3][(e & 63) + 3] = plane[e];
    __syncthreads();
    const float sb = rsqrtf(1.f + EPSV);
    float fw = fftw[c];
    float bg = bnmg[c] * sb, bb2 = bnmb[c];
    ushort* outp = h2 + (((size_t)b * HID + c) << 12);
    if (c < 64) {
        float w0 = dw1w[c], b0 = dw1b[c];
        for (int e = threadIdx.x; e < 4096; e += 256) {
            float ctr = bf2f(ls[(e >> 6) + 3][(e & 63) + 3]);
            float val = fw * (w0 * ctr + b0) + ctr;
            outp[e] = f2bf(gelu_exact(val) * bg + bb2);
        }
    } else if (c < 128) {
        int lc = c - 64;
        float wr[9];
        #pragma unroll
        for (int i = 0; i < 9; ++i) wr[i] = dw3w[lc * 9 + i];
        float b0 = dw3b[lc];
        for (int e = threadIdx.x; e < 4096; e += 256) {
            int y = e >> 6, x = e & 63;
            float acc = b0;
            #pragma unroll
            for (int dy = 0; dy < 3; ++dy)
                #pragma unroll
                for (int dx = 0; dx < 3; ++dx)
                    acc += wr[dy * 3 + dx] * bf2f(ls[y + 2 + dy][x + 2 + dx]);
            float ctr = bf2f(ls[y + 3][x + 3]);
            outp[e] = f2bf(gelu_exact(fw * acc + ctr) * bg + bb2);
        }
    } else if (c < 192) {
        int lc = c - 128;
        float wr[25];
        #pragma unroll
        for (int i = 0; i < 25; ++i) wr[i] = dw5w[lc * 25 + i];
        float b0 = dw5b[lc];
        for (int e = threadIdx.x; e < 4096; e += 256) {
            int y = e >> 6, x = e & 63;
            float acc = b0;
            #pragma unroll
            for (int dy = 0; dy < 5; ++dy)
                #pragma unroll
                for (int dx = 0; dx < 5; ++dx)
                    acc += wr[dy * 5 + dx] * bf2f(ls[y + 1 + dy][x + 1 + dx]);
            float ctr = bf2f(ls[y + 3][x + 3]);
            outp[e] = f2bf(gelu_exact(fw * acc + ctr) * bg + bb2);
        }
    } else {
        int lc = c - 192;
        float wr[49];
        #pragma unroll
        for (int i = 0; i < 49; ++i) wr[i] = dw7w[lc * 49 + i];
        float b0 = dw7b[lc];
        for (int e = threadIdx.x; e < 4096; e += 256) {
            int y = e >> 6, x = e & 63;
            float acc = b0;
            #pragma unroll
            for (int dy = 0; dy < 7; ++dy)
                #pragma unroll
                for (int dx = 0; dx < 7; ++dx)
                    acc += wr[dy * 7 + dx] * bf2f(ls[y + dy][x + dx]);
            float ctr = bf2f(ls[y + 3][x + 3]);
            outp[e] = f2bf(gelu_exact(fw * acc + ctr) * bg + bb2);
        }
    }
}

// ---------------- fc2 + bn2 + residual ----------------
// grid dim3(512, B)
__global__ __launch_bounds__(256) void fc2_kernel(const ushort* __restrict__ h2,
                                                  const float* __restrict__ fc2w,
                                                  const float* __restrict__ bn2g,
                                                  const float* __restrict__ bn2b,
                                                  const float* __restrict__ x2,
                                                  float* __restrict__ out) {
    int b = blockIdx.y;
    int tok = (blockIdx.x >> 3) * 64 + (threadIdx.x & 63);
    int o0 = (blockIdx.x & 7) * 4 + (threadIdx.x >> 6);
    int o1 = o0 + 32;
    const ushort* hp = h2 + (size_t)b * HID * NN + tok;
    const float* w0 = fc2w + o0 * 256;
    const float* w1 = fc2w + o1 * 256;
    float acc0 = 0.f, acc1 = 0.f;
    #pragma unroll 8
    for (int c = 0; c < 256; ++c) {
        float hv = bf2f(hp[(size_t)c * NN]);
        acc0 += w0[c] * hv;
        acc1 += w1[c] * hv;
    }
    const float sb = rsqrtf(1.f + EPSV);
    size_t off0 = ((size_t)b * 64 + o0) * NN + tok;
    size_t off1 = ((size_t)b * 64 + o1) * NN + tok;
    out[off0] = acc0 * bn2g[o0] * sb + bn2b[o0] + x2[off0];
    out[off1] = acc1 * bn2g[o1] * sb + bn2b[o1] + x2[off1];
}

extern "C" void kernel_launch(void* const* d_in, const int* in_sizes, int n_in,
                              void* d_out, int out_size, void* d_ws, size_t ws_size,
                              hipStream_t stream) {
    const float* x    = (const float*)d_in[0];
    const float* cnn  = (const float*)d_in[1];
    const float* n1g  = (const float*)d_in[2];
    const float* n1b  = (const float*)d_in[3];
    const float* n2g  = (const float*)d_in[4];
    const float* n2b  = (const float*)d_in[5];
    const float* n3g  = (const float*)d_in[6];
    const float* n3b  = (const float*)d_in[7];
    const float* qw   = (const float*)d_in[8];
    const float* qb   = (const float*)d_in[9];
    const float* kvw  = (const float*)d_in[10];
    const float* kvb  = (const float*)d_in[11];
    const float* lcw  = (const float*)d_in[12];
    const float* lcb  = (const float*)d_in[13];
    const float* fc1w = (const float*)d_in[14];
    const float* bn1g = (const float*)d_in[15];
    const float* bn1b = (const float*)d_in[16];
    const float* dw1w = (const float*)d_in[17];
    const float* dw1b = (const float*)d_in[18];
    const float* dw3w = (const float*)d_in[19];
    const float* dw3b = (const float*)d_in[20];
    const float* dw5w = (const float*)d_in[21];
    const float* dw5b = (const float*)d_in[22];
    const float* dw7w = (const float*)d_in[23];
    const float* dw7b = (const float*)d_in[24];
    const float* bnmg = (const float*)d_in[25];
    const float* bnmb = (const float*)d_in[26];
    const float* fftw = (const float*)d_in[27];
    const float* fc2w = (const float*)d_in[28];
    const float* bn2g = (const float*)d_in[29];
    const float* bn2b = (const float*)d_in[30];

    float* ws = (float*)d_ws;
    float* stats = ws;                     // 64
    float* part  = ws + 64;                // 1024 (2 slots x 4 b x 64 blk x 2)
    float* part2 = ws + 1088;              // 2048
    float* base  = ws + 3200;
    const size_t M = 1048576;
    float* x2     = base;                              // [0, 1M)
    ushort* qr_bf = (ushort*)(base + M);               // [1M, 1.5M)
    ushort* kr_bf = (ushort*)(base + M + M / 2);       // [1.5M, 2M)
    ushort* vt_bf = (ushort*)(base + 2 * M);           // [2M, 2.5M)
    float* kvin   = base + 5 * M / 2;                  // [2.5M, 3.5M)
    ushort* Opart = (ushort*)(base + 7 * M / 2);       // [3.5M, 7.5M)
    float* ml     = base + 15 * M / 2;                 // [7.5M, 7.75M)
    ushort* h1 = (ushort*)(base + M);                  // overlay qr/kr/vt/kvin (dead post-attn)
    ushort* h2 = (ushort*)(base + 7 * M / 2);          // overlay Opart head (dead post-combine)
    float* outp = (float*)d_out;

    stats_pair_kernel<<<dim3(64, 4), 256, 0, stream>>>(x, cnn, part);
    stats_fin_kernel<<<8, 64, 0, stream>>>(part, stats);
    dw3k_kernel<<<4096, 256, 0, stream>>>(cnn, n3g, n3b, lcw, lcb, stats, kvin);
    q_kernel<<<dim3(128, 4), 256, 0, stream>>>(x, n1g, n1b, qw, qb, stats, qr_bf);
    kv_kernel<<<dim3(256, 4), 256, 0, stream>>>(kvin, kvw, kvb, kr_bf, vt_bf);
    attn_kernel<<<dim3(64, 4, NCH), 256, 0, stream>>>(qr_bf, kr_bf, vt_bf, Opart, ml);
    combine_kernel<<<1024, 256, 0, stream>>>(Opart, ml, x, x2, part2);
    stats2b_kernel<<<4, 256, 0, stream>>>(part2, stats, 2);
    fc1_kernel<<<dim3(256, 4), 256, 0, stream>>>(x2, fc1w, n2g, n2b, bn1g, bn1b, stats, h1);
    mixer_kernel<<<dim3(HID, 4), 256, 0, stream>>>(h1, dw1w, dw1b, dw3w, dw3b, dw5w, dw5b,
                                                   dw7w, dw7b, fftw, bnmg, bnmb, h2);
    fc2_kernel<<<dim3(512, 4), 256, 0, stream>>>(h2, fc2w, bn2g, bn2b, x2, outp);
}

// Round 8
// 193.769 us; speedup vs baseline: 7.6414x; 1.4071x over previous
//
#include <hip/hip_runtime.h>
#include <hip/hip_bf16.h>
#include <math.h>

#define BB 4
#define CC 64
#define NN 4096
#define HD 64
#define HID 256
#define EPSV 1e-5f
#define CNT (CC*NN)
#define NCH 8            // KV split chunks

typedef float f32x4 __attribute__((ext_vector_type(4)));
typedef short bf16x8 __attribute__((ext_vector_type(8)));
#define MFMA16(a, b, c) __builtin_amdgcn_mfma_f32_16x16x32_bf16(a, b, c, 0, 0, 0)

__device__ __forceinline__ float gelu_exact(float x) {
    return 0.5f * x * (1.0f + erff(x * 0.70710678118654752f));
}
__device__ __forceinline__ ushort f2bf(float f) {
    unsigned u = __float_as_uint(f);
    unsigned r = (u + 0x7FFFu + ((u >> 16) & 1u)) >> 16;
    return (ushort)r;
}
__device__ __forceinline__ float bf2f(ushort u) {
    return __uint_as_float(((unsigned)u) << 16);
}
__device__ __forceinline__ unsigned cvtpk(float lo, float hi) {
    unsigned r;
    asm("v_cvt_pk_bf16_f32 %0, %1, %2" : "=v"(r) : "v"(lo), "v"(hi));
    return r;
}

// ---------------- weight prep: fp32 -> bf16 ----------------
__global__ __launch_bounds__(256) void wprep_kernel(const float* __restrict__ fc1w,
                                                    const float* __restrict__ fc2w,
                                                    ushort* __restrict__ fc1wb,
                                                    ushort* __restrict__ fc2wb) {
    int i = blockIdx.x * 256 + threadIdx.x;   // 32768
    if (i < 16384) fc1wb[i] = f2bf(fc1w[i]);
    else fc2wb[i - 16384] = f2bf(fc2w[i - 16384]);
}

// ---------------- fused stats stage 1 for x and cnn ----------------
__global__ __launch_bounds__(256) void stats_pair_kernel(const float* __restrict__ x,
                                                         const float* __restrict__ cnn,
                                                         float* __restrict__ part) {
    int b = blockIdx.y;
    int blk = blockIdx.x;
    const float4* p0 = (const float4*)(x + (size_t)b * CNT);
    const float4* p1 = (const float4*)(cnn + (size_t)b * CNT);
    float s0 = 0.f, s20 = 0.f, s1 = 0.f, s21 = 0.f;
    #pragma unroll
    for (int k = 0; k < 4; ++k) {
        float4 v = p0[blk * 1024 + k * 256 + threadIdx.x];
        s0  += v.x + v.y + v.z + v.w;
        s20 += v.x * v.x + v.y * v.y + v.z * v.z + v.w * v.w;
        float4 u = p1[blk * 1024 + k * 256 + threadIdx.x];
        s1  += u.x + u.y + u.z + u.w;
        s21 += u.x * u.x + u.y * u.y + u.z * u.z + u.w * u.w;
    }
    #pragma unroll
    for (int off = 32; off > 0; off >>= 1) {
        s0  += __shfl_xor(s0, off);
        s20 += __shfl_xor(s20, off);
        s1  += __shfl_xor(s1, off);
        s21 += __shfl_xor(s21, off);
    }
    __shared__ float sh[4][4];
    int wid = threadIdx.x >> 6, lane = threadIdx.x & 63;
    if (lane == 0) { sh[wid][0] = s0; sh[wid][1] = s20; sh[wid][2] = s1; sh[wid][3] = s21; }
    __syncthreads();
    if (threadIdx.x == 0) {
        float a0 = sh[0][0] + sh[1][0] + sh[2][0] + sh[3][0];
        float a1 = sh[0][1] + sh[1][1] + sh[2][1] + sh[3][1];
        float a2 = sh[0][2] + sh[1][2] + sh[2][2] + sh[3][2];
        float a3 = sh[0][3] + sh[1][3] + sh[2][3] + sh[3][3];
        part[((0 * 4 + b) * 64 + blk) * 2]     = a0;
        part[((0 * 4 + b) * 64 + blk) * 2 + 1] = a1;
        part[((1 * 4 + b) * 64 + blk) * 2]     = a2;
        part[((1 * 4 + b) * 64 + blk) * 2 + 1] = a3;
    }
}

// ---------------- stats finalize (both slots) ----------------
__global__ __launch_bounds__(64) void stats_fin_kernel(const float* __restrict__ part,
                                                       float* __restrict__ stats) {
    int sb_ = blockIdx.x;    // slot*4 + b
    int lane = threadIdx.x;
    float s = part[(sb_ * 64 + lane) * 2];
    float s2 = part[(sb_ * 64 + lane) * 2 + 1];
    #pragma unroll
    for (int off = 32; off > 0; off >>= 1) {
        s  += __shfl_xor(s, off);
        s2 += __shfl_xor(s2, off);
    }
    if (lane == 0) {
        int slot = sb_ >> 2, b = sb_ & 3;
        float mu = s / (float)CNT;
        float var = s2 / (float)CNT - mu * mu;
        stats[slot * 8 + b] = mu;
        stats[slot * 8 + 4 + b] = rsqrtf(var + EPSV);
    }
}

// ---------------- stats stage 2b (256 partials, slot 2) ----------------
__global__ __launch_bounds__(256) void stats2b_kernel(const float* __restrict__ part2,
                                                      float* __restrict__ stats, int slot) {
    int b = blockIdx.x;
    int t = threadIdx.x;
    float s = part2[(b * 256 + t) * 2];
    float s2 = part2[(b * 256 + t) * 2 + 1];
    #pragma unroll
    for (int off = 32; off > 0; off >>= 1) {
        s  += __shfl_xor(s, off);
        s2 += __shfl_xor(s2, off);
    }
    __shared__ float shs[4], shs2[4];
    int wid = t >> 6, lane = t & 63;
    if (lane == 0) { shs[wid] = s; shs2[wid] = s2; }
    __syncthreads();
    if (t == 0) {
        float S = shs[0] + shs[1] + shs[2] + shs[3];
        float S2 = shs2[0] + shs2[1] + shs2[2] + shs2[3];
        float mu = S / (float)CNT;
        float var = S2 / (float)CNT - mu * mu;
        stats[slot * 8 + b] = mu;
        stats[slot * 8 + 4 + b] = rsqrtf(var + EPSV);
    }
}

// ---------------- dw3k: kvin = dw3(gn(cnn)) + bias + gn(cnn) ----------------
__global__ __launch_bounds__(256) void dw3k_kernel(const float* __restrict__ cnn,
                                                   const float* __restrict__ n3g,
                                                   const float* __restrict__ n3b,
                                                   const float* __restrict__ lcw,
                                                   const float* __restrict__ lcb,
                                                   const float* __restrict__ stats,
                                                   float* __restrict__ kvin) {
    int i = blockIdx.x * 256 + threadIdx.x;   // 1,048,576
    int x = i & 63;
    int y = (i >> 6) & 63;
    int c = (i >> 12) & 63;
    int b = i >> 18;
    float mu = stats[1 * 8 + b];
    float rs = stats[1 * 8 + 4 + b];
    float sc = rs * n3g[c];
    float of = n3b[c] - mu * sc;
    const float* plane = cnn + ((size_t)(i >> 12) << 12);
    float acc = lcb[c];
    #pragma unroll
    for (int dy = 0; dy < 3; ++dy) {
        int yy = y + dy - 1;
        if (yy < 0 || yy >= 64) continue;
        #pragma unroll
        for (int dx = 0; dx < 3; ++dx) {
            int xx = x + dx - 1;
            if (xx < 0 || xx >= 64) continue;
            acc += lcw[c * 9 + dy * 3 + dx] * (plane[(yy << 6) + xx] * sc + of);
        }
    }
    kvin[i] = acc + plane[(y << 6) + x] * sc + of;
}

// ---------------- Q: gn(x) + proj + inline RoPE -> bf16 (B,N,HD) ----------------
__global__ __launch_bounds__(256) void q_kernel(const float* __restrict__ x,
                                                const float* __restrict__ n1g,
                                                const float* __restrict__ n1b,
                                                const float* __restrict__ qw,
                                                const float* __restrict__ qb,
                                                const float* __restrict__ stats,
                                                ushort* __restrict__ qr) {
    int b = blockIdx.y;
    int tok0 = (blockIdx.x >> 1) * 64;
    int obase = (blockIdx.x & 1) * 32 + (threadIdx.x >> 6) * 8;
    int tl = threadIdx.x & 63;
    int tok = tok0 + tl;
    float mu = stats[0 * 8 + b];
    float rs = stats[0 * 8 + 4 + b];
    __shared__ float xs[64][64];
    for (int k = 0; k < 16; ++k) {
        int e = threadIdx.x + k * 256;
        int c = e >> 6;
        xs[c][e & 63] = (x[((size_t)(b * 64 + c)) * NN + tok0 + (e & 63)] - mu) * rs * n1g[c] + n1b[c];
    }
    __syncthreads();
    float xc[64];
    #pragma unroll
    for (int c = 0; c < 64; ++c) xc[c] = xs[c][tl];
    int hh = tok >> 6, ww = tok & 63;
    float st[4], ct[4];
    #pragma unroll
    for (int p = 0; p < 4; ++p) {
        int o = obase + 2 * p;
        int j = (o & 31) >> 1;
        float freq = exp2f(-0.88584749f * (float)j);
        float pos = (o < 32) ? (float)hh : (float)ww;
        __sincosf(pos * freq, &st[p], &ct[p]);
    }
    ushort* qrow = qr + ((size_t)b * NN + tok) * 64;
    #pragma unroll
    for (int p = 0; p < 4; ++p) {
        int o = obase + 2 * p;
        float a0 = qb[o], a1 = qb[o + 1];
        #pragma unroll
        for (int c = 0; c < 64; ++c) {
            a0 += qw[o * 64 + c] * xc[c];
            a1 += qw[(o + 1) * 64 + c] * xc[c];
        }
        qrow[o]     = f2bf(a0 * ct[p] - a1 * st[p]);
        qrow[o + 1] = f2bf(a1 * ct[p] + a0 * st[p]);
    }
}

// ---------------- KV proj from kvin; K+inline RoPE (B,N,HD); V^T (B,HD,N) ----------------
__global__ __launch_bounds__(256) void kv_kernel(const float* __restrict__ kvin,
                                                 const float* __restrict__ kvw,
                                                 const float* __restrict__ kvb,
                                                 ushort* __restrict__ kr,
                                                 ushort* __restrict__ vt) {
    int b = blockIdx.y;
    int tok0 = (blockIdx.x >> 2) * 64;
    int obase = (blockIdx.x & 3) * 32 + (threadIdx.x >> 6) * 8;
    int tl = threadIdx.x & 63;
    int tok = tok0 + tl;
    __shared__ float xs[64][64];
    for (int k = 0; k < 16; ++k) {
        int e = threadIdx.x + k * 256;
        xs[e >> 6][e & 63] = kvin[((size_t)(b * 64 + (e >> 6))) * NN + tok0 + (e & 63)];
    }
    __syncthreads();
    float xc[64];
    #pragma unroll
    for (int c = 0; c < 64; ++c) xc[c] = xs[c][tl];
    if (obase < 64) {
        int hh = tok >> 6, ww = tok & 63;
        float st[4], ct[4];
        #pragma unroll
        for (int p = 0; p < 4; ++p) {
            int o = obase + 2 * p;
            int j = (o & 31) >> 1;
            float freq = exp2f(-0.88584749f * (float)j);
            float pos = (o < 32) ? (float)hh : (float)ww;
            __sincosf(pos * freq, &st[p], &ct[p]);
        }
        ushort* krow = kr + ((size_t)b * NN + tok) * 64;
        #pragma unroll
        for (int p = 0; p < 4; ++p) {
            int o = obase + 2 * p;
            float a0 = kvb[o], a1 = kvb[o + 1];
            #pragma unroll
            for (int c = 0; c < 64; ++c) {
                a0 += kvw[o * 64 + c] * xc[c];
                a1 += kvw[(o + 1) * 64 + c] * xc[c];
            }
            krow[o]     = f2bf(a0 * ct[p] - a1 * st[p]);
            krow[o + 1] = f2bf(a1 * ct[p] + a0 * st[p]);
        }
    } else {
        #pragma unroll
        for (int oo = 0; oo < 8; ++oo) {
            int oa = obase + oo;            // [64,128)
            float a0 = kvb[oa];
            #pragma unroll
            for (int c = 0; c < 64; ++c) a0 += kvw[oa * 64 + c] * xc[c];
            vt[((size_t)b * 64 + (oa - 64)) * NN + tok] = f2bf(a0);
        }
    }
}

// ---------------- MFMA flash attention v3: swapped QK^T, in-register P ----------------
// grid dim3(64, B, NCH), 256 thr = 4 waves x 16 q-rows; KV tile 64; chunk = 512 keys
__global__ __launch_bounds__(256) void attn_kernel(const ushort* __restrict__ qr,
                                                   const ushort* __restrict__ kr,
                                                   const ushort* __restrict__ vt,
                                                   ushort* __restrict__ Opart,
                                                   float* __restrict__ ml) {
    int b = blockIdx.y;
    int q0 = blockIdx.x * 64;
    int chunk = blockIdx.z;
    int tid = threadIdx.x;
    int w = tid >> 6;
    int lane = tid & 63;
    int lr = lane & 15;
    int lg = lane >> 4;
    const float SCL2 = 0.125f * 1.44269504f;   // HD^-0.5 * log2(e)

    __shared__ ushort Kl[64 * 64];
    __shared__ ushort Vl[64 * 64];

    // Q fragment (B-operand): lane holds Q[q = q0+w*16+lr][chan = ks*32 + lg*8 ..+8]
    bf16x8 qf[2];
    {
        const ushort* qp = qr + ((size_t)b * NN + q0 + w * 16 + lr) * 64;
        qf[0] = *(const bf16x8*)(qp + lg * 8);
        qf[1] = *(const bf16x8*)(qp + 32 + lg * 8);
    }

    f32x4 oacc[4];
    #pragma unroll
    for (int t = 0; t < 4; ++t) oacc[t] = (f32x4){0.f, 0.f, 0.f, 0.f};
    float m_ = -INFINITY, l_ = 0.f;     // scalar state for q-row = q0+w*16+lr

    const size_t kbase = ((size_t)b * NN) * 64;
    const int t0 = chunk * 8, tend = t0 + 8;

    for (int t = t0; t < tend; ++t) {
        int k0 = t * 64;
        __syncthreads();
        #pragma unroll
        for (int it = 0; it < 2; ++it) {
            int e = tid + it * 256;
            int row = e >> 3, cib = e & 7;
            int sw = cib ^ (row & 7);
            *(bf16x8*)(Kl + row * 64 + sw * 8) =
                *(const bf16x8*)(kr + kbase + (size_t)(k0 + row) * 64 + cib * 8);
            *(bf16x8*)(Vl + row * 64 + sw * 8) =
                *(const bf16x8*)(vt + ((size_t)b * 64 + row) * NN + k0 + cib * 8);
        }
        __syncthreads();

        // S^T = K Q : C[key][q], lane holds q=lr, key = kt*16 + lg*4 + r
        f32x4 sacc[4];
        #pragma unroll
        for (int kt = 0; kt < 4; ++kt) {
            int row = kt * 16 + lr;
            bf16x8 k0f = *(const bf16x8*)(Kl + row * 64 + ((0 * 4 + lg) ^ (lr & 7)) * 8);
            bf16x8 k1f = *(const bf16x8*)(Kl + row * 64 + ((1 * 4 + lg) ^ (lr & 7)) * 8);
            f32x4 z = {0.f, 0.f, 0.f, 0.f};
            z = MFMA16(k0f, qf[0], z);
            sacc[kt] = MFMA16(k1f, qf[1], z);
        }

        // scalar row max over this lane's 16 keys, then reduce across lg groups
        float vmax = fmaxf(fmaxf(fmaxf(sacc[0][0], sacc[0][1]), fmaxf(sacc[0][2], sacc[0][3])),
                           fmaxf(fmaxf(sacc[1][0], sacc[1][1]), fmaxf(sacc[1][2], sacc[1][3])));
        vmax = fmaxf(vmax, fmaxf(fmaxf(fmaxf(sacc[2][0], sacc[2][1]), fmaxf(sacc[2][2], sacc[2][3])),
                                 fmaxf(fmaxf(sacc[3][0], sacc[3][1]), fmaxf(sacc[3][2], sacc[3][3]))));
        vmax = fmaxf(vmax, __shfl_xor(vmax, 16));
        vmax = fmaxf(vmax, __shfl_xor(vmax, 32));
        float mx = vmax * SCL2;
        if (__any(mx - m_ > 8.f)) {          // defer-max: rescale only on real growth
            float mn = fmaxf(m_, mx);
            float cr = exp2f(m_ - mn);
            l_ *= cr;
            m_ = mn;
            float crq[4];
            #pragma unroll
            for (int r = 0; r < 4; ++r) crq[r] = __shfl(cr, lg * 4 + r);
            #pragma unroll
            for (int ht = 0; ht < 4; ++ht)
                #pragma unroll
                for (int r = 0; r < 4; ++r) oacc[ht][r] *= crq[r];
        }

        // exp + in-register pack: u[kt*2+h] = bf16 pair (keys kt*16+lg*4+2h, +1)
        unsigned u[8];
        float lsum = 0.f;
        #pragma unroll
        for (int kt = 0; kt < 4; ++kt) {
            float p0 = exp2f(sacc[kt][0] * SCL2 - m_);
            float p1 = exp2f(sacc[kt][1] * SCL2 - m_);
            float p2 = exp2f(sacc[kt][2] * SCL2 - m_);
            float p3 = exp2f(sacc[kt][3] * SCL2 - m_);
            lsum += (p0 + p1) + (p2 + p3);
            u[kt * 2]     = cvtpk(p0, p1);
            u[kt * 2 + 1] = cvtpk(p2, p3);
        }
        lsum += __shfl_xor(lsum, 16);
        lsum += __shfl_xor(lsum, 32);
        l_ += lsum;

        // PV: A = P assembled in-register (permuted key order), B = V with matching permutation
        uint4 t0v = {u[0], u[1], u[2], u[3]};   // keys {lg*4+0..3, 16+lg*4+0..3}
        uint4 t1v = {u[4], u[5], u[6], u[7]};   // keys {32+lg*4+0..3, 48+lg*4+0..3}
        bf16x8 pa0 = __builtin_bit_cast(bf16x8, t0v);
        bf16x8 pa1 = __builtin_bit_cast(bf16x8, t1v);
        int half4 = (lg & 1) * 4;
        int csel = lg >> 1;
        #pragma unroll
        for (int ht = 0; ht < 4; ++ht) {
            int row = ht * 16 + lr;
            int rs7 = lr & 7;
            const ushort* vrow = Vl + row * 64;
            uint2 g0 = *(const uint2*)(vrow + ((csel) ^ rs7) * 8 + half4);
            uint2 g1 = *(const uint2*)(vrow + ((2 + csel) ^ rs7) * 8 + half4);
            uint2 g2 = *(const uint2*)(vrow + ((4 + csel) ^ rs7) * 8 + half4);
            uint2 g3 = *(const uint2*)(vrow + ((6 + csel) ^ rs7) * 8 + half4);
            uint4 v0 = {g0.x, g0.y, g1.x, g1.y};
            uint4 v1 = {g2.x, g2.y, g3.x, g3.y};
            bf16x8 vf0 = __builtin_bit_cast(bf16x8, v0);
            bf16x8 vf1 = __builtin_bit_cast(bf16x8, v1);
            oacc[ht] = MFMA16(pa0, vf0, oacc[ht]);
            oacc[ht] = MFMA16(pa1, vf1, oacc[ht]);
        }
    }

    // epilogue: O[q=lg*4+r][hd=ht*16+lr]
    float invl[4];
    #pragma unroll
    for (int r = 0; r < 4; ++r) invl[r] = 1.f / __shfl(l_, lg * 4 + r);
    int n0 = q0 + w * 16 + lg * 4;
    #pragma unroll
    for (int ht = 0; ht < 4; ++ht) {
        int hd = ht * 16 + lr;
        ushort4 o4;
        o4.x = f2bf(oacc[ht][0]);
        o4.y = f2bf(oacc[ht][1]);
        o4.z = f2bf(oacc[ht][2]);
        o4.w = f2bf(oacc[ht][3]);
        *(ushort4*)&Opart[(((size_t)chunk * BB + b) * 64 + hd) * NN + n0] = o4;
    }
    if (lg == 0) {
        int n = q0 + w * 16 + lr;
        ml[((size_t)b * NN + n) * 16 + chunk * 2]     = m_;
        ml[((size_t)b * NN + n) * 16 + chunk * 2 + 1] = l_;
    }
}

// NOTE: Opart epilogue stores O un-normalized? No — stores raw accum; combine divides by L.
// (kept identical semantics to previous rounds: Opart holds un-normalized O, ml holds m,l)

// ---------------- combine: x2 = sum_c O_c*w_c + x; fused stats partials ----------------
__global__ __launch_bounds__(256) void combine_kernel(const ushort* __restrict__ Opart,
                                                      const float* __restrict__ ml,
                                                      const float* __restrict__ x,
                                                      float* __restrict__ x2,
                                                      float* __restrict__ part2) {
    int i = blockIdx.x * 256 + threadIdx.x;   // 262144
    int n4 = i & 1023;
    int hd = (i >> 10) & 63;
    int b = i >> 16;
    int n0 = n4 << 2;
    float wgt[4][NCH];
    const float* mlp = ml + ((size_t)b * NN + n0) * 16;
    #pragma unroll
    for (int tk = 0; tk < 4; ++tk) {
        float m[NCH], l[NCH];
        const float4* p4 = (const float4*)(mlp + tk * 16);
        #pragma unroll
        for (int q = 0; q < 4; ++q) {
            float4 v = p4[q];
            m[q * 2] = v.x; l[q * 2] = v.y; m[q * 2 + 1] = v.z; l[q * 2 + 1] = v.w;
        }
        float M = m[0];
        #pragma unroll
        for (int c = 1; c < NCH; ++c) M = fmaxf(M, m[c]);
        float e[NCH], L = 0.f;
        #pragma unroll
        for (int c = 0; c < NCH; ++c) { e[c] = exp2f(m[c] - M); L += l[c] * e[c]; }
        float inv = 1.f / L;
        #pragma unroll
        for (int c = 0; c < NCH; ++c) wgt[tk][c] = e[c] * inv;
    }
    float4 acc = {0.f, 0.f, 0.f, 0.f};
    #pragma unroll
    for (int c = 0; c < NCH; ++c) {
        ushort4 o4 = *(const ushort4*)&Opart[(((size_t)c * BB + b) * 64 + hd) * NN + n0];
        acc.x += bf2f(o4.x) * wgt[0][c];
        acc.y += bf2f(o4.y) * wgt[1][c];
        acc.z += bf2f(o4.z) * wgt[2][c];
        acc.w += bf2f(o4.w) * wgt[3][c];
    }
    size_t off = ((size_t)b * 64 + hd) * NN + n0;
    float4 xv = *(const float4*)&x[off];
    acc.x += xv.x; acc.y += xv.y; acc.z += xv.z; acc.w += xv.w;
    *(float4*)&x2[off] = acc;

    float s = acc.x + acc.y + acc.z + acc.w;
    float s2 = acc.x * acc.x + acc.y * acc.y + acc.z * acc.z + acc.w * acc.w;
    #pragma unroll
    for (int off2 = 32; off2 > 0; off2 >>= 1) {
        s  += __shfl_xor(s, off2);
        s2 += __shfl_xor(s2, off2);
    }
    __shared__ float shs[4], shs2[4];
    int wid = threadIdx.x >> 6, lane = threadIdx.x & 63;
    if (lane == 0) { shs[wid] = s; shs2[wid] = s2; }
    __syncthreads();
    if (threadIdx.x == 0) {
        part2[blockIdx.x * 2]     = shs[0] + shs[1] + shs[2] + shs[3];
        part2[blockIdx.x * 2 + 1] = shs2[0] + shs2[1] + shs2[2] + shs2[3];
    }
}

// ---------------- fc1 MFMA: h1 = gelu(bn1(fc1w @ gn2(x2))) -> bf16 ----------------
// grid dim3(128, B): tokblk = bx>>1 (64 tok), half = bx&1 (128 outputs)
__global__ __launch_bounds__(256) void fc1_mfma(const float* __restrict__ x2,
                                                const ushort* __restrict__ fc1wb,
                                                const float* __restrict__ n2g,
                                                const float* __restrict__ n2b,
                                                const float* __restrict__ bn1g,
                                                const float* __restrict__ bn1b,
                                                const float* __restrict__ stats,
                                                ushort* __restrict__ h1) {
    int b = blockIdx.y;
    int tok0 = (blockIdx.x >> 1) * 64;
    int half = blockIdx.x & 1;
    int tid = threadIdx.x;
    int w = tid >> 6;
    int lr = tid & 15;
    int lg = (tid & 63) >> 4;
    float mu = stats[2 * 8 + b];
    float rs = stats[2 * 8 + 4 + b];
    __shared__ ushort Xt[64][64];     // [tok][chan], chunk-swizzled
    for (int k = 0; k < 16; ++k) {
        int e = tid + k * 256;
        int c = e >> 6, t = e & 63;
        float v = (x2[((size_t)(b * 64 + c)) * NN + tok0 + t] - mu) * rs * n2g[c] + n2b[c];
        Xt[t][((c >> 3) ^ (t & 7)) * 8 + (c & 7)] = f2bf(v);
    }
    __syncthreads();
    int brow = w * 16 + lr;
    bf16x8 bf0 = *(const bf16x8*)&Xt[brow][((0 + lg) ^ (lr & 7)) * 8];
    bf16x8 bf1 = *(const bf16x8*)&Xt[brow][((4 + lg) ^ (lr & 7)) * 8];
    f32x4 acc[8];
    #pragma unroll
    for (int mt = 0; mt < 8; ++mt) acc[mt] = (f32x4){0.f, 0.f, 0.f, 0.f};
    const ushort* wb = fc1wb + (size_t)(half * 128) * 64;
    #pragma unroll
    for (int mt = 0; mt < 8; ++mt) {
        bf16x8 a0 = *(const bf16x8*)&wb[(mt * 16 + lr) * 64 + lg * 8];
        bf16x8 a1 = *(const bf16x8*)&wb[(mt * 16 + lr) * 64 + 32 + lg * 8];
        acc[mt] = MFMA16(a0, bf0, acc[mt]);
        acc[mt] = MFMA16(a1, bf1, acc[mt]);
    }
    const float sb = rsqrtf(1.f + EPSV);
    int tok = tok0 + w * 16 + lr;
    #pragma unroll
    for (int mt = 0; mt < 8; ++mt) {
        #pragma unroll
        for (int r = 0; r < 4; ++r) {
            int o = half * 128 + mt * 16 + lg * 4 + r;
            float vv = acc[mt][r] * bn1g[o] * sb + bn1b[o];
            h1[((size_t)b * HID + o) * NN + tok] = f2bf(gelu_exact(vv));
        }
    }
}

// ---------------- mixer: LDS-tiled per (b,c) plane; dw + fft-scale + res + gelu + bnm ----------------
__global__ __launch_bounds__(256) void mixer_kernel(const ushort* __restrict__ h1,
                                                    const float* __restrict__ dw1w, const float* __restrict__ dw1b,
                                                    const float* __restrict__ dw3w, const float* __restrict__ dw3b,
                                                    const float* __restrict__ dw5w, const float* __restrict__ dw5b,
                                                    const float* __restrict__ dw7w, const float* __restrict__ dw7b,
                                                    const float* __restrict__ fftw,
                                                    const float* __restrict__ bnmg, const float* __restrict__ bnmb,
                                                    ushort* __restrict__ h2) {
    int c = blockIdx.x;
    int b = blockIdx.y;
    __shared__ ushort ls[70][72];
    uint* lz = (uint*)&ls[0][0];
    for (int i = threadIdx.x; i < 2520; i += 256) lz[i] = 0;
    __syncthreads();
    const ushort* plane = h1 + (((size_t)b * HID + c) << 12);
    for (int e = threadIdx.x; e < 4096; e += 256)
        ls[(e >> 6) + 3][(e & 63) + 3] = plane[e];
    __syncthreads();
    const float sb = rsqrtf(1.f + EPSV);
    float fw = fftw[c];
    float bg = bnmg[c] * sb, bb2 = bnmb[c];
    ushort* outp = h2 + (((size_t)b * HID + c) << 12);
    if (c < 64) {
        float w0 = dw1w[c], b0 = dw1b[c];
        for (int e = threadIdx.x; e < 4096; e += 256) {
            float ctr = bf2f(ls[(e >> 6) + 3][(e & 63) + 3]);
            float val = fw * (w0 * ctr + b0) + ctr;
            outp[e] = f2bf(gelu_exact(val) * bg + bb2);
        }
    } else if (c < 128) {
        int lc = c - 64;
        float wr[9];
        #pragma unroll
        for (int i = 0; i < 9; ++i) wr[i] = dw3w[lc * 9 + i];
        float b0 = dw3b[lc];
        for (int e = threadIdx.x; e < 4096; e += 256) {
            int y = e >> 6, x = e & 63;
            float acc = b0;
            #pragma unroll
            for (int dy = 0; dy < 3; ++dy)
                #pragma unroll
                for (int dx = 0; dx < 3; ++dx)
                    acc += wr[dy * 3 + dx] * bf2f(ls[y + 2 + dy][x + 2 + dx]);
            float ctr = bf2f(ls[y + 3][x + 3]);
            outp[e] = f2bf(gelu_exact(fw * acc + ctr) * bg + bb2);
        }
    } else if (c < 192) {
        int lc = c - 128;
        float wr[25];
        #pragma unroll
        for (int i = 0; i < 25; ++i) wr[i] = dw5w[lc * 25 + i];
        float b0 = dw5b[lc];
        for (int e = threadIdx.x; e < 4096; e += 256) {
            int y = e >> 6, x = e & 63;
            float acc = b0;
            #pragma unroll
            for (int dy = 0; dy < 5; ++dy)
                #pragma unroll
                for (int dx = 0; dx < 5; ++dx)
                    acc += wr[dy * 5 + dx] * bf2f(ls[y + 1 + dy][x + 1 + dx]);
            float ctr = bf2f(ls[y + 3][x + 3]);
            outp[e] = f2bf(gelu_exact(fw * acc + ctr) * bg + bb2);
        }
    } else {
        int lc = c - 192;
        float wr[49];
        #pragma unroll
        for (int i = 0; i < 49; ++i) wr[i] = dw7w[lc * 49 + i];
        float b0 = dw7b[lc];
        for (int e = threadIdx.x; e < 4096; e += 256) {
            int y = e >> 6, x = e & 63;
            float acc = b0;
            #pragma unroll
            for (int dy = 0; dy < 7; ++dy)
                #pragma unroll
                for (int dx = 0; dx < 7; ++dx)
                    acc += wr[dy * 7 + dx] * bf2f(ls[y + dy][x + dx]);
            float ctr = bf2f(ls[y + 3][x + 3]);
            outp[e] = f2bf(gelu_exact(fw * acc + ctr) * bg + bb2);
        }
    }
}

// ---------------- fc2 MFMA: out = bn2(fc2w @ h2) + x2 ----------------
// grid dim3(64, B): 64 tokens per block, all 64 outputs, K=256
__global__ __launch_bounds__(256) void fc2_mfma(const ushort* __restrict__ h2,
                                                const ushort* __restrict__ fc2wb,
                                                const float* __restrict__ bn2g,
                                                const float* __restrict__ bn2b,
                                                const float* __restrict__ x2,
                                                float* __restrict__ out) {
    int b = blockIdx.y;
    int tok0 = blockIdx.x * 64;
    int tid = threadIdx.x;
    int w = tid >> 6;
    int lr = tid & 15;
    int lg = (tid & 63) >> 4;
    __shared__ ushort Xt[64][256];    // [tok][chan], chunk-swizzled (32 KB)
    for (int k = 0; k < 8; ++k) {
        int e = tid + k * 256;        // 2048 chunks of 8 toks
        int c = e >> 3, t8 = (e & 7) * 8;
        bf16x8 v = *(const bf16x8*)&h2[((size_t)(b * 256 + c)) * NN + tok0 + t8];
        #pragma unroll
        for (int j = 0; j < 8; ++j) {
            int t = t8 + j;
            Xt[t][((c >> 3) ^ (t & 7)) * 8 + (c & 7)] = (ushort)v[j];
        }
    }
    __syncthreads();
    int brow = w * 16 + lr;
    f32x4 acc[4];
    #pragma unroll
    for (int mt = 0; mt < 4; ++mt) acc[mt] = (f32x4){0.f, 0.f, 0.f, 0.f};
    #pragma unroll
    for (int ks = 0; ks < 8; ++ks) {
        bf16x8 bfr = *(const bf16x8*)&Xt[brow][(((ks * 4 + lg) & 7) ^ (lr & 7)) * 8 + ((ks * 4 + lg) & ~7) * 8];
        #pragma unroll
        for (int mt = 0; mt < 4; ++mt) {
            bf16x8 a = *(const bf16x8*)&fc2wb[(mt * 16 + lr) * 256 + ks * 32 + lg * 8];
            acc[mt] = MFMA16(a, bfr, acc[mt]);
        }
    }
    const float sb = rsqrtf(1.f + EPSV);
    int tok = tok0 + w * 16 + lr;
    #pragma unroll
    for (int mt = 0; mt < 4; ++mt) {
        #pragma unroll
        for (int r = 0; r < 4; ++r) {
            int o = mt * 16 + lg * 4 + r;
            size_t off = ((size_t)b * 64 + o) * NN + tok;
            out[off] = acc[mt][r] * bn2g[o] * sb + bn2b[o] + x2[off];
        }
    }
}

extern "C" void kernel_launch(void* const* d_in, const int* in_sizes, int n_in,
                              void* d_out, int out_size, void* d_ws, size_t ws_size,
                              hipStream_t stream) {
    const float* x    = (const float*)d_in[0];
    const float* cnn  = (const float*)d_in[1];
    const float* n1g  = (const float*)d_in[2];
    const float* n1b  = (const float*)d_in[3];
    const float* n2g  = (const float*)d_in[4];
    const float* n2b  = (const float*)d_in[5];
    const float* n3g  = (const float*)d_in[6];
    const float* n3b  = (const float*)d_in[7];
    const float* qw   = (const float*)d_in[8];
    const float* qb   = (const float*)d_in[9];
    const float* kvw  = (const float*)d_in[10];
    const float* kvb  = (const float*)d_in[11];
    const float* lcw  = (const float*)d_in[12];
    const float* lcb  = (const float*)d_in[13];
    const float* fc1w = (const float*)d_in[14];
    const float* bn1g = (const float*)d_in[15];
    const float* bn1b = (const float*)d_in[16];
    const float* dw1w = (const float*)d_in[17];
    const float* dw1b = (const float*)d_in[18];
    const float* dw3w = (const float*)d_in[19];
    const float* dw3b = (const float*)d_in[20];
    const float* dw5w = (const float*)d_in[21];
    const float* dw5b = (const float*)d_in[22];
    const float* dw7w = (const float*)d_in[23];
    const float* dw7b = (const float*)d_in[24];
    const float* bnmg = (const float*)d_in[25];
    const float* bnmb = (const float*)d_in[26];
    const float* fftw = (const float*)d_in[27];
    const float* fc2w = (const float*)d_in[28];
    const float* bn2g = (const float*)d_in[29];
    const float* bn2b = (const float*)d_in[30];

    float* ws = (float*)d_ws;
    float* stats = ws;                     // 64
    float* part  = ws + 64;                // 1024
    float* part2 = ws + 1088;              // 2048
    float* base  = ws + 3200;
    const size_t M = 1048576;
    float* x2     = base;                              // [0, 1M)
    ushort* qr_bf = (ushort*)(base + M);               // [1M, 1.5M)
    ushort* kr_bf = (ushort*)(base + M + M / 2);       // [1.5M, 2M)
    ushort* vt_bf = (ushort*)(base + 2 * M);           // [2M, 2.5M)
    float* kvin   = base + 5 * M / 2;                  // [2.5M, 3.5M)
    ushort* Opart = (ushort*)(base + 7 * M / 2);       // [3.5M, 7.5M)
    float* ml     = base + 15 * M / 2;                 // [7.5M, 7.75M)
    ushort* h1 = (ushort*)(base + M);                  // overlay qr/kr/vt/kvin
    ushort* h2 = (ushort*)(base + 7 * M / 2);          // overlay Opart head
    ushort* fc1wb = (ushort*)(base + 8 * M);           // 16384 ushorts
    ushort* fc2wb = fc1wb + 16384;                     // 16384 ushorts
    float* outp = (float*)d_out;

    wprep_kernel<<<128, 256, 0, stream>>>(fc1w, fc2w, fc1wb, fc2wb);
    stats_pair_kernel<<<dim3(64, 4), 256, 0, stream>>>(x, cnn, part);
    stats_fin_kernel<<<8, 64, 0, stream>>>(part, stats);
    dw3k_kernel<<<4096, 256, 0, stream>>>(cnn, n3g, n3b, lcw, lcb, stats, kvin);
    q_kernel<<<dim3(128, 4), 256, 0, stream>>>(x, n1g, n1b, qw, qb, stats, qr_bf);
    kv_kernel<<<dim3(256, 4), 256, 0, stream>>>(kvin, kvw, kvb, kr_bf, vt_bf);
    attn_kernel<<<dim3(64, 4, NCH), 256, 0, stream>>>(qr_bf, kr_bf, vt_bf, Opart, ml);
    combine_kernel<<<1024, 256, 0, stream>>>(Opart, ml, x, x2, part2);
    stats2b_kernel<<<4, 256, 0, stream>>>(part2, stats, 2);
    fc1_mfma<<<dim3(128, 4), 256, 0, stream>>>(x2, fc1wb, n2g, n2b, bn1g, bn1b, stats, h1);
    mixer_kernel<<<dim3(HID, 4), 256, 0, stream>>>(h1, dw1w, dw1b, dw3w, dw3b, dw5w, dw5b,
                                                   dw7w, dw7b, fftw, bnmg, bnmb, h2);
    fc2_mfma<<<dim3(64, 4), 256, 0, stream>>>(h2, fc2wb, bn2g, bn2b, x2, outp);
}

// Round 9
// 147.486 us; speedup vs baseline: 10.0394x; 1.3138x over previous
//
#include <hip/hip_runtime.h>
#include <hip/hip_bf16.h>
#include <math.h>

#define BB 4
#define CC 64
#define NN 4096
#define HD 64
#define HID 256
#define EPSV 1e-5f
#define CNT (CC*NN)
#define NCH 8            // KV split chunks

typedef float f32x4 __attribute__((ext_vector_type(4)));
typedef short bf16x8 __attribute__((ext_vector_type(8)));
typedef short bf16x4 __attribute__((ext_vector_type(4)));
#define MFMA16(a, b, c) __builtin_amdgcn_mfma_f32_16x16x32_bf16(a, b, c, 0, 0, 0)

__device__ __forceinline__ float gelu_exact(float x) {
    return 0.5f * x * (1.0f + erff(x * 0.70710678118654752f));
}
__device__ __forceinline__ ushort f2bf(float f) {
    unsigned u = __float_as_uint(f);
    unsigned r = (u + 0x7FFFu + ((u >> 16) & 1u)) >> 16;
    return (ushort)r;
}
__device__ __forceinline__ float bf2f(ushort u) {
    return __uint_as_float(((unsigned)u) << 16);
}
__device__ __forceinline__ unsigned cvtpk(float lo, float hi) {
    unsigned r;
    asm("v_cvt_pk_bf16_f32 %0, %1, %2" : "=v"(r) : "v"(lo), "v"(hi));
    return r;
}
__device__ __forceinline__ void unpack2(unsigned u, float& lo, float& hi) {
    lo = __uint_as_float(u << 16);
    hi = __uint_as_float(u & 0xffff0000u);
}

// ---------------- weight prep: fp32 -> bf16 ----------------
__global__ __launch_bounds__(256) void wprep_kernel(const float* __restrict__ fc1w,
                                                    const float* __restrict__ fc2w,
                                                    ushort* __restrict__ fc1wb,
                                                    ushort* __restrict__ fc2wb) {
    int i = blockIdx.x * 256 + threadIdx.x;   // 32768
    if (i < 16384) fc1wb[i] = f2bf(fc1w[i]);
    else fc2wb[i - 16384] = f2bf(fc2w[i - 16384]);
}

// ---------------- fused stats stage 1 for x and cnn ----------------
__global__ __launch_bounds__(256) void stats_pair_kernel(const float* __restrict__ x,
                                                         const float* __restrict__ cnn,
                                                         float* __restrict__ part) {
    int b = blockIdx.y;
    int blk = blockIdx.x;
    const float4* p0 = (const float4*)(x + (size_t)b * CNT);
    const float4* p1 = (const float4*)(cnn + (size_t)b * CNT);
    float s0 = 0.f, s20 = 0.f, s1 = 0.f, s21 = 0.f;
    #pragma unroll
    for (int k = 0; k < 4; ++k) {
        float4 v = p0[blk * 1024 + k * 256 + threadIdx.x];
        s0  += v.x + v.y + v.z + v.w;
        s20 += v.x * v.x + v.y * v.y + v.z * v.z + v.w * v.w;
        float4 u = p1[blk * 1024 + k * 256 + threadIdx.x];
        s1  += u.x + u.y + u.z + u.w;
        s21 += u.x * u.x + u.y * u.y + u.z * u.z + u.w * u.w;
    }
    #pragma unroll
    for (int off = 32; off > 0; off >>= 1) {
        s0  += __shfl_xor(s0, off);
        s20 += __shfl_xor(s20, off);
        s1  += __shfl_xor(s1, off);
        s21 += __shfl_xor(s21, off);
    }
    __shared__ float sh[4][4];
    int wid = threadIdx.x >> 6, lane = threadIdx.x & 63;
    if (lane == 0) { sh[wid][0] = s0; sh[wid][1] = s20; sh[wid][2] = s1; sh[wid][3] = s21; }
    __syncthreads();
    if (threadIdx.x == 0) {
        float a0 = sh[0][0] + sh[1][0] + sh[2][0] + sh[3][0];
        float a1 = sh[0][1] + sh[1][1] + sh[2][1] + sh[3][1];
        float a2 = sh[0][2] + sh[1][2] + sh[2][2] + sh[3][2];
        float a3 = sh[0][3] + sh[1][3] + sh[2][3] + sh[3][3];
        part[((0 * 4 + b) * 64 + blk) * 2]     = a0;
        part[((0 * 4 + b) * 64 + blk) * 2 + 1] = a1;
        part[((1 * 4 + b) * 64 + blk) * 2]     = a2;
        part[((1 * 4 + b) * 64 + blk) * 2 + 1] = a3;
    }
}

// ---------------- stats finalize (both slots) ----------------
__global__ __launch_bounds__(64) void stats_fin_kernel(const float* __restrict__ part,
                                                       float* __restrict__ stats) {
    int sb_ = blockIdx.x;    // slot*4 + b
    int lane = threadIdx.x;
    float s = part[(sb_ * 64 + lane) * 2];
    float s2 = part[(sb_ * 64 + lane) * 2 + 1];
    #pragma unroll
    for (int off = 32; off > 0; off >>= 1) {
        s  += __shfl_xor(s, off);
        s2 += __shfl_xor(s2, off);
    }
    if (lane == 0) {
        int slot = sb_ >> 2, b = sb_ & 3;
        float mu = s / (float)CNT;
        float var = s2 / (float)CNT - mu * mu;
        stats[slot * 8 + b] = mu;
        stats[slot * 8 + 4 + b] = rsqrtf(var + EPSV);
    }
}

// ---------------- stats stage 2b (256 partials, slot 2) ----------------
__global__ __launch_bounds__(256) void stats2b_kernel(const float* __restrict__ part2,
                                                      float* __restrict__ stats, int slot) {
    int b = blockIdx.x;
    int t = threadIdx.x;
    float s = part2[(b * 256 + t) * 2];
    float s2 = part2[(b * 256 + t) * 2 + 1];
    #pragma unroll
    for (int off = 32; off > 0; off >>= 1) {
        s  += __shfl_xor(s, off);
        s2 += __shfl_xor(s2, off);
    }
    __shared__ float shs[4], shs2[4];
    int wid = t >> 6, lane = t & 63;
    if (lane == 0) { shs[wid] = s; shs2[wid] = s2; }
    __syncthreads();
    if (t == 0) {
        float S = shs[0] + shs[1] + shs[2] + shs[3];
        float S2 = shs2[0] + shs2[1] + shs2[2] + shs2[3];
        float mu = S / (float)CNT;
        float var = S2 / (float)CNT - mu * mu;
        stats[slot * 8 + b] = mu;
        stats[slot * 8 + 4 + b] = rsqrtf(var + EPSV);
    }
}

// ---------------- dw3k: kvin = dw3(gn(cnn)) + bias + gn(cnn) ----------------
__global__ __launch_bounds__(256) void dw3k_kernel(const float* __restrict__ cnn,
                                                   const float* __restrict__ n3g,
                                                   const float* __restrict__ n3b,
                                                   const float* __restrict__ lcw,
                                                   const float* __restrict__ lcb,
                                                   const float* __restrict__ stats,
                                                   float* __restrict__ kvin) {
    int i = blockIdx.x * 256 + threadIdx.x;   // 1,048,576
    int x = i & 63;
    int y = (i >> 6) & 63;
    int c = (i >> 12) & 63;
    int b = i >> 18;
    float mu = stats[1 * 8 + b];
    float rs = stats[1 * 8 + 4 + b];
    float sc = rs * n3g[c];
    float of = n3b[c] - mu * sc;
    const float* plane = cnn + ((size_t)(i >> 12) << 12);
    float acc = lcb[c];
    #pragma unroll
    for (int dy = 0; dy < 3; ++dy) {
        int yy = y + dy - 1;
        if (yy < 0 || yy >= 64) continue;
        #pragma unroll
        for (int dx = 0; dx < 3; ++dx) {
            int xx = x + dx - 1;
            if (xx < 0 || xx >= 64) continue;
            acc += lcw[c * 9 + dy * 3 + dx] * (plane[(yy << 6) + xx] * sc + of);
        }
    }
    kvin[i] = acc + plane[(y << 6) + x] * sc + of;
}

// ---------------- Q: gn(x) + proj + inline RoPE -> bf16 (B,N,HD) ----------------
__global__ __launch_bounds__(256) void q_kernel(const float* __restrict__ x,
                                                const float* __restrict__ n1g,
                                                const float* __restrict__ n1b,
                                                const float* __restrict__ qw,
                                                const float* __restrict__ qb,
                                                const float* __restrict__ stats,
                                                ushort* __restrict__ qr) {
    int b = blockIdx.y;
    int tok0 = (blockIdx.x >> 1) * 64;
    int obase = (blockIdx.x & 1) * 32 + (threadIdx.x >> 6) * 8;
    int tl = threadIdx.x & 63;
    int tok = tok0 + tl;
    float mu = stats[0 * 8 + b];
    float rs = stats[0 * 8 + 4 + b];
    __shared__ float xs[64][64];
    for (int k = 0; k < 16; ++k) {
        int e = threadIdx.x + k * 256;
        int c = e >> 6;
        xs[c][e & 63] = (x[((size_t)(b * 64 + c)) * NN + tok0 + (e & 63)] - mu) * rs * n1g[c] + n1b[c];
    }
    __syncthreads();
    float xc[64];
    #pragma unroll
    for (int c = 0; c < 64; ++c) xc[c] = xs[c][tl];
    int hh = tok >> 6, ww = tok & 63;
    float st[4], ct[4];
    #pragma unroll
    for (int p = 0; p < 4; ++p) {
        int o = obase + 2 * p;
        int j = (o & 31) >> 1;
        float freq = exp2f(-0.88584749f * (float)j);
        float pos = (o < 32) ? (float)hh : (float)ww;
        __sincosf(pos * freq, &st[p], &ct[p]);
    }
    ushort* qrow = qr + ((size_t)b * NN + tok) * 64;
    #pragma unroll
    for (int p = 0; p < 4; ++p) {
        int o = obase + 2 * p;
        float a0 = qb[o], a1 = qb[o + 1];
        #pragma unroll
        for (int c = 0; c < 64; ++c) {
            a0 += qw[o * 64 + c] * xc[c];
            a1 += qw[(o + 1) * 64 + c] * xc[c];
        }
        qrow[o]     = f2bf(a0 * ct[p] - a1 * st[p]);
        qrow[o + 1] = f2bf(a1 * ct[p] + a0 * st[p]);
    }
}

// ---------------- KV proj from kvin; K+inline RoPE (B,N,HD); V^T (B,HD,N) ----------------
__global__ __launch_bounds__(256) void kv_kernel(const float* __restrict__ kvin,
                                                 const float* __restrict__ kvw,
                                                 const float* __restrict__ kvb,
                                                 ushort* __restrict__ kr,
                                                 ushort* __restrict__ vt) {
    int b = blockIdx.y;
    int tok0 = (blockIdx.x >> 2) * 64;
    int obase = (blockIdx.x & 3) * 32 + (threadIdx.x >> 6) * 8;
    int tl = threadIdx.x & 63;
    int tok = tok0 + tl;
    __shared__ float xs[64][64];
    for (int k = 0; k < 16; ++k) {
        int e = threadIdx.x + k * 256;
        xs[e >> 6][e & 63] = kvin[((size_t)(b * 64 + (e >> 6))) * NN + tok0 + (e & 63)];
    }
    __syncthreads();
    float xc[64];
    #pragma unroll
    for (int c = 0; c < 64; ++c) xc[c] = xs[c][tl];
    if (obase < 64) {
        int hh = tok >> 6, ww = tok & 63;
        float st[4], ct[4];
        #pragma unroll
        for (int p = 0; p < 4; ++p) {
            int o = obase + 2 * p;
            int j = (o & 31) >> 1;
            float freq = exp2f(-0.88584749f * (float)j);
            float pos = (o < 32) ? (float)hh : (float)ww;
            __sincosf(pos * freq, &st[p], &ct[p]);
        }
        ushort* krow = kr + ((size_t)b * NN + tok) * 64;
        #pragma unroll
        for (int p = 0; p < 4; ++p) {
            int o = obase + 2 * p;
            float a0 = kvb[o], a1 = kvb[o + 1];
            #pragma unroll
            for (int c = 0; c < 64; ++c) {
                a0 += kvw[o * 64 + c] * xc[c];
                a1 += kvw[(o + 1) * 64 + c] * xc[c];
            }
            krow[o]     = f2bf(a0 * ct[p] - a1 * st[p]);
            krow[o + 1] = f2bf(a1 * ct[p] + a0 * st[p]);
        }
    } else {
        #pragma unroll
        for (int oo = 0; oo < 8; ++oo) {
            int oa = obase + oo;            // [64,128)
            float a0 = kvb[oa];
            #pragma unroll
            for (int c = 0; c < 64; ++c) a0 += kvw[oa * 64 + c] * xc[c];
            vt[((size_t)b * 64 + (oa - 64)) * NN + tok] = f2bf(a0);
        }
    }
}

// ---------------- MFMA flash attention v3: swapped QK^T, in-register P ----------------
// grid dim3(64, B, NCH), 256 thr = 4 waves x 16 q-rows; KV tile 64; chunk = 512 keys
__global__ __launch_bounds__(256) void attn_kernel(const ushort* __restrict__ qr,
                                                   const ushort* __restrict__ kr,
                                                   const ushort* __restrict__ vt,
                                                   ushort* __restrict__ Opart,
                                                   float* __restrict__ ml) {
    int b = blockIdx.y;
    int q0 = blockIdx.x * 64;
    int chunk = blockIdx.z;
    int tid = threadIdx.x;
    int w = tid >> 6;
    int lane = tid & 63;
    int lr = lane & 15;
    int lg = lane >> 4;
    const float SCL2 = 0.125f * 1.44269504f;   // HD^-0.5 * log2(e)

    __shared__ ushort Kl[64 * 64];
    __shared__ ushort Vl[64 * 64];

    bf16x8 qf[2];
    {
        const ushort* qp = qr + ((size_t)b * NN + q0 + w * 16 + lr) * 64;
        qf[0] = *(const bf16x8*)(qp + lg * 8);
        qf[1] = *(const bf16x8*)(qp + 32 + lg * 8);
    }

    f32x4 oacc[4];
    #pragma unroll
    for (int t = 0; t < 4; ++t) oacc[t] = (f32x4){0.f, 0.f, 0.f, 0.f};
    float m_ = -INFINITY, l_ = 0.f;     // scalar state for q-row = q0+w*16+lr

    const size_t kbase = ((size_t)b * NN) * 64;
    const int t0 = chunk * 8, tend = t0 + 8;

    for (int t = t0; t < tend; ++t) {
        int k0 = t * 64;
        __syncthreads();
        #pragma unroll
        for (int it = 0; it < 2; ++it) {
            int e = tid + it * 256;
            int row = e >> 3, cib = e & 7;
            int sw = cib ^ (row & 7);
            *(bf16x8*)(Kl + row * 64 + sw * 8) =
                *(const bf16x8*)(kr + kbase + (size_t)(k0 + row) * 64 + cib * 8);
            *(bf16x8*)(Vl + row * 64 + sw * 8) =
                *(const bf16x8*)(vt + ((size_t)b * 64 + row) * NN + k0 + cib * 8);
        }
        __syncthreads();

        // S^T = K Q : C[key][q], lane holds q=lr, key = kt*16 + lg*4 + r
        f32x4 sacc[4];
        #pragma unroll
        for (int kt = 0; kt < 4; ++kt) {
            int row = kt * 16 + lr;
            bf16x8 k0f = *(const bf16x8*)(Kl + row * 64 + ((0 * 4 + lg) ^ (lr & 7)) * 8);
            bf16x8 k1f = *(const bf16x8*)(Kl + row * 64 + ((1 * 4 + lg) ^ (lr & 7)) * 8);
            f32x4 z = {0.f, 0.f, 0.f, 0.f};
            z = MFMA16(k0f, qf[0], z);
            sacc[kt] = MFMA16(k1f, qf[1], z);
        }

        float vmax = fmaxf(fmaxf(fmaxf(sacc[0][0], sacc[0][1]), fmaxf(sacc[0][2], sacc[0][3])),
                           fmaxf(fmaxf(sacc[1][0], sacc[1][1]), fmaxf(sacc[1][2], sacc[1][3])));
        vmax = fmaxf(vmax, fmaxf(fmaxf(fmaxf(sacc[2][0], sacc[2][1]), fmaxf(sacc[2][2], sacc[2][3])),
                                 fmaxf(fmaxf(sacc[3][0], sacc[3][1]), fmaxf(sacc[3][2], sacc[3][3]))));
        vmax = fmaxf(vmax, __shfl_xor(vmax, 16));
        vmax = fmaxf(vmax, __shfl_xor(vmax, 32));
        float mx = vmax * SCL2;
        if (__any(mx - m_ > 8.f)) {
            float mn = fmaxf(m_, mx);
            float cr = exp2f(m_ - mn);
            l_ *= cr;
            m_ = mn;
            float crq[4];
            #pragma unroll
            for (int r = 0; r < 4; ++r) crq[r] = __shfl(cr, lg * 4 + r);
            #pragma unroll
            for (int ht = 0; ht < 4; ++ht)
                #pragma unroll
                for (int r = 0; r < 4; ++r) oacc[ht][r] *= crq[r];
        }

        unsigned u[8];
        float lsum = 0.f;
        #pragma unroll
        for (int kt = 0; kt < 4; ++kt) {
            float p0 = exp2f(sacc[kt][0] * SCL2 - m_);
            float p1 = exp2f(sacc[kt][1] * SCL2 - m_);
            float p2 = exp2f(sacc[kt][2] * SCL2 - m_);
            float p3 = exp2f(sacc[kt][3] * SCL2 - m_);
            lsum += (p0 + p1) + (p2 + p3);
            u[kt * 2]     = cvtpk(p0, p1);
            u[kt * 2 + 1] = cvtpk(p2, p3);
        }
        lsum += __shfl_xor(lsum, 16);
        lsum += __shfl_xor(lsum, 32);
        l_ += lsum;

        uint4 t0v = {u[0], u[1], u[2], u[3]};
        uint4 t1v = {u[4], u[5], u[6], u[7]};
        bf16x8 pa0 = __builtin_bit_cast(bf16x8, t0v);
        bf16x8 pa1 = __builtin_bit_cast(bf16x8, t1v);
        int half4 = (lg & 1) * 4;
        int csel = lg >> 1;
        #pragma unroll
        for (int ht = 0; ht < 4; ++ht) {
            int row = ht * 16 + lr;
            int rs7 = lr & 7;
            const ushort* vrow = Vl + row * 64;
            uint2 g0 = *(const uint2*)(vrow + ((csel) ^ rs7) * 8 + half4);
            uint2 g1 = *(const uint2*)(vrow + ((2 + csel) ^ rs7) * 8 + half4);
            uint2 g2 = *(const uint2*)(vrow + ((4 + csel) ^ rs7) * 8 + half4);
            uint2 g3 = *(const uint2*)(vrow + ((6 + csel) ^ rs7) * 8 + half4);
            uint4 v0 = {g0.x, g0.y, g1.x, g1.y};
            uint4 v1 = {g2.x, g2.y, g3.x, g3.y};
            bf16x8 vf0 = __builtin_bit_cast(bf16x8, v0);
            bf16x8 vf1 = __builtin_bit_cast(bf16x8, v1);
            oacc[ht] = MFMA16(pa0, vf0, oacc[ht]);
            oacc[ht] = MFMA16(pa1, vf1, oacc[ht]);
        }
    }

    int n0 = q0 + w * 16 + lg * 4;
    #pragma unroll
    for (int ht = 0; ht < 4; ++ht) {
        int hd = ht * 16 + lr;
        ushort4 o4;
        o4.x = f2bf(oacc[ht][0]);
        o4.y = f2bf(oacc[ht][1]);
        o4.z = f2bf(oacc[ht][2]);
        o4.w = f2bf(oacc[ht][3]);
        *(ushort4*)&Opart[(((size_t)chunk * BB + b) * 64 + hd) * NN + n0] = o4;
    }
    if (lg == 0) {
        int n = q0 + w * 16 + lr;
        ml[((size_t)b * NN + n) * 16 + chunk * 2]     = m_;
        ml[((size_t)b * NN + n) * 16 + chunk * 2 + 1] = l_;
    }
}

// ---------------- combine: x2 = sum_c O_c*w_c + x; fused stats partials ----------------
__global__ __launch_bounds__(256) void combine_kernel(const ushort* __restrict__ Opart,
                                                      const float* __restrict__ ml,
                                                      const float* __restrict__ x,
                                                      float* __restrict__ x2,
                                                      float* __restrict__ part2) {
    int i = blockIdx.x * 256 + threadIdx.x;   // 262144
    int n4 = i & 1023;
    int hd = (i >> 10) & 63;
    int b = i >> 16;
    int n0 = n4 << 2;
    float wgt[4][NCH];
    const float* mlp = ml + ((size_t)b * NN + n0) * 16;
    #pragma unroll
    for (int tk = 0; tk < 4; ++tk) {
        float m[NCH], l[NCH];
        const float4* p4 = (const float4*)(mlp + tk * 16);
        #pragma unroll
        for (int q = 0; q < 4; ++q) {
            float4 v = p4[q];
            m[q * 2] = v.x; l[q * 2] = v.y; m[q * 2 + 1] = v.z; l[q * 2 + 1] = v.w;
        }
        float M = m[0];
        #pragma unroll
        for (int c = 1; c < NCH; ++c) M = fmaxf(M, m[c]);
        float e[NCH], L = 0.f;
        #pragma unroll
        for (int c = 0; c < NCH; ++c) { e[c] = exp2f(m[c] - M); L += l[c] * e[c]; }
        float inv = 1.f / L;
        #pragma unroll
        for (int c = 0; c < NCH; ++c) wgt[tk][c] = e[c] * inv;
    }
    float4 acc = {0.f, 0.f, 0.f, 0.f};
    #pragma unroll
    for (int c = 0; c < NCH; ++c) {
        ushort4 o4 = *(const ushort4*)&Opart[(((size_t)c * BB + b) * 64 + hd) * NN + n0];
        acc.x += bf2f(o4.x) * wgt[0][c];
        acc.y += bf2f(o4.y) * wgt[1][c];
        acc.z += bf2f(o4.z) * wgt[2][c];
        acc.w += bf2f(o4.w) * wgt[3][c];
    }
    size_t off = ((size_t)b * 64 + hd) * NN + n0;
    float4 xv = *(const float4*)&x[off];
    acc.x += xv.x; acc.y += xv.y; acc.z += xv.z; acc.w += xv.w;
    *(float4*)&x2[off] = acc;

    float s = acc.x + acc.y + acc.z + acc.w;
    float s2 = acc.x * acc.x + acc.y * acc.y + acc.z * acc.z + acc.w * acc.w;
    #pragma unroll
    for (int off2 = 32; off2 > 0; off2 >>= 1) {
        s  += __shfl_xor(s, off2);
        s2 += __shfl_xor(s2, off2);
    }
    __shared__ float shs[4], shs2[4];
    int wid = threadIdx.x >> 6, lane = threadIdx.x & 63;
    if (lane == 0) { shs[wid] = s; shs2[wid] = s2; }
    __syncthreads();
    if (threadIdx.x == 0) {
        part2[blockIdx.x * 2]     = shs[0] + shs[1] + shs[2] + shs[3];
        part2[blockIdx.x * 2 + 1] = shs2[0] + shs2[1] + shs2[2] + shs2[3];
    }
}

// ---------------- fc1 MFMA: h1 = gelu(bn1(fc1w @ gn2(x2))) -> bf16 ----------------
__global__ __launch_bounds__(256) void fc1_mfma(const float* __restrict__ x2,
                                                const ushort* __restrict__ fc1wb,
                                                const float* __restrict__ n2g,
                                                const float* __restrict__ n2b,
                                                const float* __restrict__ bn1g,
                                                const float* __restrict__ bn1b,
                                                const float* __restrict__ stats,
                                                ushort* __restrict__ h1) {
    int b = blockIdx.y;
    int tok0 = (blockIdx.x >> 1) * 64;
    int half = blockIdx.x & 1;
    int tid = threadIdx.x;
    int w = tid >> 6;
    int lr = tid & 15;
    int lg = (tid & 63) >> 4;
    float mu = stats[2 * 8 + b];
    float rs = stats[2 * 8 + 4 + b];
    __shared__ ushort Xt[64][64];     // [tok][chan], chunk-swizzled
    for (int k = 0; k < 16; ++k) {
        int e = tid + k * 256;
        int c = e >> 6, t = e & 63;
        float v = (x2[((size_t)(b * 64 + c)) * NN + tok0 + t] - mu) * rs * n2g[c] + n2b[c];
        Xt[t][((c >> 3) ^ (t & 7)) * 8 + (c & 7)] = f2bf(v);
    }
    __syncthreads();
    int brow = w * 16 + lr;
    bf16x8 bf0 = *(const bf16x8*)&Xt[brow][((0 + lg) ^ (lr & 7)) * 8];
    bf16x8 bf1 = *(const bf16x8*)&Xt[brow][((4 + lg) ^ (lr & 7)) * 8];
    f32x4 acc[8];
    #pragma unroll
    for (int mt = 0; mt < 8; ++mt) acc[mt] = (f32x4){0.f, 0.f, 0.f, 0.f};
    const ushort* wb = fc1wb + (size_t)(half * 128) * 64;
    #pragma unroll
    for (int mt = 0; mt < 8; ++mt) {
        bf16x8 a0 = *(const bf16x8*)&wb[(mt * 16 + lr) * 64 + lg * 8];
        bf16x8 a1 = *(const bf16x8*)&wb[(mt * 16 + lr) * 64 + 32 + lg * 8];
        acc[mt] = MFMA16(a0, bf0, acc[mt]);
        acc[mt] = MFMA16(a1, bf1, acc[mt]);
    }
    const float sb = rsqrtf(1.f + EPSV);
    int tok = tok0 + w * 16 + lr;
    #pragma unroll
    for (int mt = 0; mt < 8; ++mt) {
        #pragma unroll
        for (int r = 0; r < 4; ++r) {
            int o = half * 128 + mt * 16 + lg * 4 + r;
            float vv = acc[mt][r] * bn1g[o] * sb + bn1b[o];
            h1[((size_t)b * HID + o) * NN + tok] = f2bf(gelu_exact(vv));
        }
    }
}

// ---------------- mixer v2: register sliding-window; 32-row half planes ----------------
// grid dim3(512, B): c = bx>>1, half = bx&1. 256 thr: row = t>>3, x0 = (t&7)*8.
// LDS tile ls[38][80] bf16: row i = global row r0+i-3; col xp = global col xp-4. Zero halo.
__global__ __launch_bounds__(256) void mixer_kernel(const ushort* __restrict__ h1,
                                                    const float* __restrict__ dw1w, const float* __restrict__ dw1b,
                                                    const float* __restrict__ dw3w, const float* __restrict__ dw3b,
                                                    const float* __restrict__ dw5w, const float* __restrict__ dw5b,
                                                    const float* __restrict__ dw7w, const float* __restrict__ dw7b,
                                                    const float* __restrict__ fftw,
                                                    const float* __restrict__ bnmg, const float* __restrict__ bnmb,
                                                    ushort* __restrict__ h2) {
    int c = blockIdx.x >> 1;
    int r0 = (blockIdx.x & 1) * 32;
    int b = blockIdx.y;
    int tid = threadIdx.x;
    __shared__ ushort ls[38][80];      // 6080 B
    uint* lz = (uint*)&ls[0][0];
    #pragma unroll
    for (int k = 0; k < 6; ++k) {
        int i = tid + k * 256;
        if (i < 1520) lz[i] = 0;
    }
    __syncthreads();
    const ushort* plane = h1 + (((size_t)b * HID + c) << 12);
    for (int e = tid; e < 304; e += 256) {
        int i = e >> 3, xc = e & 7;
        int gr = r0 + i - 3;
        if (gr >= 0 && gr < 64) {
            bf16x8 v = *(const bf16x8*)&plane[(gr << 6) + xc * 8];
            bf16x4 lo = {v[0], v[1], v[2], v[3]};
            bf16x4 hi = {v[4], v[5], v[6], v[7]};
            *(bf16x4*)&ls[i][xc * 8 + 4] = lo;
            *(bf16x4*)&ls[i][xc * 8 + 8] = hi;
        }
    }
    __syncthreads();

    int yy = tid >> 3;
    int x0 = (tid & 7) * 8;
    const float sb = rsqrtf(1.f + EPSV);
    float fw = fftw[c];
    float bg = bnmg[c] * sb, bb2 = bnmb[c];
    float acc[8], ctr[8];
    #pragma unroll
    for (int j = 0; j < 8; ++j) acc[j] = 0.f;

    if (c < 64) {
        float w0 = dw1w[c], b0 = dw1b[c];
        uint4 ua = *(const uint4*)&ls[yy + 3][x0];
        uint4 ub = *(const uint4*)&ls[yy + 3][x0 + 8];
        float wv[16];
        unpack2(ua.x, wv[0], wv[1]); unpack2(ua.y, wv[2], wv[3]);
        unpack2(ua.z, wv[4], wv[5]); unpack2(ua.w, wv[6], wv[7]);
        unpack2(ub.x, wv[8], wv[9]); unpack2(ub.y, wv[10], wv[11]);
        unpack2(ub.z, wv[12], wv[13]); unpack2(ub.w, wv[14], wv[15]);
        #pragma unroll
        for (int j = 0; j < 8; ++j) { ctr[j] = wv[j + 4]; acc[j] = w0 * ctr[j] + b0; }
    } else if (c < 128) {
        int lc = c - 64;
        float b0 = dw3b[lc];
        #pragma unroll
        for (int j = 0; j < 8; ++j) acc[j] = b0;
        #pragma unroll
        for (int dy = 0; dy < 3; ++dy) {
            int i = yy + dy + 2;
            uint4 ua = *(const uint4*)&ls[i][x0];
            uint4 ub = *(const uint4*)&ls[i][x0 + 8];
            float wv[16];
            unpack2(ua.x, wv[0], wv[1]); unpack2(ua.y, wv[2], wv[3]);
            unpack2(ua.z, wv[4], wv[5]); unpack2(ua.w, wv[6], wv[7]);
            unpack2(ub.x, wv[8], wv[9]); unpack2(ub.y, wv[10], wv[11]);
            unpack2(ub.z, wv[12], wv[13]); unpack2(ub.w, wv[14], wv[15]);
            if (dy == 1) {
                #pragma unroll
                for (int j = 0; j < 8; ++j) ctr[j] = wv[j + 4];
            }
            #pragma unroll
            for (int dx = 0; dx < 3; ++dx) {
                float wt = dw3w[lc * 9 + dy * 3 + dx];
                #pragma unroll
                for (int j = 0; j < 8; ++j) acc[j] += wt * wv[j + dx + 3];
            }
        }
    } else if (c < 192) {
        int lc = c - 128;
        float b0 = dw5b[lc];
        #pragma unroll
        for (int j = 0; j < 8; ++j) acc[j] = b0;
        #pragma unroll
        for (int dy = 0; dy < 5; ++dy) {
            int i = yy + dy + 1;
            uint4 ua = *(const uint4*)&ls[i][x0];
            uint4 ub = *(const uint4*)&ls[i][x0 + 8];
            float wv[16];
            unpack2(ua.x, wv[0], wv[1]); unpack2(ua.y, wv[2], wv[3]);
            unpack2(ua.z, wv[4], wv[5]); unpack2(ua.w, wv[6], wv[7]);
            unpack2(ub.x, wv[8], wv[9]); unpack2(ub.y, wv[10], wv[11]);
            unpack2(ub.z, wv[12], wv[13]); unpack2(ub.w, wv[14], wv[15]);
            if (dy == 2) {
                #pragma unroll
                for (int j = 0; j < 8; ++j) ctr[j] = wv[j + 4];
            }
            #pragma unroll
            for (int dx = 0; dx < 5; ++dx) {
                float wt = dw5w[lc * 25 + dy * 5 + dx];
                #pragma unroll
                for (int j = 0; j < 8; ++j) acc[j] += wt * wv[j + dx + 2];
            }
        }
    } else {
        int lc = c - 192;
        float b0 = dw7b[lc];
        #pragma unroll
        for (int j = 0; j < 8; ++j) acc[j] = b0;
        #pragma unroll
        for (int dy = 0; dy < 7; ++dy) {
            int i = yy + dy;
            uint4 ua = *(const uint4*)&ls[i][x0];
            uint4 ub = *(const uint4*)&ls[i][x0 + 8];
            float wv[16];
            unpack2(ua.x, wv[0], wv[1]); unpack2(ua.y, wv[2], wv[3]);
            unpack2(ua.z, wv[4], wv[5]); unpack2(ua.w, wv[6], wv[7]);
            unpack2(ub.x, wv[8], wv[9]); unpack2(ub.y, wv[10], wv[11]);
            unpack2(ub.z, wv[12], wv[13]); unpack2(ub.w, wv[14], wv[15]);
            if (dy == 3) {
                #pragma unroll
                for (int j = 0; j < 8; ++j) ctr[j] = wv[j + 4];
            }
            #pragma unroll
            for (int dx = 0; dx < 7; ++dx) {
                float wt = dw7w[lc * 49 + dy * 7 + dx];
                #pragma unroll
                for (int j = 0; j < 8; ++j) acc[j] += wt * wv[j + dx + 1];
            }
        }
    }

    bf16x8 o;
    #pragma unroll
    for (int j = 0; j < 8; ++j) {
        float val = fw * acc[j] + ctr[j];
        o[j] = (short)f2bf(gelu_exact(val) * bg + bb2);
    }
    ushort* outp = h2 + (((size_t)b * HID + c) << 12);
    *(bf16x8*)&outp[((r0 + yy) << 6) + x0] = o;
}

// ---------------- fc2 MFMA: out = bn2(fc2w @ h2) + x2 ----------------
__global__ __launch_bounds__(256) void fc2_mfma(const ushort* __restrict__ h2,
                                                const ushort* __restrict__ fc2wb,
                                                const float* __restrict__ bn2g,
                                                const float* __restrict__ bn2b,
                                                const float* __restrict__ x2,
                                                float* __restrict__ out) {
    int b = blockIdx.y;
    int tok0 = blockIdx.x * 64;
    int tid = threadIdx.x;
    int w = tid >> 6;
    int lr = tid & 15;
    int lg = (tid & 63) >> 4;
    __shared__ ushort Xt[64][256];    // [tok][chan], chunk-swizzled (32 KB)
    for (int k = 0; k < 8; ++k) {
        int e = tid + k * 256;        // 2048 chunks of 8 toks
        int c = e >> 3, t8 = (e & 7) * 8;
        bf16x8 v = *(const bf16x8*)&h2[((size_t)(b * 256 + c)) * NN + tok0 + t8];
        #pragma unroll
        for (int j = 0; j < 8; ++j) {
            int t = t8 + j;
            Xt[t][((c >> 3) ^ (t & 7)) * 8 + (c & 7)] = (ushort)v[j];
        }
    }
    __syncthreads();
    int brow = w * 16 + lr;
    f32x4 acc[4];
    #pragma unroll
    for (int mt = 0; mt < 4; ++mt) acc[mt] = (f32x4){0.f, 0.f, 0.f, 0.f};
    #pragma unroll
    for (int ks = 0; ks < 8; ++ks) {
        bf16x8 bfr = *(const bf16x8*)&Xt[brow][(((ks * 4 + lg) & 7) ^ (lr & 7)) * 8 + ((ks * 4 + lg) & ~7) * 8];
        #pragma unroll
        for (int mt = 0; mt < 4; ++mt) {
            bf16x8 a = *(const bf16x8*)&fc2wb[(mt * 16 + lr) * 256 + ks * 32 + lg * 8];
            acc[mt] = MFMA16(a, bfr, acc[mt]);
        }
    }
    const float sb = rsqrtf(1.f + EPSV);
    int tok = tok0 + w * 16 + lr;
    #pragma unroll
    for (int mt = 0; mt < 4; ++mt) {
        #pragma unroll
        for (int r = 0; r < 4; ++r) {
            int o = mt * 16 + lg * 4 + r;
            size_t off = ((size_t)b * 64 + o) * NN + tok;
            out[off] = acc[mt][r] * bn2g[o] * sb + bn2b[o] + x2[off];
        }
    }
}

extern "C" void kernel_launch(void* const* d_in, const int* in_sizes, int n_in,
                              void* d_out, int out_size, void* d_ws, size_t ws_size,
                              hipStream_t stream) {
    const float* x    = (const float*)d_in[0];
    const float* cnn  = (const float*)d_in[1];
    const float* n1g  = (const float*)d_in[2];
    const float* n1b  = (const float*)d_in[3];
    const float* n2g  = (const float*)d_in[4];
    const float* n2b  = (const float*)d_in[5];
    const float* n3g  = (const float*)d_in[6];
    const float* n3b  = (const float*)d_in[7];
    const float* qw   = (const float*)d_in[8];
    const float* qb   = (const float*)d_in[9];
    const float* kvw  = (const float*)d_in[10];
    const float* kvb  = (const float*)d_in[11];
    const float* lcw  = (const float*)d_in[12];
    const float* lcb  = (const float*)d_in[13];
    const float* fc1w = (const float*)d_in[14];
    const float* bn1g = (const float*)d_in[15];
    const float* bn1b = (const float*)d_in[16];
    const float* dw1w = (const float*)d_in[17];
    const float* dw1b = (const float*)d_in[18];
    const float* dw3w = (const float*)d_in[19];
    const float* dw3b = (const float*)d_in[20];
    const float* dw5w = (const float*)d_in[21];
    const float* dw5b = (const float*)d_in[22];
    const float* dw7w = (const float*)d_in[23];
    const float* dw7b = (const float*)d_in[24];
    const float* bnmg = (const float*)d_in[25];
    const float* bnmb = (const float*)d_in[26];
    const float* fftw = (const float*)d_in[27];
    const float* fc2w = (const float*)d_in[28];
    const float* bn2g = (const float*)d_in[29];
    const float* bn2b = (const float*)d_in[30];

    float* ws = (float*)d_ws;
    float* stats = ws;                     // 64
    float* part  = ws + 64;                // 1024
    float* part2 = ws + 1088;              // 2048
    float* base  = ws + 3200;
    const size_t M = 1048576;
    float* x2     = base;                              // [0, 1M)
    ushort* qr_bf = (ushort*)(base + M);               // [1M, 1.5M)
    ushort* kr_bf = (ushort*)(base + M + M / 2);       // [1.5M, 2M)
    ushort* vt_bf = (ushort*)(base + 2 * M);           // [2M, 2.5M)
    float* kvin   = base + 5 * M / 2;                  // [2.5M, 3.5M)
    ushort* Opart = (ushort*)(base + 7 * M / 2);       // [3.5M, 7.5M)
    float* ml     = base + 15 * M / 2;                 // [7.5M, 7.75M)
    ushort* h1 = (ushort*)(base + M);                  // overlay qr/kr/vt/kvin
    ushort* h2 = (ushort*)(base + 7 * M / 2);          // overlay Opart head
    ushort* fc1wb = (ushort*)(base + 8 * M);           // 16384 ushorts
    ushort* fc2wb = fc1wb + 16384;                     // 16384 ushorts
    float* outp = (float*)d_out;

    wprep_kernel<<<128, 256, 0, stream>>>(fc1w, fc2w, fc1wb, fc2wb);
    stats_pair_kernel<<<dim3(64, 4), 256, 0, stream>>>(x, cnn, part);
    stats_fin_kernel<<<8, 64, 0, stream>>>(part, stats);
    dw3k_kernel<<<4096, 256, 0, stream>>>(cnn, n3g, n3b, lcw, lcb, stats, kvin);
    q_kernel<<<dim3(128, 4), 256, 0, stream>>>(x, n1g, n1b, qw, qb, stats, qr_bf);
    kv_kernel<<<dim3(256, 4), 256, 0, stream>>>(kvin, kvw, kvb, kr_bf, vt_bf);
    attn_kernel<<<dim3(64, 4, NCH), 256, 0, stream>>>(qr_bf, kr_bf, vt_bf, Opart, ml);
    combine_kernel<<<1024, 256, 0, stream>>>(Opart, ml, x, x2, part2);
    stats2b_kernel<<<4, 256, 0, stream>>>(part2, stats, 2);
    fc1_mfma<<<dim3(128, 4), 256, 0, stream>>>(x2, fc1wb, n2g, n2b, bn1g, bn1b, stats, h1);
    mixer_kernel<<<dim3(512, 4), 256, 0, stream>>>(h1, dw1w, dw1b, dw3w, dw3b, dw5w, dw5b,
                                                   dw7w, dw7b, fftw, bnmg, bnmb, h2);
    fc2_mfma<<<dim3(64, 4), 256, 0, stream>>>(h2, fc2wb, bn2g, bn2b, x2, outp);
}

// Round 10
// 120.955 us; speedup vs baseline: 12.2415x; 1.2193x over previous
//
#include <hip/hip_runtime.h>
#include <hip/hip_bf16.h>
#include <math.h>

#define BB 4
#define CC 64
#define NN 4096
#define HD 64
#define HID 256
#define EPSV 1e-5f
#define CNT (CC*NN)
#define NCH 8            // KV split chunks

typedef float f32x4 __attribute__((ext_vector_type(4)));
typedef short bf16x8 __attribute__((ext_vector_type(8)));
typedef short bf16x4 __attribute__((ext_vector_type(4)));
#define MFMA16(a, b, c) __builtin_amdgcn_mfma_f32_16x16x32_bf16(a, b, c, 0, 0, 0)

__device__ __forceinline__ float gelu_exact(float x) {
    return 0.5f * x * (1.0f + erff(x * 0.70710678118654752f));
}
__device__ __forceinline__ ushort f2bf(float f) {
    unsigned u = __float_as_uint(f);
    unsigned r = (u + 0x7FFFu + ((u >> 16) & 1u)) >> 16;
    return (ushort)r;
}
__device__ __forceinline__ float bf2f(ushort u) {
    return __uint_as_float(((unsigned)u) << 16);
}
__device__ __forceinline__ unsigned cvtpk(float lo, float hi) {
    unsigned r;
    asm("v_cvt_pk_bf16_f32 %0, %1, %2" : "=v"(r) : "v"(lo), "v"(hi));
    return r;
}
__device__ __forceinline__ void unpack2(unsigned u, float& lo, float& hi) {
    lo = __uint_as_float(u << 16);
    hi = __uint_as_float(u & 0xffff0000u);
}

// ---------------- weight prep: fp32 -> bf16 (fc1, fc2, qw, kvw) ----------------
__global__ __launch_bounds__(256) void wprep_kernel(const float* __restrict__ fc1w,
                                                    const float* __restrict__ fc2w,
                                                    const float* __restrict__ qw,
                                                    const float* __restrict__ kvw,
                                                    ushort* __restrict__ fc1wb,
                                                    ushort* __restrict__ fc2wb,
                                                    ushort* __restrict__ qwb,
                                                    ushort* __restrict__ kvwb) {
    int i = blockIdx.x * 256 + threadIdx.x;   // 45056
    if (i < 16384) fc1wb[i] = f2bf(fc1w[i]);
    else if (i < 32768) fc2wb[i - 16384] = f2bf(fc2w[i - 16384]);
    else if (i < 36864) qwb[i - 32768] = f2bf(qw[i - 32768]);
    else if (i < 45056) kvwb[i - 36864] = f2bf(kvw[i - 36864]);
}

// ---------------- fused stats stage 1 for x and cnn ----------------
__global__ __launch_bounds__(256) void stats_pair_kernel(const float* __restrict__ x,
                                                         const float* __restrict__ cnn,
                                                         float* __restrict__ part) {
    int b = blockIdx.y;
    int blk = blockIdx.x;
    const float4* p0 = (const float4*)(x + (size_t)b * CNT);
    const float4* p1 = (const float4*)(cnn + (size_t)b * CNT);
    float s0 = 0.f, s20 = 0.f, s1 = 0.f, s21 = 0.f;
    #pragma unroll
    for (int k = 0; k < 4; ++k) {
        float4 v = p0[blk * 1024 + k * 256 + threadIdx.x];
        s0  += v.x + v.y + v.z + v.w;
        s20 += v.x * v.x + v.y * v.y + v.z * v.z + v.w * v.w;
        float4 u = p1[blk * 1024 + k * 256 + threadIdx.x];
        s1  += u.x + u.y + u.z + u.w;
        s21 += u.x * u.x + u.y * u.y + u.z * u.z + u.w * u.w;
    }
    #pragma unroll
    for (int off = 32; off > 0; off >>= 1) {
        s0  += __shfl_xor(s0, off);
        s20 += __shfl_xor(s20, off);
        s1  += __shfl_xor(s1, off);
        s21 += __shfl_xor(s21, off);
    }
    __shared__ float sh[4][4];
    int wid = threadIdx.x >> 6, lane = threadIdx.x & 63;
    if (lane == 0) { sh[wid][0] = s0; sh[wid][1] = s20; sh[wid][2] = s1; sh[wid][3] = s21; }
    __syncthreads();
    if (threadIdx.x == 0) {
        float a0 = sh[0][0] + sh[1][0] + sh[2][0] + sh[3][0];
        float a1 = sh[0][1] + sh[1][1] + sh[2][1] + sh[3][1];
        float a2 = sh[0][2] + sh[1][2] + sh[2][2] + sh[3][2];
        float a3 = sh[0][3] + sh[1][3] + sh[2][3] + sh[3][3];
        part[((0 * 4 + b) * 64 + blk) * 2]     = a0;
        part[((0 * 4 + b) * 64 + blk) * 2 + 1] = a1;
        part[((1 * 4 + b) * 64 + blk) * 2]     = a2;
        part[((1 * 4 + b) * 64 + blk) * 2 + 1] = a3;
    }
}

// ---------------- stats finalize (both slots) ----------------
__global__ __launch_bounds__(64) void stats_fin_kernel(const float* __restrict__ part,
                                                       float* __restrict__ stats) {
    int sb_ = blockIdx.x;    // slot*4 + b
    int lane = threadIdx.x;
    float s = part[(sb_ * 64 + lane) * 2];
    float s2 = part[(sb_ * 64 + lane) * 2 + 1];
    #pragma unroll
    for (int off = 32; off > 0; off >>= 1) {
        s  += __shfl_xor(s, off);
        s2 += __shfl_xor(s2, off);
    }
    if (lane == 0) {
        int slot = sb_ >> 2, b = sb_ & 3;
        float mu = s / (float)CNT;
        float var = s2 / (float)CNT - mu * mu;
        stats[slot * 8 + b] = mu;
        stats[slot * 8 + 4 + b] = rsqrtf(var + EPSV);
    }
}

// ---------------- stats stage 2b (256 partials, slot 2) ----------------
__global__ __launch_bounds__(256) void stats2b_kernel(const float* __restrict__ part2,
                                                      float* __restrict__ stats, int slot) {
    int b = blockIdx.x;
    int t = threadIdx.x;
    float s = part2[(b * 256 + t) * 2];
    float s2 = part2[(b * 256 + t) * 2 + 1];
    #pragma unroll
    for (int off = 32; off > 0; off >>= 1) {
        s  += __shfl_xor(s, off);
        s2 += __shfl_xor(s2, off);
    }
    __shared__ float shs[4], shs2[4];
    int wid = t >> 6, lane = t & 63;
    if (lane == 0) { shs[wid] = s; shs2[wid] = s2; }
    __syncthreads();
    if (t == 0) {
        float S = shs[0] + shs[1] + shs[2] + shs[3];
        float S2 = shs2[0] + shs2[1] + shs2[2] + shs2[3];
        float mu = S / (float)CNT;
        float var = S2 / (float)CNT - mu * mu;
        stats[slot * 8 + b] = mu;
        stats[slot * 8 + 4 + b] = rsqrtf(var + EPSV);
    }
}

// ---------------- dw3k: kvin = dw3(gn(cnn)) + bias + gn(cnn) ----------------
__global__ __launch_bounds__(256) void dw3k_kernel(const float* __restrict__ cnn,
                                                   const float* __restrict__ n3g,
                                                   const float* __restrict__ n3b,
                                                   const float* __restrict__ lcw,
                                                   const float* __restrict__ lcb,
                                                   const float* __restrict__ stats,
                                                   float* __restrict__ kvin) {
    int i = blockIdx.x * 256 + threadIdx.x;   // 1,048,576
    int x = i & 63;
    int y = (i >> 6) & 63;
    int c = (i >> 12) & 63;
    int b = i >> 18;
    float mu = stats[1 * 8 + b];
    float rs = stats[1 * 8 + 4 + b];
    float sc = rs * n3g[c];
    float of = n3b[c] - mu * sc;
    const float* plane = cnn + ((size_t)(i >> 12) << 12);
    float acc = lcb[c];
    #pragma unroll
    for (int dy = 0; dy < 3; ++dy) {
        int yy = y + dy - 1;
        if (yy < 0 || yy >= 64) continue;
        #pragma unroll
        for (int dx = 0; dx < 3; ++dx) {
            int xx = x + dx - 1;
            if (xx < 0 || xx >= 64) continue;
            acc += lcw[c * 9 + dy * 3 + dx] * (plane[(yy << 6) + xx] * sc + of);
        }
    }
    kvin[i] = acc + plane[(y << 6) + x] * sc + of;
}

// ---------------- Q MFMA: gn(x) -> proj -> bias+RoPE -> bf16 (B,N,HD) ----------------
// grid dim3(64, B), 256 thr: 64 toks, 64 outputs
__global__ __launch_bounds__(256) void q_mfma(const float* __restrict__ x,
                                              const float* __restrict__ n1g,
                                              const float* __restrict__ n1b,
                                              const ushort* __restrict__ qwb,
                                              const float* __restrict__ qb,
                                              const float* __restrict__ stats,
                                              ushort* __restrict__ qr) {
    int b = blockIdx.y;
    int tok0 = blockIdx.x * 64;
    int tid = threadIdx.x;
    int w = tid >> 6;
    int lr = tid & 15;
    int lg = (tid & 63) >> 4;
    float mu = stats[0 * 8 + b];
    float rs = stats[0 * 8 + 4 + b];
    __shared__ ushort Xt[64][64];     // [tok][chan], chunk-swizzled
    for (int k = 0; k < 16; ++k) {
        int e = tid + k * 256;
        int c = e >> 6, t = e & 63;
        float v = (x[((size_t)(b * 64 + c)) * NN + tok0 + t] - mu) * rs * n1g[c] + n1b[c];
        Xt[t][((c >> 3) ^ (t & 7)) * 8 + (c & 7)] = f2bf(v);
    }
    __syncthreads();
    int brow = w * 16 + lr;
    bf16x8 bf0 = *(const bf16x8*)&Xt[brow][((0 + lg) ^ (lr & 7)) * 8];
    bf16x8 bf1 = *(const bf16x8*)&Xt[brow][((4 + lg) ^ (lr & 7)) * 8];
    f32x4 acc[4];
    #pragma unroll
    for (int mt = 0; mt < 4; ++mt) acc[mt] = (f32x4){0.f, 0.f, 0.f, 0.f};
    #pragma unroll
    for (int mt = 0; mt < 4; ++mt) {
        bf16x8 a0 = *(const bf16x8*)&qwb[(mt * 16 + lr) * 64 + lg * 8];
        bf16x8 a1 = *(const bf16x8*)&qwb[(mt * 16 + lr) * 64 + 32 + lg * 8];
        acc[mt] = MFMA16(a0, bf0, acc[mt]);
        acc[mt] = MFMA16(a1, bf1, acc[mt]);
    }
    int tok = tok0 + w * 16 + lr;
    int hh = tok >> 6, ww2 = tok & 63;
    ushort* qrow = qr + ((size_t)b * NN + tok) * 64;
    #pragma unroll
    for (int mt = 0; mt < 4; ++mt) {
        #pragma unroll
        for (int pr = 0; pr < 2; ++pr) {
            int o = mt * 16 + lg * 4 + pr * 2;
            float a0 = acc[mt][pr * 2]     + qb[o];
            float a1 = acc[mt][pr * 2 + 1] + qb[o + 1];
            int j = (o & 31) >> 1;
            float freq = exp2f(-0.88584749f * (float)j);
            float pos = (o < 32) ? (float)hh : (float)ww2;
            float st, ct;
            __sincosf(pos * freq, &st, &ct);
            qrow[o]     = f2bf(a0 * ct - a1 * st);
            qrow[o + 1] = f2bf(a1 * ct + a0 * st);
        }
    }
}

// ---------------- KV MFMA: kvin -> proj; K+RoPE (B,N,HD); V^T key-permuted (B,HD,N) ----------------
// grid dim3(64, B), 256 thr: 64 toks, 128 outputs
__global__ __launch_bounds__(256) void kv_mfma(const float* __restrict__ kvin,
                                               const ushort* __restrict__ kvwb,
                                               const float* __restrict__ kvb,
                                               ushort* __restrict__ kr,
                                               ushort* __restrict__ vt) {
    int b = blockIdx.y;
    int tok0 = blockIdx.x * 64;
    int tid = threadIdx.x;
    int w = tid >> 6;
    int lr = tid & 15;
    int lg = (tid & 63) >> 4;
    __shared__ ushort Xt[64][64];
    for (int k = 0; k < 16; ++k) {
        int e = tid + k * 256;
        int c = e >> 6, t = e & 63;
        Xt[t][((c >> 3) ^ (t & 7)) * 8 + (c & 7)] =
            f2bf(kvin[((size_t)(b * 64 + c)) * NN + tok0 + t]);
    }
    __syncthreads();
    int brow = w * 16 + lr;
    bf16x8 bf0 = *(const bf16x8*)&Xt[brow][((0 + lg) ^ (lr & 7)) * 8];
    bf16x8 bf1 = *(const bf16x8*)&Xt[brow][((4 + lg) ^ (lr & 7)) * 8];
    f32x4 acc[8];
    #pragma unroll
    for (int mt = 0; mt < 8; ++mt) acc[mt] = (f32x4){0.f, 0.f, 0.f, 0.f};
    #pragma unroll
    for (int mt = 0; mt < 8; ++mt) {
        bf16x8 a0 = *(const bf16x8*)&kvwb[(mt * 16 + lr) * 64 + lg * 8];
        bf16x8 a1 = *(const bf16x8*)&kvwb[(mt * 16 + lr) * 64 + 32 + lg * 8];
        acc[mt] = MFMA16(a0, bf0, acc[mt]);
        acc[mt] = MFMA16(a1, bf1, acc[mt]);
    }
    int tl = w * 16 + lr;                 // token-in-block
    int tok = tok0 + tl;
    int hh = tok >> 6, ww2 = tok & 63;
    int permk = (lr >> 2) * 16 + w * 4 + (lr & 3);   // perm(tl) for V key order
    ushort* krow = kr + ((size_t)b * NN + tok) * 64;
    #pragma unroll
    for (int mt = 0; mt < 4; ++mt) {      // K half, with RoPE
        #pragma unroll
        for (int pr = 0; pr < 2; ++pr) {
            int o = mt * 16 + lg * 4 + pr * 2;
            float a0 = acc[mt][pr * 2]     + kvb[o];
            float a1 = acc[mt][pr * 2 + 1] + kvb[o + 1];
            int j = (o & 31) >> 1;
            float freq = exp2f(-0.88584749f * (float)j);
            float pos = (o < 32) ? (float)hh : (float)ww2;
            float st, ct;
            __sincosf(pos * freq, &st, &ct);
            krow[o]     = f2bf(a0 * ct - a1 * st);
            krow[o + 1] = f2bf(a1 * ct + a0 * st);
        }
    }
    #pragma unroll
    for (int mt = 4; mt < 8; ++mt) {      // V half, key-permuted transpose store
        #pragma unroll
        for (int r = 0; r < 4; ++r) {
            int o = mt * 16 + lg * 4 + r;          // [64,128)
            float a0 = acc[mt][r] + kvb[o];
            vt[((size_t)b * 64 + (o - 64)) * NN + tok0 + permk] = f2bf(a0);
        }
    }
}

// ---------------- MFMA flash attention v4: swapped QK^T, in-reg P, b128 PV ----------------
// grid dim3(64, B, NCH), 256 thr = 4 waves x 16 q-rows; KV tile 64; chunk = 512 keys
__global__ __launch_bounds__(256) void attn_kernel(const ushort* __restrict__ qr,
                                                   const ushort* __restrict__ kr,
                                                   const ushort* __restrict__ vt,
                                                   ushort* __restrict__ Opart,
                                                   float* __restrict__ ml) {
    int b = blockIdx.y;
    int q0 = blockIdx.x * 64;
    int chunk = blockIdx.z;
    int tid = threadIdx.x;
    int w = tid >> 6;
    int lane = tid & 63;
    int lr = lane & 15;
    int lg = lane >> 4;
    const float SCL2 = 0.125f * 1.44269504f;   // HD^-0.5 * log2(e)

    __shared__ ushort Kl[64 * 64];
    __shared__ ushort Vl[64 * 64];

    bf16x8 qf[2];
    {
        const ushort* qp = qr + ((size_t)b * NN + q0 + w * 16 + lr) * 64;
        qf[0] = *(const bf16x8*)(qp + lg * 8);
        qf[1] = *(const bf16x8*)(qp + 32 + lg * 8);
    }

    f32x4 oacc[4];
    #pragma unroll
    for (int t = 0; t < 4; ++t) oacc[t] = (f32x4){0.f, 0.f, 0.f, 0.f};
    float m_ = -INFINITY, l_ = 0.f;     // scalar state for q-row = q0+w*16+lr

    const size_t kbase = ((size_t)b * NN) * 64;
    const int t0 = chunk * 8, tend = t0 + 8;

    for (int t = t0; t < tend; ++t) {
        int k0 = t * 64;
        __syncthreads();
        #pragma unroll
        for (int it = 0; it < 2; ++it) {
            int e = tid + it * 256;
            int row = e >> 3, cib = e & 7;
            int sw = cib ^ (row & 7);
            *(bf16x8*)(Kl + row * 64 + sw * 8) =
                *(const bf16x8*)(kr + kbase + (size_t)(k0 + row) * 64 + cib * 8);
            *(bf16x8*)(Vl + row * 64 + sw * 8) =
                *(const bf16x8*)(vt + ((size_t)b * 64 + row) * NN + k0 + cib * 8);
        }
        __syncthreads();

        // S^T = K Q : lane holds q=lr, keys kt*16 + lg*4 + r
        f32x4 sacc[4];
        #pragma unroll
        for (int kt = 0; kt < 4; ++kt) {
            int row = kt * 16 + lr;
            bf16x8 k0f = *(const bf16x8*)(Kl + row * 64 + ((0 * 4 + lg) ^ (lr & 7)) * 8);
            bf16x8 k1f = *(const bf16x8*)(Kl + row * 64 + ((1 * 4 + lg) ^ (lr & 7)) * 8);
            f32x4 z = {0.f, 0.f, 0.f, 0.f};
            z = MFMA16(k0f, qf[0], z);
            sacc[kt] = MFMA16(k1f, qf[1], z);
        }

        float vmax = fmaxf(fmaxf(fmaxf(sacc[0][0], sacc[0][1]), fmaxf(sacc[0][2], sacc[0][3])),
                           fmaxf(fmaxf(sacc[1][0], sacc[1][1]), fmaxf(sacc[1][2], sacc[1][3])));
        vmax = fmaxf(vmax, fmaxf(fmaxf(fmaxf(sacc[2][0], sacc[2][1]), fmaxf(sacc[2][2], sacc[2][3])),
                                 fmaxf(fmaxf(sacc[3][0], sacc[3][1]), fmaxf(sacc[3][2], sacc[3][3]))));
        vmax = fmaxf(vmax, __shfl_xor(vmax, 16));
        vmax = fmaxf(vmax, __shfl_xor(vmax, 32));
        float mx = vmax * SCL2;
        if (__any(mx - m_ > 8.f)) {          // defer-max
            float mn = fmaxf(m_, mx);
            float cr = exp2f(m_ - mn);
            l_ *= cr;
            m_ = mn;
            float crq[4];
            #pragma unroll
            for (int r = 0; r < 4; ++r) crq[r] = __shfl(cr, lg * 4 + r);
            #pragma unroll
            for (int ht = 0; ht < 4; ++ht)
                #pragma unroll
                for (int r = 0; r < 4; ++r) oacc[ht][r] *= crq[r];
        }

        unsigned u[8];
        float lsum = 0.f;
        #pragma unroll
        for (int kt = 0; kt < 4; ++kt) {
            float p0 = exp2f(sacc[kt][0] * SCL2 - m_);
            float p1 = exp2f(sacc[kt][1] * SCL2 - m_);
            float p2 = exp2f(sacc[kt][2] * SCL2 - m_);
            float p3 = exp2f(sacc[kt][3] * SCL2 - m_);
            lsum += (p0 + p1) + (p2 + p3);
            u[kt * 2]     = cvtpk(p0, p1);
            u[kt * 2 + 1] = cvtpk(p2, p3);
        }
        lsum += __shfl_xor(lsum, 16);
        lsum += __shfl_xor(lsum, 32);
        l_ += lsum;

        uint4 t0v = {u[0], u[1], u[2], u[3]};   // keys {lg*4+r, 16+lg*4+r}
        uint4 t1v = {u[4], u[5], u[6], u[7]};   // keys {32+lg*4+r, 48+lg*4+r}
        bf16x8 pa0 = __builtin_bit_cast(bf16x8, t0v);
        bf16x8 pa1 = __builtin_bit_cast(bf16x8, t1v);
        // PV: V stored key-permuted so lane's keys are contiguous chunks lg*2, lg*2+1
        #pragma unroll
        for (int ht = 0; ht < 4; ++ht) {
            int row = ht * 16 + lr;
            bf16x8 vf0 = *(const bf16x8*)(Vl + row * 64 + ((lg * 2) ^ (row & 7)) * 8);
            bf16x8 vf1 = *(const bf16x8*)(Vl + row * 64 + ((lg * 2 + 1) ^ (row & 7)) * 8);
            oacc[ht] = MFMA16(pa0, vf0, oacc[ht]);
            oacc[ht] = MFMA16(pa1, vf1, oacc[ht]);
        }
    }

    int n0 = q0 + w * 16 + lg * 4;
    #pragma unroll
    for (int ht = 0; ht < 4; ++ht) {
        int hd = ht * 16 + lr;
        ushort4 o4;
        o4.x = f2bf(oacc[ht][0]);
        o4.y = f2bf(oacc[ht][1]);
        o4.z = f2bf(oacc[ht][2]);
        o4.w = f2bf(oacc[ht][3]);
        *(ushort4*)&Opart[(((size_t)chunk * BB + b) * 64 + hd) * NN + n0] = o4;
    }
    if (lg == 0) {
        int n = q0 + w * 16 + lr;
        ml[((size_t)b * NN + n) * 16 + chunk * 2]     = m_;
        ml[((size_t)b * NN + n) * 16 + chunk * 2 + 1] = l_;
    }
}

// ---------------- combine: x2 = sum_c O_c*w_c + x; fused stats partials ----------------
__global__ __launch_bounds__(256) void combine_kernel(const ushort* __restrict__ Opart,
                                                      const float* __restrict__ ml,
                                                      const float* __restrict__ x,
                                                      float* __restrict__ x2,
                                                      float* __restrict__ part2) {
    int i = blockIdx.x * 256 + threadIdx.x;   // 262144
    int n4 = i & 1023;
    int hd = (i >> 10) & 63;
    int b = i >> 16;
    int n0 = n4 << 2;
    float wgt[4][NCH];
    const float* mlp = ml + ((size_t)b * NN + n0) * 16;
    #pragma unroll
    for (int tk = 0; tk < 4; ++tk) {
        float m[NCH], l[NCH];
        const float4* p4 = (const float4*)(mlp + tk * 16);
        #pragma unroll
        for (int q = 0; q < 4; ++q) {
            float4 v = p4[q];
            m[q * 2] = v.x; l[q * 2] = v.y; m[q * 2 + 1] = v.z; l[q * 2 + 1] = v.w;
        }
        float M = m[0];
        #pragma unroll
        for (int c = 1; c < NCH; ++c) M = fmaxf(M, m[c]);
        float e[NCH], L = 0.f;
        #pragma unroll
        for (int c = 0; c < NCH; ++c) { e[c] = exp2f(m[c] - M); L += l[c] * e[c]; }
        float inv = 1.f / L;
        #pragma unroll
        for (int c = 0; c < NCH; ++c) wgt[tk][c] = e[c] * inv;
    }
    float4 acc = {0.f, 0.f, 0.f, 0.f};
    #pragma unroll
    for (int c = 0; c < NCH; ++c) {
        ushort4 o4 = *(const ushort4*)&Opart[(((size_t)c * BB + b) * 64 + hd) * NN + n0];
        acc.x += bf2f(o4.x) * wgt[0][c];
        acc.y += bf2f(o4.y) * wgt[1][c];
        acc.z += bf2f(o4.z) * wgt[2][c];
        acc.w += bf2f(o4.w) * wgt[3][c];
    }
    size_t off = ((size_t)b * 64 + hd) * NN + n0;
    float4 xv = *(const float4*)&x[off];
    acc.x += xv.x; acc.y += xv.y; acc.z += xv.z; acc.w += xv.w;
    *(float4*)&x2[off] = acc;

    float s = acc.x + acc.y + acc.z + acc.w;
    float s2 = acc.x * acc.x + acc.y * acc.y + acc.z * acc.z + acc.w * acc.w;
    #pragma unroll
    for (int off2 = 32; off2 > 0; off2 >>= 1) {
        s  += __shfl_xor(s, off2);
        s2 += __shfl_xor(s2, off2);
    }
    __shared__ float shs[4], shs2[4];
    int wid = threadIdx.x >> 6, lane = threadIdx.x & 63;
    if (lane == 0) { shs[wid] = s; shs2[wid] = s2; }
    __syncthreads();
    if (threadIdx.x == 0) {
        part2[blockIdx.x * 2]     = shs[0] + shs[1] + shs[2] + shs[3];
        part2[blockIdx.x * 2 + 1] = shs2[0] + shs2[1] + shs2[2] + shs2[3];
    }
}

// ---------------- fc1 MFMA: h1 = gelu(bn1(fc1w @ gn2(x2))) -> bf16 ----------------
__global__ __launch_bounds__(256) void fc1_mfma(const float* __restrict__ x2,
                                                const ushort* __restrict__ fc1wb,
                                                const float* __restrict__ n2g,
                                                const float* __restrict__ n2b,
                                                const float* __restrict__ bn1g,
                                                const float* __restrict__ bn1b,
                                                const float* __restrict__ stats,
                                                ushort* __restrict__ h1) {
    int b = blockIdx.y;
    int tok0 = (blockIdx.x >> 1) * 64;
    int half = blockIdx.x & 1;
    int tid = threadIdx.x;
    int w = tid >> 6;
    int lr = tid & 15;
    int lg = (tid & 63) >> 4;
    float mu = stats[2 * 8 + b];
    float rs = stats[2 * 8 + 4 + b];
    __shared__ ushort Xt[64][64];     // [tok][chan], chunk-swizzled
    for (int k = 0; k < 16; ++k) {
        int e = tid + k * 256;
        int c = e >> 6, t = e & 63;
        float v = (x2[((size_t)(b * 64 + c)) * NN + tok0 + t] - mu) * rs * n2g[c] + n2b[c];
        Xt[t][((c >> 3) ^ (t & 7)) * 8 + (c & 7)] = f2bf(v);
    }
    __syncthreads();
    int brow = w * 16 + lr;
    bf16x8 bf0 = *(const bf16x8*)&Xt[brow][((0 + lg) ^ (lr & 7)) * 8];
    bf16x8 bf1 = *(const bf16x8*)&Xt[brow][((4 + lg) ^ (lr & 7)) * 8];
    f32x4 acc[8];
    #pragma unroll
    for (int mt = 0; mt < 8; ++mt) acc[mt] = (f32x4){0.f, 0.f, 0.f, 0.f};
    const ushort* wb = fc1wb + (size_t)(half * 128) * 64;
    #pragma unroll
    for (int mt = 0; mt < 8; ++mt) {
        bf16x8 a0 = *(const bf16x8*)&wb[(mt * 16 + lr) * 64 + lg * 8];
        bf16x8 a1 = *(const bf16x8*)&wb[(mt * 16 + lr) * 64 + 32 + lg * 8];
        acc[mt] = MFMA16(a0, bf0, acc[mt]);
        acc[mt] = MFMA16(a1, bf1, acc[mt]);
    }
    const float sb = rsqrtf(1.f + EPSV);
    int tok = tok0 + w * 16 + lr;
    #pragma unroll
    for (int mt = 0; mt < 8; ++mt) {
        #pragma unroll
        for (int r = 0; r < 4; ++r) {
            int o = half * 128 + mt * 16 + lg * 4 + r;
            float vv = acc[mt][r] * bn1g[o] * sb + bn1b[o];
            h1[((size_t)b * HID + o) * NN + tok] = f2bf(gelu_exact(vv));
        }
    }
}

// ---------------- mixer v2: register sliding-window; 32-row half planes ----------------
__global__ __launch_bounds__(256) void mixer_kernel(const ushort* __restrict__ h1,
                                                    const float* __restrict__ dw1w, const float* __restrict__ dw1b,
                                                    const float* __restrict__ dw3w, const float* __restrict__ dw3b,
                                                    const float* __restrict__ dw5w, const float* __restrict__ dw5b,
                                                    const float* __restrict__ dw7w, const float* __restrict__ dw7b,
                                                    const float* __restrict__ fftw,
                                                    const float* __restrict__ bnmg, const float* __restrict__ bnmb,
                                                    ushort* __restrict__ h2) {
    int c = blockIdx.x >> 1;
    int r0 = (blockIdx.x & 1) * 32;
    int b = blockIdx.y;
    int tid = threadIdx.x;
    __shared__ ushort ls[38][80];      // 6080 B
    uint* lz = (uint*)&ls[0][0];
    #pragma unroll
    for (int k = 0; k < 6; ++k) {
        int i = tid + k * 256;
        if (i < 1520) lz[i] = 0;
    }
    __syncthreads();
    const ushort* plane = h1 + (((size_t)b * HID + c) << 12);
    for (int e = tid; e < 304; e += 256) {
        int i = e >> 3, xc = e & 7;
        int gr = r0 + i - 3;
        if (gr >= 0 && gr < 64) {
            bf16x8 v = *(const bf16x8*)&plane[(gr << 6) + xc * 8];
            bf16x4 lo = {v[0], v[1], v[2], v[3]};
            bf16x4 hi = {v[4], v[5], v[6], v[7]};
            *(bf16x4*)&ls[i][xc * 8 + 4] = lo;
            *(bf16x4*)&ls[i][xc * 8 + 8] = hi;
        }
    }
    __syncthreads();

    int yy = tid >> 3;
    int x0 = (tid & 7) * 8;
    const float sb = rsqrtf(1.f + EPSV);
    float fw = fftw[c];
    float bg = bnmg[c] * sb, bb2 = bnmb[c];
    float acc[8], ctr[8];
    #pragma unroll
    for (int j = 0; j < 8; ++j) acc[j] = 0.f;

    if (c < 64) {
        float w0 = dw1w[c], b0 = dw1b[c];
        uint4 ua = *(const uint4*)&ls[yy + 3][x0];
        uint4 ub = *(const uint4*)&ls[yy + 3][x0 + 8];
        float wv[16];
        unpack2(ua.x, wv[0], wv[1]); unpack2(ua.y, wv[2], wv[3]);
        unpack2(ua.z, wv[4], wv[5]); unpack2(ua.w, wv[6], wv[7]);
        unpack2(ub.x, wv[8], wv[9]); unpack2(ub.y, wv[10], wv[11]);
        unpack2(ub.z, wv[12], wv[13]); unpack2(ub.w, wv[14], wv[15]);
        #pragma unroll
        for (int j = 0; j < 8; ++j) { ctr[j] = wv[j + 4]; acc[j] = w0 * ctr[j] + b0; }
    } else if (c < 128) {
        int lc = c - 64;
        float b0 = dw3b[lc];
        #pragma unroll
        for (int j = 0; j < 8; ++j) acc[j] = b0;
        #pragma unroll
        for (int dy = 0; dy < 3; ++dy) {
            int i = yy + dy + 2;
            uint4 ua = *(const uint4*)&ls[i][x0];
            uint4 ub = *(const uint4*)&ls[i][x0 + 8];
            float wv[16];
            unpack2(ua.x, wv[0], wv[1]); unpack2(ua.y, wv[2], wv[3]);
            unpack2(ua.z, wv[4], wv[5]); unpack2(ua.w, wv[6], wv[7]);
            unpack2(ub.x, wv[8], wv[9]); unpack2(ub.y, wv[10], wv[11]);
            unpack2(ub.z, wv[12], wv[13]); unpack2(ub.w, wv[14], wv[15]);
            if (dy == 1) {
                #pragma unroll
                for (int j = 0; j < 8; ++j) ctr[j] = wv[j + 4];
            }
            #pragma unroll
            for (int dx = 0; dx < 3; ++dx) {
                float wt = dw3w[lc * 9 + dy * 3 + dx];
                #pragma unroll
                for (int j = 0; j < 8; ++j) acc[j] += wt * wv[j + dx + 3];
            }
        }
    } else if (c < 192) {
        int lc = c - 128;
        float b0 = dw5b[lc];
        #pragma unroll
        for (int j = 0; j < 8; ++j) acc[j] = b0;
        #pragma unroll
        for (int dy = 0; dy < 5; ++dy) {
            int i = yy + dy + 1;
            uint4 ua = *(const uint4*)&ls[i][x0];
            uint4 ub = *(const uint4*)&ls[i][x0 + 8];
            float wv[16];
            unpack2(ua.x, wv[0], wv[1]); unpack2(ua.y, wv[2], wv[3]);
            unpack2(ua.z, wv[4], wv[5]); unpack2(ua.w, wv[6], wv[7]);
            unpack2(ub.x, wv[8], wv[9]); unpack2(ub.y, wv[10], wv[11]);
            unpack2(ub.z, wv[12], wv[13]); unpack2(ub.w, wv[14], wv[15]);
            if (dy == 2) {
                #pragma unroll
                for (int j = 0; j < 8; ++j) ctr[j] = wv[j + 4];
            }
            #pragma unroll
            for (int dx = 0; dx < 5; ++dx) {
                float wt = dw5w[lc * 25 + dy * 5 + dx];
                #pragma unroll
                for (int j = 0; j < 8; ++j) acc[j] += wt * wv[j + dx + 2];
            }
        }
    } else {
        int lc = c - 192;
        float b0 = dw7b[lc];
        #pragma unroll
        for (int j = 0; j < 8; ++j) acc[j] = b0;
        #pragma unroll
        for (int dy = 0; dy < 7; ++dy) {
            int i = yy + dy;
            uint4 ua = *(const uint4*)&ls[i][x0];
            uint4 ub = *(const uint4*)&ls[i][x0 + 8];
            float wv[16];
            unpack2(ua.x, wv[0], wv[1]); unpack2(ua.y, wv[2], wv[3]);
            unpack2(ua.z, wv[4], wv[5]); unpack2(ua.w, wv[6], wv[7]);
            unpack2(ub.x, wv[8], wv[9]); unpack2(ub.y, wv[10], wv[11]);
            unpack2(ub.z, wv[12], wv[13]); unpack2(ub.w, wv[14], wv[15]);
            if (dy == 3) {
                #pragma unroll
                for (int j = 0; j < 8; ++j) ctr[j] = wv[j + 4];
            }
            #pragma unroll
            for (int dx = 0; dx < 7; ++dx) {
                float wt = dw7w[lc * 49 + dy * 7 + dx];
                #pragma unroll
                for (int j = 0; j < 8; ++j) acc[j] += wt * wv[j + dx + 1];
            }
        }
    }

    bf16x8 o;
    #pragma unroll
    for (int j = 0; j < 8; ++j) {
        float val = fw * acc[j] + ctr[j];
        o[j] = (short)f2bf(gelu_exact(val) * bg + bb2);
    }
    ushort* outp = h2 + (((size_t)b * HID + c) << 12);
    *(bf16x8*)&outp[((r0 + yy) << 6) + x0] = o;
}

// ---------------- fc2 MFMA: out = bn2(fc2w @ h2) + x2 ----------------
__global__ __launch_bounds__(256) void fc2_mfma(const ushort* __restrict__ h2,
                                                const ushort* __restrict__ fc2wb,
                                                const float* __restrict__ bn2g,
                                                const float* __restrict__ bn2b,
                                                const float* __restrict__ x2,
                                                float* __restrict__ out) {
    int b = blockIdx.y;
    int tok0 = blockIdx.x * 64;
    int tid = threadIdx.x;
    int w = tid >> 6;
    int lr = tid & 15;
    int lg = (tid & 63) >> 4;
    __shared__ ushort Xt[64][256];    // [tok][chan], chunk-swizzled (32 KB)
    for (int k = 0; k < 8; ++k) {
        int e = tid + k * 256;        // 2048 chunks of 8 toks
        int c = e >> 3, t8 = (e & 7) * 8;
        bf16x8 v = *(const bf16x8*)&h2[((size_t)(b * 256 + c)) * NN + tok0 + t8];
        #pragma unroll
        for (int j = 0; j < 8; ++j) {
            int t = t8 + j;
            Xt[t][((c >> 3) ^ (t & 7)) * 8 + (c & 7)] = (ushort)v[j];
        }
    }
    __syncthreads();
    int brow = w * 16 + lr;
    f32x4 acc[4];
    #pragma unroll
    for (int mt = 0; mt < 4; ++mt) acc[mt] = (f32x4){0.f, 0.f, 0.f, 0.f};
    #pragma unroll
    for (int ks = 0; ks < 8; ++ks) {
        bf16x8 bfr = *(const bf16x8*)&Xt[brow][(((ks * 4 + lg) & 7) ^ (lr & 7)) * 8 + ((ks * 4 + lg) & ~7) * 8];
        #pragma unroll
        for (int mt = 0; mt < 4; ++mt) {
            bf16x8 a = *(const bf16x8*)&fc2wb[(mt * 16 + lr) * 256 + ks * 32 + lg * 8];
            acc[mt] = MFMA16(a, bfr, acc[mt]);
        }
    }
    const float sb = rsqrtf(1.f + EPSV);
    int tok = tok0 + w * 16 + lr;
    #pragma unroll
    for (int mt = 0; mt < 4; ++mt) {
        #pragma unroll
        for (int r = 0; r < 4; ++r) {
            int o = mt * 16 + lg * 4 + r;
            size_t off = ((size_t)b * 64 + o) * NN + tok;
            out[off] = acc[mt][r] * bn2g[o] * sb + bn2b[o] + x2[off];
        }
    }
}

extern "C" void kernel_launch(void* const* d_in, const int* in_sizes, int n_in,
                              void* d_out, int out_size, void* d_ws, size_t ws_size,
                              hipStream_t stream) {
    const float* x    = (const float*)d_in[0];
    const float* cnn  = (const float*)d_in[1];
    const float* n1g  = (const float*)d_in[2];
    const float* n1b  = (const float*)d_in[3];
    const float* n2g  = (const float*)d_in[4];
    const float* n2b  = (const float*)d_in[5];
    const float* n3g  = (const float*)d_in[6];
    const float* n3b  = (const float*)d_in[7];
    const float* qw   = (const float*)d_in[8];
    const float* qb   = (const float*)d_in[9];
    const float* kvw  = (const float*)d_in[10];
    const float* kvb  = (const float*)d_in[11];
    const float* lcw  = (const float*)d_in[12];
    const float* lcb  = (const float*)d_in[13];
    const float* fc1w = (const float*)d_in[14];
    const float* bn1g = (const float*)d_in[15];
    const float* bn1b = (const float*)d_in[16];
    const float* dw1w = (const float*)d_in[17];
    const float* dw1b = (const float*)d_in[18];
    const float* dw3w = (const float*)d_in[19];
    const float* dw3b = (const float*)d_in[20];
    const float* dw5w = (const float*)d_in[21];
    const float* dw5b = (const float*)d_in[22];
    const float* dw7w = (const float*)d_in[23];
    const float* dw7b = (const float*)d_in[24];
    const float* bnmg = (const float*)d_in[25];
    const float* bnmb = (const float*)d_in[26];
    const float* fftw = (const float*)d_in[27];
    const float* fc2w = (const float*)d_in[28];
    const float* bn2g = (const float*)d_in[29];
    const float* bn2b = (const float*)d_in[30];

    float* ws = (float*)d_ws;
    float* stats = ws;                     // 64
    float* part  = ws + 64;                // 1024
    float* part2 = ws + 1088;              // 2048
    float* base  = ws + 3200;
    const size_t M = 1048576;
    float* x2     = base;                              // [0, 1M)
    ushort* qr_bf = (ushort*)(base + M);               // [1M, 1.5M)
    ushort* kr_bf = (ushort*)(base + M + M / 2);       // [1.5M, 2M)
    ushort* vt_bf = (ushort*)(base + 2 * M);           // [2M, 2.5M)
    float* kvin   = base + 5 * M / 2;                  // [2.5M, 3.5M)
    ushort* Opart = (ushort*)(base + 7 * M / 2);       // [3.5M, 7.5M)
    float* ml     = base + 15 * M / 2;                 // [7.5M, 7.75M)
    ushort* h1 = (ushort*)(base + M);                  // overlay qr/kr/vt/kvin
    ushort* h2 = (ushort*)(base + 7 * M / 2);          // overlay Opart head
    ushort* fc1wb = (ushort*)(base + 8 * M);           // 16384 ushorts
    ushort* fc2wb = fc1wb + 16384;
    ushort* qwb   = fc2wb + 16384;                     // 4096
    ushort* kvwb  = qwb + 4096;                        // 8192
    float* outp = (float*)d_out;

    wprep_kernel<<<176, 256, 0, stream>>>(fc1w, fc2w, qw, kvw, fc1wb, fc2wb, qwb, kvwb);
    stats_pair_kernel<<<dim3(64, 4), 256, 0, stream>>>(x, cnn, part);
    stats_fin_kernel<<<8, 64, 0, stream>>>(part, stats);
    dw3k_kernel<<<4096, 256, 0, stream>>>(cnn, n3g, n3b, lcw, lcb, stats, kvin);
    q_mfma<<<dim3(64, 4), 256, 0, stream>>>(x, n1g, n1b, qwb, qb, stats, qr_bf);
    kv_mfma<<<dim3(64, 4), 256, 0, stream>>>(kvin, kvwb, kvb, kr_bf, vt_bf);
    attn_kernel<<<dim3(64, 4, NCH), 256, 0, stream>>>(qr_bf, kr_bf, vt_bf, Opart, ml);
    combine_kernel<<<1024, 256, 0, stream>>>(Opart, ml, x, x2, part2);
    stats2b_kernel<<<4, 256, 0, stream>>>(part2, stats, 2);
    fc1_mfma<<<dim3(128, 4), 256, 0, stream>>>(x2, fc1wb, n2g, n2b, bn1g, bn1b, stats, h1);
    mixer_kernel<<<dim3(512, 4), 256, 0, stream>>>(h1, dw1w, dw1b, dw3w, dw3b, dw5w, dw5b,
                                                   dw7w, dw7b, fftw, bnmg, bnmb, h2);
    fc2_mfma<<<dim3(64, 4), 256, 0, stream>>>(h2, fc2wb, bn2g, bn2b, x2, outp);
}